// Round 1
// baseline (2854.336 us; speedup 1.0000x reference)
//
#include <hip/hip_runtime.h>
#include <math.h>

#define KNN 30
#define SIGMA_N 0.8f
#define THRESHV 1e-3f

// ---------------- old (fallback) path constants ----------------
#define QT 32
#define NTH 256
#define CAP 160
#define CAPS 161
#define RSEL 20

// ---------------- grid path constants ----------------
#define RG 64
#define NC (RG*RG*RG)
#define QT2 32
#define NTH2 256
#define CAP2 192
#define CAPS2 193
#define TGT 50.0f

// ============================================================
// ===============  OLD BRUTE-FORCE PATH (fallback) ===========
// ============================================================

__global__ void prep_pack(const float* __restrict__ src, float4* __restrict__ dst, int M) {
    int j = blockIdx.x * 256 + threadIdx.x;
    if (j < M) {
        float x = src[3*j+0], y = src[3*j+1], z = src[3*j+2];
        dst[j] = make_float4(x, y, z, 0.5f*(x*x + y*y + z*z));
    }
}

template<bool PACKED>
__device__ __forceinline__ float4 fetch_pt(const float4* __restrict__ sp,
                                           const float* __restrict__ sv, int j) {
    if (PACKED) return sp[j];
    float x = sv[3*j+0], y = sv[3*j+1], z = sv[3*j+2];
    return make_float4(x, y, z, 0.5f*(x*x + y*y + z*z));
}

__device__ __forceinline__ void ins4(unsigned int k, unsigned int &m0, unsigned int &m1,
                                     unsigned int &m2, unsigned int &m3) {
    if (k < m3) {
        if (k < m2) {
            m3 = m2;
            if (k < m1) { m2 = m1; if (k < m0) { m1 = m0; m0 = k; } else m1 = k; }
            else m2 = k;
        } else m3 = k;
    }
}

template<bool PACKED>
__global__ __launch_bounds__(NTH)
void rimls_fused(const float* __restrict__ qpts,
                 const float* __restrict__ sverts,
                 const float* __restrict__ snorms,
                 const float4* __restrict__ spack,
                 float* __restrict__ out,
                 int N, int M)
{
    __shared__ unsigned int cand[QT * CAPS];
    __shared__ unsigned int selk[QT * KNN];
    __shared__ float4 qbuf[QT];
    __shared__ unsigned int cnt[QT];
    __shared__ unsigned int T16[QT];
    __shared__ int retryq[QT];

    const int t  = threadIdx.x;
    const int qg = t >> 4;
    const int c  = t & 15;
    const int qa = qg, qb = qg + 16;

    if (t < QT) {
        int gq = blockIdx.x * QT + t; if (gq >= N) gq = N - 1;
        float x = qpts[3*gq+0], y = qpts[3*gq+1], z = qpts[3*gq+2];
        qbuf[t] = make_float4(x, y, z, 0.5f*(x*x + y*y + z*z));
    }
    for (int i = t; i < QT * KNN; i += NTH) selk[i] = 0u;
    __syncthreads();

    const float ax = qbuf[qa].x, ay = qbuf[qa].y, az = qbuf[qa].z, aw = qbuf[qa].w;
    const float bx = qbuf[qb].x, by = qbuf[qb].y, bz = qbuf[qb].z, bw = qbuf[qb].w;

    unsigned int a0=~0u,a1=~0u,a2=~0u,a3=~0u, b0=~0u,b1=~0u,b2=~0u,b3=~0u;
    {
        const int n1 = M >> 6;
        #pragma unroll 2
        for (int i = 0; i < n1; ++i) {
            int j = (c + (i << 4)) << 2;
            float4 s = fetch_pt<PACKED>(spack, sverts, j);
            float va = fmaxf(fmaf(-ax, s.x, fmaf(-ay, s.y, fmaf(-az, s.z, s.w + aw))), 0.0f);
            float vb = fmaxf(fmaf(-bx, s.x, fmaf(-by, s.y, fmaf(-bz, s.z, s.w + bw))), 0.0f);
            unsigned int ka = (__float_as_uint(va) & 0xFFFF0000u) | (unsigned int)j;
            unsigned int kb = (__float_as_uint(vb) & 0xFFFF0000u) | (unsigned int)j;
            ins4(ka, a0, a1, a2, a3);
            ins4(kb, b0, b1, b2, b3);
        }
    }
    {
        unsigned int* mb = cand;
        mb[qa*64 + c*4 + 0] = a0; mb[qa*64 + c*4 + 1] = a1;
        mb[qa*64 + c*4 + 2] = a2; mb[qa*64 + c*4 + 3] = a3;
        mb[qb*64 + c*4 + 0] = b0; mb[qb*64 + c*4 + 1] = b1;
        mb[qb*64 + c*4 + 2] = b2; mb[qb*64 + c*4 + 3] = b3;
    }
    __syncthreads();
    if (t < QT) {
        const unsigned int* m_ = cand + t * 64;
        unsigned int kth = 0xFFFFFFFFu;
        for (int a = 0; a < 64; ++a) {
            unsigned int ka = m_[a]; int r = 0;
            for (int b = 0; b < 64; ++b) r += (m_[b] < ka) ? 1 : 0;
            if (r == RSEL - 1) kth = ka;
        }
        unsigned int tb = (kth >> 16) + 1u;
        if (tb > 0x7F00u) tb = 0x7F00u;
        T16[t] = tb; cnt[t] = 0u; retryq[t] = 1;
    }
    __syncthreads();

    const int n3 = M >> 4;
    for (int round = 0; round < 8; ++round) {
        bool aa = retryq[qa] != 0, ab = retryq[qb] != 0;
        if (aa || ab) {
            float Ta = aa ? __uint_as_float(T16[qa] << 16) : 0.0f;
            float Tb = ab ? __uint_as_float(T16[qb] << 16) : 0.0f;
            #pragma unroll 4
            for (int i = 0; i < n3; ++i) {
                int j = c + (i << 4);
                float4 s = fetch_pt<PACKED>(spack, sverts, j);
                float va = fmaxf(fmaf(-ax, s.x, fmaf(-ay, s.y, fmaf(-az, s.z, s.w + aw))), 0.0f);
                float vb = fmaxf(fmaf(-bx, s.x, fmaf(-by, s.y, fmaf(-bz, s.z, s.w + bw))), 0.0f);
                if (va < Ta) {
                    unsigned int pos = atomicAdd(&cnt[qa], 1u);
                    if (pos < (unsigned)CAP)
                        cand[qa*CAPS + pos] = (__float_as_uint(va) & 0xFFFF0000u) | (unsigned int)j;
                }
                if (vb < Tb) {
                    unsigned int pos = atomicAdd(&cnt[qb], 1u);
                    if (pos < (unsigned)CAP)
                        cand[qb*CAPS + pos] = (__float_as_uint(vb) & 0xFFFF0000u) | (unsigned int)j;
                }
            }
        }
        __syncthreads();
        int bad = 0;
        if (t < QT && retryq[t]) {
            unsigned int cc = cnt[t], tb = T16[t];
            if (cc < (unsigned)KNN) {
                if (tb < 0x7F00u) {
                    tb += (1u << 7);
                    if (tb > 0x7F00u) tb = 0x7F00u;
                    bad = 1;
                }
            } else if (cc > (unsigned)CAP && round < 4 && tb > (1u << 6)) {
                tb -= (1u << 6); bad = 1;
            }
            if (bad) { T16[t] = tb; cnt[t] = 0u; }
            else retryq[t] = 0;
        }
        if (!__syncthreads_or(bad)) break;
    }

    const int qs = t >> 3, s8 = t & 7;
    {
        unsigned int cc = cnt[qs];
        int C = (int)(cc < (unsigned)CAP ? cc : (unsigned)CAP);
        const unsigned int* cd = cand + qs * CAPS;
        for (int a = s8; a < C; a += 8) {
            unsigned int ka = cd[a]; int r = 0;
            for (int b = 0; b < C; ++b) r += (cd[b] < ka) ? 1 : 0;
            if (r < KNN) selk[qs*KNN + r] = ka;
        }
    }
    __syncthreads();

    {
        const float qx = qbuf[qs].x, qy = qbuf[qs].y, qz = qbuf[qs].z;
        float px_[4], py_[4], pz_[4], nx_[4], ny_[4], nz_[4];
        float fx_[4], phi_[4], gco_[4], r2_[4];
        float dsum = 0.0f;
        #pragma unroll
        for (int u = 0; u < 4; ++u) {
            int k = s8 + 8*u;
            bool v = (k < KNN);
            int j = v ? (int)(selk[qs*KNN + k] & 0xFFFFu) : 0;
            float4 s = fetch_pt<PACKED>(spack, sverts, j);
            float px = qx - s.x, py = qy - s.y, pz = qz - s.z;
            float r2 = px*px + py*py + pz*pz;
            float nx = snorms[3*j+0], ny = snorms[3*j+1], nz = snorms[3*j+2];
            float nrm = sqrtf(nx*nx + ny*ny + nz*nz);
            float inv = 1.0f / fmaxf(nrm, 1e-8f);
            float m = v ? 1.0f : 0.0f;
            nx *= inv * m; ny *= inv * m; nz *= inv * m;
            px_[u] = px * m; py_[u] = py * m; pz_[u] = pz * m;
            nx_[u] = nx; ny_[u] = ny; nz_[u] = nz;
            r2_[u] = r2 * m;
            fx_[u] = px_[u]*nx + py_[u]*ny + pz_[u]*nz;
            dsum += v ? sqrtf(r2) : 0.0f;
            phi_[u] = m;
        }
        dsum += __shfl_xor(dsum, 1);
        dsum += __shfl_xor(dsum, 2);
        dsum += __shfl_xor(dsum, 4);
        float h = dsum * (1.0f / (float)KNN) + 1e-8f;
        float h2 = h * h;
        float c8 = -8.0f / h2;
        #pragma unroll
        for (int u = 0; u < 4; ++u) {
            float tt = fmaxf(1.0f - r2_[u] / h2, 0.0f);
            float t2 = tt * tt;
            float valid = phi_[u];
            phi_[u] = t2 * t2 * valid;
            gco_[u] = c8 * t2 * tt * valid;
        }

        const float inv_sn2 = 1.0f / (SIGMA_N * SIGMA_N);
        float f = 0.0f, gx = 0.0f, gy = 0.0f, gz = 0.0f;
        bool done = false;
        for (int it = 0; it < 3; ++it) {
            if (done) break;
            float sw=0, swf=0, sgx=0, sgy=0, sgz=0, sfx=0, sfy=0, sfz=0, snx=0, sny=0, snz=0;
            #pragma unroll
            for (int u = 0; u < 4; ++u) {
                float alpha = 1.0f;
                if (it > 0) {
                    float dx = nx_[u]-gx, dy = ny_[u]-gy, dz = nz_[u]-gz;
                    alpha = expf(-(dx*dx + dy*dy + dz*dz) * inv_sn2);
                }
                float w = alpha * phi_[u];
                float g = alpha * gco_[u];
                float gf = g * fx_[u];
                sw  += w;          swf += w * fx_[u];
                sgx += g*px_[u];   sgy += g*py_[u];   sgz += g*pz_[u];
                sfx += gf*px_[u];  sfy += gf*py_[u];  sfz += gf*pz_[u];
                snx += w*nx_[u];   sny += w*ny_[u];   snz += w*nz_[u];
            }
            #pragma unroll
            for (int m = 1; m < 8; m <<= 1) {
                sw  += __shfl_xor(sw, m);  swf += __shfl_xor(swf, m);
                sgx += __shfl_xor(sgx, m); sgy += __shfl_xor(sgy, m); sgz += __shfl_xor(sgz, m);
                sfx += __shfl_xor(sfx, m); sfy += __shfl_xor(sfy, m); sfz += __shfl_xor(sfz, m);
                snx += __shfl_xor(snx, m); sny += __shfl_xor(sny, m); snz += __shfl_xor(snz, m);
            }
            sw += 1e-8f;
            float fn  = swf / sw;
            float gnx = (sfx + snx - fn*sgx) / sw;
            float gny = (sfy + sny - fn*sgy) / sw;
            float gnz = (sfz + snz - fn*sgz) / sw;
            float delta = fabsf(fn - f);
            f = fn; gx = gnx; gy = gny; gz = gnz;
            done = (delta < THRESHV);
        }
        if (s8 == 0) {
            int gq = blockIdx.x * QT + qs;
            if (gq < N) {
                out[gq] = f;
                out[N + 3*gq + 0] = gx;
                out[N + 3*gq + 1] = gy;
                out[N + 3*gq + 2] = gz;
            }
        }
    }
}

// ============================================================
// ===============  GRID KNN PATH  ============================
// ============================================================

__device__ __forceinline__ unsigned int enc_f(float f) {
    unsigned int b = __float_as_uint(f);
    return (b & 0x80000000u) ? ~b : (b | 0x80000000u);
}
__device__ __forceinline__ float dec_f(unsigned int u) {
    unsigned int b = (u & 0x80000000u) ? (u ^ 0x80000000u) : ~u;
    return __uint_as_float(b);
}
__device__ __forceinline__ int cell_of(float v, float mn, float ics) {
    int c = (int)floorf((v - mn) * ics);
    return c < 0 ? 0 : (c >= RG ? RG-1 : c);
}

__global__ void grid_init(unsigned int* __restrict__ offs, unsigned int* __restrict__ aux,
                          unsigned int* __restrict__ bbox) {
    int i = blockIdx.x * 256 + threadIdx.x;
    if (i < NC) offs[i] = 0u;
    if (i < 256) aux[i] = 0u;
    if (i < 6) bbox[i] = (i < 3) ? 0xFFFFFFFFu : 0u;
}

__global__ void grid_bbox(const float* __restrict__ sv, unsigned int* __restrict__ bbox, int M) {
    int i = blockIdx.x * 256 + threadIdx.x;
    unsigned int mn0=0xFFFFFFFFu, mn1=0xFFFFFFFFu, mn2=0xFFFFFFFFu;
    unsigned int mx0=0u, mx1=0u, mx2=0u;
    if (i < M) {
        unsigned int e0 = enc_f(sv[3*i+0]);
        unsigned int e1 = enc_f(sv[3*i+1]);
        unsigned int e2 = enc_f(sv[3*i+2]);
        mn0=e0; mn1=e1; mn2=e2; mx0=e0; mx1=e1; mx2=e2;
    }
    for (int off = 1; off < 64; off <<= 1) {
        mn0 = min(mn0, (unsigned int)__shfl_xor(mn0, off));
        mn1 = min(mn1, (unsigned int)__shfl_xor(mn1, off));
        mn2 = min(mn2, (unsigned int)__shfl_xor(mn2, off));
        mx0 = max(mx0, (unsigned int)__shfl_xor(mx0, off));
        mx1 = max(mx1, (unsigned int)__shfl_xor(mx1, off));
        mx2 = max(mx2, (unsigned int)__shfl_xor(mx2, off));
    }
    if ((threadIdx.x & 63) == 0) {
        atomicMin(&bbox[0], mn0); atomicMin(&bbox[1], mn1); atomicMin(&bbox[2], mn2);
        atomicMax(&bbox[3], mx0); atomicMax(&bbox[4], mx1); atomicMax(&bbox[5], mx2);
    }
}

__global__ void grid_params(const unsigned int* __restrict__ bbox, float* __restrict__ gp) {
    if (threadIdx.x != 0 || blockIdx.x != 0) return;
    float csmin = 1e30f, vcell = 1.0f;
    for (int a = 0; a < 3; ++a) {
        float mn = dec_f(bbox[a]), mx = dec_f(bbox[3+a]);
        float span = mx - mn;
        if (!(span > 1e-5f)) span = 1e-5f;
        float cs = span / (float)RG;
        gp[a] = mn; gp[3+a] = cs; gp[6+a] = 1.0f / cs;
        csmin = fminf(csmin, cs); vcell *= cs;
    }
    gp[9]  = 1.0f / csmin;
    gp[10] = vcell;
}

__global__ void grid_count(const float* __restrict__ sv, const float* __restrict__ gp,
                           unsigned int* __restrict__ offs, int M) {
    int i = blockIdx.x * 256 + threadIdx.x;
    if (i >= M) return;
    int cx = cell_of(sv[3*i+0], gp[0], gp[6]);
    int cy = cell_of(sv[3*i+1], gp[1], gp[7]);
    int cz = cell_of(sv[3*i+2], gp[2], gp[8]);
    atomicAdd(&offs[(cz*RG + cy)*RG + cx], 1u);
}

__global__ void grid_scan_tile(unsigned int* __restrict__ offs, unsigned int* __restrict__ aux) {
    __shared__ unsigned int sm[256];
    const int tid = threadIdx.x;
    const int base = blockIdx.x * 1024 + tid * 4;
    uint4 v = *(const uint4*)&offs[base];
    v.y += v.x; v.z += v.y; v.w += v.z;
    sm[tid] = v.w;
    __syncthreads();
    for (int off = 1; off < 256; off <<= 1) {
        unsigned int add = (tid >= off) ? sm[tid - off] : 0u;
        __syncthreads();
        sm[tid] += add;
        __syncthreads();
    }
    unsigned int add = tid ? sm[tid-1] : 0u;
    v.x += add; v.y += add; v.z += add; v.w += add;
    *(uint4*)&offs[base] = v;
    if (tid == 255) aux[blockIdx.x] = sm[255];
}

__global__ void grid_scan_aux(unsigned int* __restrict__ aux) {
    __shared__ unsigned int sm[256];
    const int tid = threadIdx.x;
    sm[tid] = aux[tid];
    __syncthreads();
    for (int off = 1; off < 256; off <<= 1) {
        unsigned int add = (tid >= off) ? sm[tid - off] : 0u;
        __syncthreads();
        sm[tid] += add;
        __syncthreads();
    }
    aux[tid] = tid ? sm[tid-1] : 0u;
}

__global__ void grid_scan_add(unsigned int* __restrict__ offs, const unsigned int* __restrict__ aux) {
    __shared__ unsigned int sm[1024];
    const int tid = threadIdx.x;
    const int base = blockIdx.x * 1024;
    uint4 v = *(const uint4*)&offs[base + tid*4];
    sm[tid*4+0] = v.x; sm[tid*4+1] = v.y; sm[tid*4+2] = v.z; sm[tid*4+3] = v.w;
    __syncthreads();
    unsigned int a = aux[blockIdx.x];
    uint4 o;
    o.x = a + (tid ? sm[tid*4-1] : 0u);
    o.y = a + sm[tid*4+0];
    o.z = a + sm[tid*4+1];
    o.w = a + sm[tid*4+2];
    *(uint4*)&offs[base + tid*4] = o;
}

__global__ void grid_scatter(const float* __restrict__ sv, const float* __restrict__ gp,
                             unsigned int* __restrict__ offs, float4* __restrict__ spts, int M) {
    int i = blockIdx.x * 256 + threadIdx.x;
    if (i >= M) return;
    float x = sv[3*i+0], y = sv[3*i+1], z = sv[3*i+2];
    int cx = cell_of(x, gp[0], gp[6]);
    int cy = cell_of(y, gp[1], gp[7]);
    int cz = cell_of(z, gp[2], gp[8]);
    unsigned int pos = atomicAdd(&offs[(cz*RG + cy)*RG + cx], 1u);
    spts[pos] = make_float4(x, y, z, __uint_as_float((unsigned int)i));
}

__global__ __launch_bounds__(NTH2)
void rimls_grid(const float* __restrict__ qpts,
                const float* __restrict__ sverts,
                const float* __restrict__ snorms,
                const float4* __restrict__ spts,
                const unsigned int* __restrict__ cellend,   // post-scatter: cellend[c] = end(c)
                const float* __restrict__ gp,
                float* __restrict__ out,
                int N)
{
    __shared__ unsigned int cand[QT2*CAPS2];   // 24704 B
    __shared__ unsigned int selk[QT2*KNN];     // 3840 B
    __shared__ float qsx[QT2], qsy[QT2], qsz[QT2];
    __shared__ float Tq[QT2], Tcq[QT2];
    __shared__ unsigned int cntq[QT2];
    __shared__ int retq[QT2];

    const int t = threadIdx.x;
    const int q = t >> 3;
    const int l = t & 7;

    if (t < QT2) {
        int gq = blockIdx.x * QT2 + t; if (gq >= N) gq = N - 1;
        qsx[t] = qpts[3*gq+0]; qsy[t] = qpts[3*gq+1]; qsz[t] = qpts[3*gq+2];
    }
    for (int i = t; i < QT2*KNN; i += NTH2) selk[i] = 0u;
    __syncthreads();

    const float gx0 = gp[0], gy0 = gp[1], gz0 = gp[2];
    const float csx = gp[3], csy = gp[4], csz = gp[5];
    const float icx = gp[6], icy = gp[7], icz = gp[8];
    const float icsmin = gp[9], vcell = gp[10];

    const float qx = qsx[q], qy = qsy[q], qz = qsz[q];
    int qcx = (int)floorf((qx - gx0) * icx); qcx = qcx < 0 ? 0 : (qcx >= RG ? RG-1 : qcx);
    int qcy = (int)floorf((qy - gy0) * icy); qcy = qcy < 0 ? 0 : (qcy >= RG ? RG-1 : qcy);
    int qcz = (int)floorf((qz - gz0) * icz); qcz = qcz < 0 ? 0 : (qcz >= RG ? RG-1 : qcz);

    // ---- phase A: grow cell box until it holds >= KNN points (counts only) ----
    int S0 = 0; unsigned int cbox = 0;
    for (int s = 0; s <= RG; ++s) {
        unsigned int csum = 0u;
        int B = 2*s + 1;
        int dx = -s + l, dy = -s, dz = -s;
        while (dx > s) { dx -= B; ++dy; }
        while (dy > s) { dy -= B; ++dz; }
        while (dz <= s) {
            int cx = qcx + dx, cy = qcy + dy, cz = qcz + dz;
            if ((unsigned)cx < (unsigned)RG && (unsigned)cy < (unsigned)RG && (unsigned)cz < (unsigned)RG) {
                int c = (cz*RG + cy)*RG + cx;
                unsigned int e_ = cellend[c];
                unsigned int b_ = c ? cellend[c-1] : 0u;
                csum += e_ - b_;
            }
            dx += 8;
            while (dx > s) { dx -= B; ++dy; }
            while (dy > s) { dy -= B; ++dz; }
        }
        csum += __shfl_xor(csum, 1);
        csum += __shfl_xor(csum, 2);
        csum += __shfl_xor(csum, 4);
        if (csum >= (unsigned)KNN) { S0 = s; cbox = csum; break; }
    }

    // threshold cap (rigorous: all cbox points lie within this radius) + density estimate
    {
        float blx = gx0 + (float)(qcx - S0) * csx, bhx = gx0 + (float)(qcx + S0 + 1) * csx;
        float bly = gy0 + (float)(qcy - S0) * csy, bhy = gy0 + (float)(qcy + S0 + 1) * csy;
        float blz = gz0 + (float)(qcz - S0) * csz, bhz = gz0 + (float)(qcz + S0 + 1) * csz;
        float dfx = fmaxf(qx - blx, bhx - qx);
        float dfy = fmaxf(qy - bly, bhy - qy);
        float dfz = fmaxf(qz - blz, bhz - qz);
        float tc = sqrtf(dfx*dfx + dfy*dfy + dfz*dfz) * 1.0001f + 1e-6f;
        float fb = (float)(2*S0 + 1); fb = fb*fb*fb;
        float t0 = cbrtf(TGT * vcell * fb / (4.18879f * (float)cbox));
        if (t0 > tc) t0 = tc;
        if (l == 0) { Tq[q] = t0; Tcq[q] = tc; cntq[q] = 0u; retq[q] = 1; }
    }
    __syncthreads();

    // ---- phase B: threshold collection over pruned cells, with retry ----
    for (int round = 0; round < 8; ++round) {
        if (retq[q]) {
            float T = Tq[q], T2 = T*T;
            int smax = (int)(T * icsmin) + 1; if (smax > RG) smax = RG;
            int B = 2*smax + 1;
            int dx = -smax + l, dy = -smax, dz = -smax;
            while (dx > smax) { dx -= B; ++dy; }
            while (dy > smax) { dy -= B; ++dz; }
            while (dz <= smax) {
                int cx = qcx + dx, cy = qcy + dy, cz = qcz + dz;
                if ((unsigned)cx < (unsigned)RG && (unsigned)cy < (unsigned)RG && (unsigned)cz < (unsigned)RG) {
                    float lox = gx0 + (float)cx * csx;
                    float loy = gy0 + (float)cy * csy;
                    float loz = gz0 + (float)cz * csz;
                    float ax_ = fmaxf(0.0f, fmaxf(lox - qx, qx - lox - csx));
                    float ay_ = fmaxf(0.0f, fmaxf(loy - qy, qy - loy - csy));
                    float az_ = fmaxf(0.0f, fmaxf(loz - qz, qz - loz - csz));
                    float md2 = fmaf(ax_, ax_, fmaf(ay_, ay_, az_*az_));
                    if (md2 < T2) {
                        int c = (cz*RG + cy)*RG + cx;
                        unsigned int e_ = cellend[c];
                        unsigned int b_ = c ? cellend[c-1] : 0u;
                        for (unsigned int p = b_; p < e_; ++p) {
                            float4 sp = spts[p];
                            float ex = qx - sp.x, ey = qy - sp.y, ez = qz - sp.z;
                            float d2 = fmaf(ex, ex, fmaf(ey, ey, ez*ez));
                            if (d2 < T2) {
                                unsigned int pos = atomicAdd(&cntq[q], 1u);
                                if (pos < (unsigned)CAP2)
                                    cand[q*CAPS2 + pos] = (__float_as_uint(d2) & 0xFFFF0000u)
                                                        | (__float_as_uint(sp.w) & 0xFFFFu);
                            }
                        }
                    }
                }
                dx += 8;
                while (dx > smax) { dx -= B; ++dy; }
                while (dy > smax) { dy -= B; ++dz; }
            }
        }
        __syncthreads();
        int bad = 0;
        if (t < QT2 && retq[t]) {
            unsigned int c_ = cntq[t];
            if (c_ >= (unsigned)KNN && c_ <= (unsigned)CAP2) retq[t] = 0;
            else {
                float T = Tq[t];
                float sc = cbrtf(TGT / (float)(c_ ? c_ : 1u));
                sc = fminf(fmaxf(sc, 0.45f), 2.5f);
                Tq[t] = fminf(T * sc, Tcq[t]);
                cntq[t] = 0u; bad = 1;
            }
        }
        if (!__syncthreads_or(bad)) break;
    }

    // ---- phase C: exact rank-select of KNN smallest keys (8 lanes/query) ----
    {
        unsigned int cc = cntq[q];
        int C = (int)(cc < (unsigned)CAP2 ? cc : (unsigned)CAP2);
        const unsigned int* cd = cand + q * CAPS2;
        for (int a = l; a < C; a += 8) {
            unsigned int ka = cd[a]; int r = 0;
            for (int b = 0; b < C; ++b) r += (cd[b] < ka) ? 1 : 0;
            if (r < KNN) selk[q*KNN + r] = ka;
        }
    }
    __syncthreads();

    // ---- phase D: epilogue (same math as verified kernel) ----
    {
        float px_[4], py_[4], pz_[4], nx_[4], ny_[4], nz_[4];
        float fx_[4], phi_[4], gco_[4], r2_[4];
        float dsum = 0.0f;
        #pragma unroll
        for (int u = 0; u < 4; ++u) {
            int k = l + 8*u;
            bool v = (k < KNN);
            int j = v ? (int)(selk[q*KNN + k] & 0xFFFFu) : 0;
            float sx = sverts[3*j+0], sy = sverts[3*j+1], sz = sverts[3*j+2];
            float px = qx - sx, py = qy - sy, pz = qz - sz;
            float r2 = px*px + py*py + pz*pz;
            float nx = snorms[3*j+0], ny = snorms[3*j+1], nz = snorms[3*j+2];
            float nrm = sqrtf(nx*nx + ny*ny + nz*nz);
            float inv = 1.0f / fmaxf(nrm, 1e-8f);
            float m = v ? 1.0f : 0.0f;
            nx *= inv * m; ny *= inv * m; nz *= inv * m;
            px_[u] = px * m; py_[u] = py * m; pz_[u] = pz * m;
            nx_[u] = nx; ny_[u] = ny; nz_[u] = nz;
            r2_[u] = r2 * m;
            fx_[u] = px_[u]*nx + py_[u]*ny + pz_[u]*nz;
            dsum += v ? sqrtf(r2) : 0.0f;
            phi_[u] = m;
        }
        dsum += __shfl_xor(dsum, 1);
        dsum += __shfl_xor(dsum, 2);
        dsum += __shfl_xor(dsum, 4);
        float h = dsum * (1.0f / (float)KNN) + 1e-8f;
        float h2 = h * h;
        float c8 = -8.0f / h2;
        #pragma unroll
        for (int u = 0; u < 4; ++u) {
            float tt = fmaxf(1.0f - r2_[u] / h2, 0.0f);
            float t2 = tt * tt;
            float valid = phi_[u];
            phi_[u] = t2 * t2 * valid;
            gco_[u] = c8 * t2 * tt * valid;
        }

        const float inv_sn2 = 1.0f / (SIGMA_N * SIGMA_N);
        float f = 0.0f, gx = 0.0f, gy = 0.0f, gz = 0.0f;
        bool done = false;
        for (int it = 0; it < 3; ++it) {
            if (done) break;
            float sw=0, swf=0, sgx=0, sgy=0, sgz=0, sfx=0, sfy=0, sfz=0, snx=0, sny=0, snz=0;
            #pragma unroll
            for (int u = 0; u < 4; ++u) {
                float alpha = 1.0f;
                if (it > 0) {
                    float dx = nx_[u]-gx, dy = ny_[u]-gy, dz = nz_[u]-gz;
                    alpha = expf(-(dx*dx + dy*dy + dz*dz) * inv_sn2);
                }
                float w = alpha * phi_[u];
                float g = alpha * gco_[u];
                float gf = g * fx_[u];
                sw  += w;          swf += w * fx_[u];
                sgx += g*px_[u];   sgy += g*py_[u];   sgz += g*pz_[u];
                sfx += gf*px_[u];  sfy += gf*py_[u];  sfz += gf*pz_[u];
                snx += w*nx_[u];   sny += w*ny_[u];   snz += w*nz_[u];
            }
            #pragma unroll
            for (int m = 1; m < 8; m <<= 1) {
                sw  += __shfl_xor(sw, m);  swf += __shfl_xor(swf, m);
                sgx += __shfl_xor(sgx, m); sgy += __shfl_xor(sgy, m); sgz += __shfl_xor(sgz, m);
                sfx += __shfl_xor(sfx, m); sfy += __shfl_xor(sfy, m); sfz += __shfl_xor(sfz, m);
                snx += __shfl_xor(snx, m); sny += __shfl_xor(sny, m); snz += __shfl_xor(snz, m);
            }
            sw += 1e-8f;
            float fn  = swf / sw;
            float gnx = (sfx + snx - fn*sgx) / sw;
            float gny = (sfy + sny - fn*sgy) / sw;
            float gnz = (sfz + snz - fn*sgz) / sw;
            float delta = fabsf(fn - f);
            f = fn; gx = gnx; gy = gny; gz = gnz;
            done = (delta < THRESHV);
        }
        if (l == 0) {
            int gq = blockIdx.x * QT2 + q;
            if (gq < N) {
                out[gq] = f;
                out[N + 3*gq + 0] = gx;
                out[N + 3*gq + 1] = gy;
                out[N + 3*gq + 2] = gz;
            }
        }
    }
}

// ============================================================

extern "C" void kernel_launch(void* const* d_in, const int* in_sizes, int n_in,
                              void* d_out, int out_size, void* d_ws, size_t ws_size,
                              hipStream_t stream) {
    (void)n_in; (void)out_size;
    const float* qpts   = (const float*)d_in[0];
    const float* sverts = (const float*)d_in[1];
    const float* snorms = (const float*)d_in[2];
    float* out = (float*)d_out;
    int N = in_sizes[0] / 3;
    int M = in_sizes[1] / 3;

    size_t need_grid = (size_t)M * 16 + (size_t)NC * 4 + 256 * 4 + 6 * 4 + 12 * 4;

    if (ws_size >= need_grid && M <= 65536) {
        char* w = (char*)d_ws;
        float4*       spts = (float4*)w;
        unsigned int* offs = (unsigned int*)(w + (size_t)M * 16);
        unsigned int* aux  = offs + NC;
        unsigned int* bbox = aux + 256;
        float*        gp   = (float*)(bbox + 6);

        int mb = (M + 255) / 256;
        grid_init   <<<(NC + 255) / 256, 256, 0, stream>>>(offs, aux, bbox);
        grid_bbox   <<<mb, 256, 0, stream>>>(sverts, bbox, M);
        grid_params <<<1, 64, 0, stream>>>(bbox, gp);
        grid_count  <<<mb, 256, 0, stream>>>(sverts, gp, offs, M);
        grid_scan_tile<<<NC / 1024, 256, 0, stream>>>(offs, aux);
        grid_scan_aux <<<1, 256, 0, stream>>>(aux);
        grid_scan_add <<<NC / 1024, 256, 0, stream>>>(offs, aux);
        grid_scatter<<<mb, 256, 0, stream>>>(sverts, gp, offs, spts, M);

        int blocks = (N + QT2 - 1) / QT2;
        rimls_grid<<<blocks, NTH2, 0, stream>>>(qpts, sverts, snorms, spts, offs, gp, out, N);
    } else {
        int blocks = (N + QT - 1) / QT;
        if (ws_size >= (size_t)M * sizeof(float4)) {
            float4* spack = (float4*)d_ws;
            prep_pack<<<(M + 255) / 256, 256, 0, stream>>>(sverts, spack, M);
            rimls_fused<true><<<blocks, NTH, 0, stream>>>(qpts, sverts, snorms, spack, out, N, M);
        } else {
            rimls_fused<false><<<blocks, NTH, 0, stream>>>(qpts, sverts, snorms, nullptr, out, N, M);
        }
    }
}

// Round 3
// 1342.640 us; speedup vs baseline: 2.1259x; 2.1259x over previous
//
#include <hip/hip_runtime.h>
#include <math.h>

#define KNN 30
#define SIGMA_N 0.8f
#define THRESHV 1e-3f

// ---------------- old (fallback) path constants ----------------
#define QT 32
#define NTH 256
#define CAP 160
#define CAPS 161
#define RSEL 20

// ---------------- grid path constants ----------------
#define RG 64
#define NC (RG*RG*RG)
#define RC 16                    // coarse grid (RG/4)
#define NCC (RC*RC*RC)
#define QT2 32
#define NTH2 256
#define CAP2 256
#define CAPS2 257
#define TGT 50.0f
#define MAXR 14

// ============================================================
// ===============  OLD BRUTE-FORCE PATH (fallback) ===========
// ============================================================

__global__ void prep_pack(const float* __restrict__ src, float4* __restrict__ dst, int M) {
    int j = blockIdx.x * 256 + threadIdx.x;
    if (j < M) {
        float x = src[3*j+0], y = src[3*j+1], z = src[3*j+2];
        dst[j] = make_float4(x, y, z, 0.5f*(x*x + y*y + z*z));
    }
}

template<bool PACKED>
__device__ __forceinline__ float4 fetch_pt(const float4* __restrict__ sp,
                                           const float* __restrict__ sv, int j) {
    if (PACKED) return sp[j];
    float x = sv[3*j+0], y = sv[3*j+1], z = sv[3*j+2];
    return make_float4(x, y, z, 0.5f*(x*x + y*y + z*z));
}

__device__ __forceinline__ void ins4(unsigned int k, unsigned int &m0, unsigned int &m1,
                                     unsigned int &m2, unsigned int &m3) {
    if (k < m3) {
        if (k < m2) {
            m3 = m2;
            if (k < m1) { m2 = m1; if (k < m0) { m1 = m0; m0 = k; } else m1 = k; }
            else m2 = k;
        } else m3 = k;
    }
}

template<bool PACKED>
__global__ __launch_bounds__(NTH)
void rimls_fused(const float* __restrict__ qpts,
                 const float* __restrict__ sverts,
                 const float* __restrict__ snorms,
                 const float4* __restrict__ spack,
                 float* __restrict__ out,
                 int N, int M)
{
    __shared__ unsigned int cand[QT * CAPS];
    __shared__ unsigned int selk[QT * KNN];
    __shared__ float4 qbuf[QT];
    __shared__ unsigned int cnt[QT];
    __shared__ unsigned int T16[QT];
    __shared__ int retryq[QT];

    const int t  = threadIdx.x;
    const int qg = t >> 4;
    const int c  = t & 15;
    const int qa = qg, qb = qg + 16;

    if (t < QT) {
        int gq = blockIdx.x * QT + t; if (gq >= N) gq = N - 1;
        float x = qpts[3*gq+0], y = qpts[3*gq+1], z = qpts[3*gq+2];
        qbuf[t] = make_float4(x, y, z, 0.5f*(x*x + y*y + z*z));
    }
    for (int i = t; i < QT * KNN; i += NTH) selk[i] = 0u;
    __syncthreads();

    const float ax = qbuf[qa].x, ay = qbuf[qa].y, az = qbuf[qa].z, aw = qbuf[qa].w;
    const float bx = qbuf[qb].x, by = qbuf[qb].y, bz = qbuf[qb].z, bw = qbuf[qb].w;

    unsigned int a0=~0u,a1=~0u,a2=~0u,a3=~0u, b0=~0u,b1=~0u,b2=~0u,b3=~0u;
    {
        const int n1 = M >> 6;
        #pragma unroll 2
        for (int i = 0; i < n1; ++i) {
            int j = (c + (i << 4)) << 2;
            float4 s = fetch_pt<PACKED>(spack, sverts, j);
            float va = fmaxf(fmaf(-ax, s.x, fmaf(-ay, s.y, fmaf(-az, s.z, s.w + aw))), 0.0f);
            float vb = fmaxf(fmaf(-bx, s.x, fmaf(-by, s.y, fmaf(-bz, s.z, s.w + bw))), 0.0f);
            unsigned int ka = (__float_as_uint(va) & 0xFFFF0000u) | (unsigned int)j;
            unsigned int kb = (__float_as_uint(vb) & 0xFFFF0000u) | (unsigned int)j;
            ins4(ka, a0, a1, a2, a3);
            ins4(kb, b0, b1, b2, b3);
        }
    }
    {
        unsigned int* mb = cand;
        mb[qa*64 + c*4 + 0] = a0; mb[qa*64 + c*4 + 1] = a1;
        mb[qa*64 + c*4 + 2] = a2; mb[qa*64 + c*4 + 3] = a3;
        mb[qb*64 + c*4 + 0] = b0; mb[qb*64 + c*4 + 1] = b1;
        mb[qb*64 + c*4 + 2] = b2; mb[qb*64 + c*4 + 3] = b3;
    }
    __syncthreads();
    if (t < QT) {
        const unsigned int* m_ = cand + t * 64;
        unsigned int kth = 0xFFFFFFFFu;
        for (int a = 0; a < 64; ++a) {
            unsigned int ka = m_[a]; int r = 0;
            for (int b = 0; b < 64; ++b) r += (m_[b] < ka) ? 1 : 0;
            if (r == RSEL - 1) kth = ka;
        }
        unsigned int tb = (kth >> 16) + 1u;
        if (tb > 0x7F00u) tb = 0x7F00u;
        T16[t] = tb; cnt[t] = 0u; retryq[t] = 1;
    }
    __syncthreads();

    const int n3 = M >> 4;
    for (int round = 0; round < 8; ++round) {
        bool aa = retryq[qa] != 0, ab = retryq[qb] != 0;
        if (aa || ab) {
            float Ta = aa ? __uint_as_float(T16[qa] << 16) : 0.0f;
            float Tb = ab ? __uint_as_float(T16[qb] << 16) : 0.0f;
            #pragma unroll 4
            for (int i = 0; i < n3; ++i) {
                int j = c + (i << 4);
                float4 s = fetch_pt<PACKED>(spack, sverts, j);
                float va = fmaxf(fmaf(-ax, s.x, fmaf(-ay, s.y, fmaf(-az, s.z, s.w + aw))), 0.0f);
                float vb = fmaxf(fmaf(-bx, s.x, fmaf(-by, s.y, fmaf(-bz, s.z, s.w + bw))), 0.0f);
                if (va < Ta) {
                    unsigned int pos = atomicAdd(&cnt[qa], 1u);
                    if (pos < (unsigned)CAP)
                        cand[qa*CAPS + pos] = (__float_as_uint(va) & 0xFFFF0000u) | (unsigned int)j;
                }
                if (vb < Tb) {
                    unsigned int pos = atomicAdd(&cnt[qb], 1u);
                    if (pos < (unsigned)CAP)
                        cand[qb*CAPS + pos] = (__float_as_uint(vb) & 0xFFFF0000u) | (unsigned int)j;
                }
            }
        }
        __syncthreads();
        int bad = 0;
        if (t < QT && retryq[t]) {
            unsigned int cc = cnt[t], tb = T16[t];
            if (cc < (unsigned)KNN) {
                if (tb < 0x7F00u) {
                    tb += (1u << 7);
                    if (tb > 0x7F00u) tb = 0x7F00u;
                    bad = 1;
                }
            } else if (cc > (unsigned)CAP && round < 4 && tb > (1u << 6)) {
                tb -= (1u << 6); bad = 1;
            }
            if (bad) { T16[t] = tb; cnt[t] = 0u; }
            else retryq[t] = 0;
        }
        if (!__syncthreads_or(bad)) break;
    }

    const int qs = t >> 3, s8 = t & 7;
    {
        unsigned int cc = cnt[qs];
        int C = (int)(cc < (unsigned)CAP ? cc : (unsigned)CAP);
        const unsigned int* cd = cand + qs * CAPS;
        for (int a = s8; a < C; a += 8) {
            unsigned int ka = cd[a]; int r = 0;
            for (int b = 0; b < C; ++b) r += (cd[b] < ka) ? 1 : 0;
            if (r < KNN) selk[qs*KNN + r] = ka;
        }
    }
    __syncthreads();

    {
        const float qx = qbuf[qs].x, qy = qbuf[qs].y, qz = qbuf[qs].z;
        float px_[4], py_[4], pz_[4], nx_[4], ny_[4], nz_[4];
        float fx_[4], phi_[4], gco_[4], r2_[4];
        float dsum = 0.0f;
        #pragma unroll
        for (int u = 0; u < 4; ++u) {
            int k = s8 + 8*u;
            bool v = (k < KNN);
            int j = v ? (int)(selk[qs*KNN + k] & 0xFFFFu) : 0;
            float4 s = fetch_pt<PACKED>(spack, sverts, j);
            float px = qx - s.x, py = qy - s.y, pz = qz - s.z;
            float r2 = px*px + py*py + pz*pz;
            float nx = snorms[3*j+0], ny = snorms[3*j+1], nz = snorms[3*j+2];
            float nrm = sqrtf(nx*nx + ny*ny + nz*nz);
            float inv = 1.0f / fmaxf(nrm, 1e-8f);
            float m = v ? 1.0f : 0.0f;
            nx *= inv * m; ny *= inv * m; nz *= inv * m;
            px_[u] = px * m; py_[u] = py * m; pz_[u] = pz * m;
            nx_[u] = nx; ny_[u] = ny; nz_[u] = nz;
            r2_[u] = r2 * m;
            fx_[u] = px_[u]*nx + py_[u]*ny + pz_[u]*nz;
            dsum += v ? sqrtf(r2) : 0.0f;
            phi_[u] = m;
        }
        dsum += __shfl_xor(dsum, 1);
        dsum += __shfl_xor(dsum, 2);
        dsum += __shfl_xor(dsum, 4);
        float h = dsum * (1.0f / (float)KNN) + 1e-8f;
        float h2 = h * h;
        float c8 = -8.0f / h2;
        #pragma unroll
        for (int u = 0; u < 4; ++u) {
            float tt = fmaxf(1.0f - r2_[u] / h2, 0.0f);
            float t2 = tt * tt;
            float valid = phi_[u];
            phi_[u] = t2 * t2 * valid;
            gco_[u] = c8 * t2 * tt * valid;
        }

        const float inv_sn2 = 1.0f / (SIGMA_N * SIGMA_N);
        float f = 0.0f, gx = 0.0f, gy = 0.0f, gz = 0.0f;
        bool done = false;
        for (int it = 0; it < 3; ++it) {
            if (done) break;
            float sw=0, swf=0, sgx=0, sgy=0, sgz=0, sfx=0, sfy=0, sfz=0, snx=0, sny=0, snz=0;
            #pragma unroll
            for (int u = 0; u < 4; ++u) {
                float alpha = 1.0f;
                if (it > 0) {
                    float dx = nx_[u]-gx, dy = ny_[u]-gy, dz = nz_[u]-gz;
                    alpha = expf(-(dx*dx + dy*dy + dz*dz) * inv_sn2);
                }
                float w = alpha * phi_[u];
                float g = alpha * gco_[u];
                float gf = g * fx_[u];
                sw  += w;          swf += w * fx_[u];
                sgx += g*px_[u];   sgy += g*py_[u];   sgz += g*pz_[u];
                sfx += gf*px_[u];  sfy += gf*py_[u];  sfz += gf*pz_[u];
                snx += w*nx_[u];   sny += w*ny_[u];   snz += w*nz_[u];
            }
            #pragma unroll
            for (int m = 1; m < 8; m <<= 1) {
                sw  += __shfl_xor(sw, m);  swf += __shfl_xor(swf, m);
                sgx += __shfl_xor(sgx, m); sgy += __shfl_xor(sgy, m); sgz += __shfl_xor(sgz, m);
                sfx += __shfl_xor(sfx, m); sfy += __shfl_xor(sfy, m); sfz += __shfl_xor(sfz, m);
                snx += __shfl_xor(snx, m); sny += __shfl_xor(sny, m); snz += __shfl_xor(snz, m);
            }
            sw += 1e-8f;
            float fn  = swf / sw;
            float gnx = (sfx + snx - fn*sgx) / sw;
            float gny = (sfy + sny - fn*sgy) / sw;
            float gnz = (sfz + snz - fn*sgz) / sw;
            float delta = fabsf(fn - f);
            f = fn; gx = gnx; gy = gny; gz = gnz;
            done = (delta < THRESHV);
        }
        if (s8 == 0) {
            int gq = blockIdx.x * QT + qs;
            if (gq < N) {
                out[gq] = f;
                out[N + 3*gq + 0] = gx;
                out[N + 3*gq + 1] = gy;
                out[N + 3*gq + 2] = gz;
            }
        }
    }
}

// ============================================================
// ===============  GRID KNN PATH  ============================
// ============================================================

__device__ __forceinline__ unsigned int enc_f(float f) {
    unsigned int b = __float_as_uint(f);
    return (b & 0x80000000u) ? ~b : (b | 0x80000000u);
}
__device__ __forceinline__ float dec_f(unsigned int u) {
    unsigned int b = (u & 0x80000000u) ? (u ^ 0x80000000u) : ~u;
    return __uint_as_float(b);
}
__device__ __forceinline__ int cell_of(float v, float mn, float ics) {
    int c = (int)floorf((v - mn) * ics);
    return c < 0 ? 0 : (c >= RG ? RG-1 : c);
}

__global__ void grid_init(unsigned int* __restrict__ offs, unsigned int* __restrict__ aux,
                          unsigned int* __restrict__ bbox, unsigned int* __restrict__ coarse) {
    int i = blockIdx.x * 256 + threadIdx.x;
    if (i < NC) offs[i] = 0u;
    if (i < NCC) coarse[i] = 0u;
    if (i < 256) aux[i] = 0u;
    if (i < 6) bbox[i] = (i < 3) ? 0xFFFFFFFFu : 0u;
}

__global__ void grid_bbox(const float* __restrict__ sv, unsigned int* __restrict__ bbox, int M) {
    int i = blockIdx.x * 256 + threadIdx.x;
    unsigned int mn0=0xFFFFFFFFu, mn1=0xFFFFFFFFu, mn2=0xFFFFFFFFu;
    unsigned int mx0=0u, mx1=0u, mx2=0u;
    if (i < M) {
        unsigned int e0 = enc_f(sv[3*i+0]);
        unsigned int e1 = enc_f(sv[3*i+1]);
        unsigned int e2 = enc_f(sv[3*i+2]);
        mn0=e0; mn1=e1; mn2=e2; mx0=e0; mx1=e1; mx2=e2;
    }
    for (int off = 1; off < 64; off <<= 1) {
        mn0 = min(mn0, (unsigned int)__shfl_xor(mn0, off));
        mn1 = min(mn1, (unsigned int)__shfl_xor(mn1, off));
        mn2 = min(mn2, (unsigned int)__shfl_xor(mn2, off));
        mx0 = max(mx0, (unsigned int)__shfl_xor(mx0, off));
        mx1 = max(mx1, (unsigned int)__shfl_xor(mx1, off));
        mx2 = max(mx2, (unsigned int)__shfl_xor(mx2, off));
    }
    if ((threadIdx.x & 63) == 0) {
        atomicMin(&bbox[0], mn0); atomicMin(&bbox[1], mn1); atomicMin(&bbox[2], mn2);
        atomicMax(&bbox[3], mx0); atomicMax(&bbox[4], mx1); atomicMax(&bbox[5], mx2);
    }
}

__global__ void grid_params(const unsigned int* __restrict__ bbox, float* __restrict__ gp) {
    if (threadIdx.x != 0 || blockIdx.x != 0) return;
    float csmin = 1e30f, vcell = 1.0f;
    for (int a = 0; a < 3; ++a) {
        float mn = dec_f(bbox[a]), mx = dec_f(bbox[3+a]);
        float span = mx - mn;
        if (!(span > 1e-5f)) span = 1e-5f;
        float cs = span / (float)RG;
        gp[a] = mn; gp[3+a] = cs; gp[6+a] = 1.0f / cs;
        csmin = fminf(csmin, cs); vcell *= cs;
    }
    gp[9]  = 1.0f / csmin;
    gp[10] = vcell;
}

__global__ void grid_count(const float* __restrict__ sv, const float* __restrict__ gp,
                           unsigned int* __restrict__ offs, unsigned int* __restrict__ coarse,
                           int M) {
    int i = blockIdx.x * 256 + threadIdx.x;
    if (i >= M) return;
    int cx = cell_of(sv[3*i+0], gp[0], gp[6]);
    int cy = cell_of(sv[3*i+1], gp[1], gp[7]);
    int cz = cell_of(sv[3*i+2], gp[2], gp[8]);
    atomicAdd(&offs[(cz*RG + cy)*RG + cx], 1u);
    atomicAdd(&coarse[((cz>>2)*RC + (cy>>2))*RC + (cx>>2)], 1u);
}

__global__ void grid_scan_tile(unsigned int* __restrict__ offs, unsigned int* __restrict__ aux) {
    __shared__ unsigned int sm[256];
    const int tid = threadIdx.x;
    const int base = blockIdx.x * 1024 + tid * 4;
    uint4 v = *(const uint4*)&offs[base];
    v.y += v.x; v.z += v.y; v.w += v.z;
    sm[tid] = v.w;
    __syncthreads();
    for (int off = 1; off < 256; off <<= 1) {
        unsigned int add = (tid >= off) ? sm[tid - off] : 0u;
        __syncthreads();
        sm[tid] += add;
        __syncthreads();
    }
    unsigned int add = tid ? sm[tid-1] : 0u;
    v.x += add; v.y += add; v.z += add; v.w += add;
    *(uint4*)&offs[base] = v;
    if (tid == 255) aux[blockIdx.x] = sm[255];
}

__global__ void grid_scan_aux(unsigned int* __restrict__ aux) {
    __shared__ unsigned int sm[256];
    const int tid = threadIdx.x;
    sm[tid] = aux[tid];
    __syncthreads();
    for (int off = 1; off < 256; off <<= 1) {
        unsigned int add = (tid >= off) ? sm[tid - off] : 0u;
        __syncthreads();
        sm[tid] += add;
        __syncthreads();
    }
    aux[tid] = tid ? sm[tid-1] : 0u;
}

__global__ void grid_scan_add(unsigned int* __restrict__ offs, const unsigned int* __restrict__ aux) {
    __shared__ unsigned int sm[1024];
    const int tid = threadIdx.x;
    const int base = blockIdx.x * 1024;
    uint4 v = *(const uint4*)&offs[base + tid*4];
    sm[tid*4+0] = v.x; sm[tid*4+1] = v.y; sm[tid*4+2] = v.z; sm[tid*4+3] = v.w;
    __syncthreads();
    unsigned int a = aux[blockIdx.x];
    uint4 o;
    o.x = a + (tid ? sm[tid*4-1] : 0u);
    o.y = a + sm[tid*4+0];
    o.z = a + sm[tid*4+1];
    o.w = a + sm[tid*4+2];
    *(uint4*)&offs[base + tid*4] = o;
}

__global__ void grid_scatter(const float* __restrict__ sv, const float* __restrict__ gp,
                             unsigned int* __restrict__ offs, float4* __restrict__ spts, int M) {
    int i = blockIdx.x * 256 + threadIdx.x;
    if (i >= M) return;
    float x = sv[3*i+0], y = sv[3*i+1], z = sv[3*i+2];
    int cx = cell_of(x, gp[0], gp[6]);
    int cy = cell_of(y, gp[1], gp[7]);
    int cz = cell_of(z, gp[2], gp[8]);
    unsigned int pos = atomicAdd(&offs[(cz*RG + cy)*RG + cx], 1u);
    spts[pos] = make_float4(x, y, z, __uint_as_float((unsigned int)i));
}

__device__ __forceinline__ void scan_cell(const float4* __restrict__ spts,
                                          const unsigned int* __restrict__ cellend,
                                          int c, float qx, float qy, float qz, float T2,
                                          unsigned int* cntp, unsigned int* candp) {
    unsigned int e_ = cellend[c];
    unsigned int b_ = c ? cellend[c-1] : 0u;
    for (unsigned int p = b_; p < e_; ++p) {
        float4 sp = spts[p];
        float ex = qx - sp.x, ey = qy - sp.y, ez = qz - sp.z;
        float d2 = fmaf(ex, ex, fmaf(ey, ey, ez*ez));
        if (d2 < T2) {
            unsigned int pos = atomicAdd(cntp, 1u);
            if (pos < (unsigned)CAP2)
                candp[pos] = (__float_as_uint(d2) & 0xFFFF0000u) | (__float_as_uint(sp.w) & 0xFFFFu);
        }
    }
}

__global__ __launch_bounds__(NTH2)
void rimls_grid(const float* __restrict__ qpts,
                const float* __restrict__ sverts,
                const float* __restrict__ snorms,
                const float4* __restrict__ spts,
                const unsigned int* __restrict__ cellend,   // post-scatter: cellend[c] = end(c)
                const unsigned int* __restrict__ coarse,    // coarse cell point counts
                const float* __restrict__ gp,
                float* __restrict__ out,
                int N)
{
    __shared__ unsigned int cand[QT2*CAPS2];   // 32896 B
    __shared__ unsigned int selk[QT2*KNN];     // 3840 B
    __shared__ unsigned int ccnt[NCC];         // 16384 B — coarse counts, block-shared
    __shared__ float qsx[QT2], qsy[QT2], qsz[QT2];
    __shared__ float Tq[QT2], Tcq[QT2], Tloq[QT2], Thiq[QT2];
    __shared__ unsigned int cntq[QT2];
    __shared__ int retq[QT2];

    const int t = threadIdx.x;
    const int q = t >> 3;
    const int l = t & 7;

    if (t < QT2) {
        int gq = blockIdx.x * QT2 + t; if (gq >= N) gq = N - 1;
        qsx[t] = qpts[3*gq+0]; qsy[t] = qpts[3*gq+1]; qsz[t] = qpts[3*gq+2];
    }
    for (int i = t; i < QT2*KNN; i += NTH2) selk[i] = 0u;
    for (int i = t; i < NCC; i += NTH2) ccnt[i] = coarse[i];
    __syncthreads();

    const float gx0 = gp[0], gy0 = gp[1], gz0 = gp[2];
    const float csx = gp[3], csy = gp[4], csz = gp[5];
    const float icx = gp[6], icy = gp[7], icz = gp[8];
    const float icsmin = gp[9], vcell = gp[10];

    const float qx = qsx[q], qy = qsy[q], qz = qsz[q];
    int qcx = (int)floorf((qx - gx0) * icx); qcx = qcx < 0 ? 0 : (qcx >= RG ? RG-1 : qcx);
    int qcy = (int)floorf((qy - gy0) * icy); qcy = qcy < 0 ? 0 : (qcy >= RG ? RG-1 : qcy);
    int qcz = (int)floorf((qz - gz0) * icz); qcz = qcz < 0 ? 0 : (qcz >= RG ? RG-1 : qcz);

    // ---- phase A: grow COARSE cell box (LDS counts) until >= KNN points ----
    const int qccx = qcx >> 2, qccy = qcy >> 2, qccz = qcz >> 2;
    int S0 = 0; unsigned int cbox = 0;
    for (int s = 0; s < RC; ++s) {
        int lx = qccx - s; if (lx < 0) lx = 0;
        int hx = qccx + s; if (hx > RC-1) hx = RC-1;
        int ly = qccy - s; if (ly < 0) ly = 0;
        int hy = qccy + s; if (hy > RC-1) hy = RC-1;
        int lz = qccz - s; if (lz < 0) lz = 0;
        int hz = qccz + s; if (hz > RC-1) hz = RC-1;
        int nx = hx-lx+1, ny = hy-ly+1, nz = hz-lz+1;
        int nxy = nx*ny, tot = nxy*nz;
        unsigned int csum = 0u;
        for (int i = l; i < tot; i += 8) {
            int iz = i / nxy; int r = i - iz*nxy; int iy = r / nx; int ix = r - iy*nx;
            csum += ccnt[((lz+iz)*RC + (ly+iy))*RC + (lx+ix)];
        }
        csum += __shfl_xor(csum, 1);
        csum += __shfl_xor(csum, 2);
        csum += __shfl_xor(csum, 4);
        if (csum >= (unsigned)KNN || s == RC-1) { S0 = s; cbox = (csum ? csum : 1u); break; }
    }

    // threshold cap (rigorous: all cbox points lie within this radius) + density estimate
    {
        float ccsx = 4.0f*csx, ccsy = 4.0f*csy, ccsz = 4.0f*csz;
        float blx = gx0 + (float)(qccx - S0) * ccsx, bhx = gx0 + (float)(qccx + S0 + 1) * ccsx;
        float bly = gy0 + (float)(qccy - S0) * ccsy, bhy = gy0 + (float)(qccy + S0 + 1) * ccsy;
        float blz = gz0 + (float)(qccz - S0) * ccsz, bhz = gz0 + (float)(qccz + S0 + 1) * ccsz;
        float dfx = fmaxf(qx - blx, bhx - qx);
        float dfy = fmaxf(qy - bly, bhy - qy);
        float dfz = fmaxf(qz - blz, bhz - qz);
        float tc = sqrtf(dfx*dfx + dfy*dfy + dfz*dfz) * 1.0001f + 1e-6f;
        int nxc = ((qccx+S0 > RC-1) ? RC-1 : qccx+S0) - ((qccx-S0 < 0) ? 0 : qccx-S0) + 1;
        int nyc = ((qccy+S0 > RC-1) ? RC-1 : qccy+S0) - ((qccy-S0 < 0) ? 0 : qccy-S0) + 1;
        int nzc = ((qccz+S0 > RC-1) ? RC-1 : qccz+S0) - ((qccz-S0 < 0) ? 0 : qccz-S0) + 1;
        float vol = (float)(nxc*nyc*nzc) * vcell * 64.0f;
        float t0 = cbrtf(TGT * vol / (4.18879f * (float)cbox));
        if (t0 > tc) t0 = tc;
        if (l == 0) {
            Tq[q] = t0; Tcq[q] = tc; Tloq[q] = 0.0f; Thiq[q] = 0.0f;
            cntq[q] = 0u; retq[q] = 1;
        }
    }
    __syncthreads();

    // ---- phase B: hybrid pruned collection + geometric bracket bisection retry ----
    for (int round = 0; round < MAXR; ++round) {
        if (retq[q]) {
            float T = Tq[q], T2 = T*T;
            int smaxF = (int)(T * icsmin) + 1; if (smaxF > RG) smaxF = RG;
            unsigned int* candp = cand + q*CAPS2;
            if (smaxF <= 4) {
                // ---- fine centered walk (dense-core common case), box dim <= 9 ----
                int B = 2*smaxF + 1, B2 = B*B, tot = B*B2;
                for (int i = l; i < tot; i += 8) {
                    int dz = i / B2; int r = i - dz*B2; int dy = r / B; int dx = r - dy*B;
                    int cx = qcx + dx - smaxF, cy = qcy + dy - smaxF, cz = qcz + dz - smaxF;
                    if ((unsigned)cx < (unsigned)RG && (unsigned)cy < (unsigned)RG && (unsigned)cz < (unsigned)RG) {
                        float lox = gx0 + (float)cx * csx;
                        float loy = gy0 + (float)cy * csy;
                        float loz = gz0 + (float)cz * csz;
                        float ax_ = fmaxf(0.0f, fmaxf(lox - qx, qx - lox - csx));
                        float ay_ = fmaxf(0.0f, fmaxf(loy - qy, qy - loy - csy));
                        float az_ = fmaxf(0.0f, fmaxf(loz - qz, qz - loz - csz));
                        float md2 = fmaf(ax_, ax_, fmaf(ay_, ay_, az_*az_));
                        if (md2 < T2) {
                            int c = (cz*RG + cy)*RG + cx;
                            scan_cell(spts, cellend, c, qx, qy, qz, T2, &cntq[q], candp);
                        }
                    }
                }
            } else {
                // ---- coarse-skip walk (sparse outlier case) ----
                int fx0 = qcx - smaxF, fx1 = qcx + smaxF;
                int fy0 = qcy - smaxF, fy1 = qcy + smaxF;
                int fz0 = qcz - smaxF, fz1 = qcz + smaxF;
                int cx0 = (fx0 < 0 ? 0 : fx0) >> 2, cx1 = (fx1 > RG-1 ? RG-1 : fx1) >> 2;
                int cy0 = (fy0 < 0 ? 0 : fy0) >> 2, cy1 = (fy1 > RG-1 ? RG-1 : fy1) >> 2;
                int cz0 = (fz0 < 0 ? 0 : fz0) >> 2, cz1 = (fz1 > RG-1 ? RG-1 : fz1) >> 2;
                int nx = cx1-cx0+1, ny = cy1-cy0+1, nz = cz1-cz0+1;
                int nxy = nx*ny, tot = nxy*nz;
                float ccsx = 4.0f*csx, ccsy = 4.0f*csy, ccsz = 4.0f*csz;
                for (int i = l; i < tot; i += 8) {
                    int iz = i / nxy; int r = i - iz*nxy; int iy = r / nx; int ix = r - iy*nx;
                    int ccx = cx0+ix, ccy = cy0+iy, ccz = cz0+iz;
                    unsigned int pc = ccnt[(ccz*RC + ccy)*RC + ccx];
                    if (!pc) continue;
                    float clx = gx0 + (float)ccx * ccsx;
                    float cly = gy0 + (float)ccy * ccsy;
                    float clz = gz0 + (float)ccz * ccsz;
                    float bx_ = fmaxf(0.0f, fmaxf(clx - qx, qx - clx - ccsx));
                    float by_ = fmaxf(0.0f, fmaxf(cly - qy, qy - cly - ccsy));
                    float bz_ = fmaxf(0.0f, fmaxf(clz - qz, qz - clz - ccsz));
                    float cmd2 = fmaf(bx_, bx_, fmaf(by_, by_, bz_*bz_));
                    if (cmd2 >= T2) continue;
                    // per-axis fine min-dist contributions for the 4x4x4 sub-cells
                    float axv[4], ayv[4], azv[4];
                    #pragma unroll
                    for (int u2 = 0; u2 < 4; ++u2) {
                        float lox = clx + (float)u2 * csx;
                        axv[u2] = fmaxf(0.0f, fmaxf(lox - qx, qx - lox - csx));
                        float loy = cly + (float)u2 * csy;
                        ayv[u2] = fmaxf(0.0f, fmaxf(loy - qy, qy - loy - csy));
                        float loz = clz + (float)u2 * csz;
                        azv[u2] = fmaxf(0.0f, fmaxf(loz - qz, qz - loz - csz));
                    }
                    int fbx = ccx << 2, fby = ccy << 2, fbz = ccz << 2;
                    #pragma unroll
                    for (int fz = 0; fz < 4; ++fz) {
                        float pz2 = azv[fz]*azv[fz];
                        #pragma unroll
                        for (int fy = 0; fy < 4; ++fy) {
                            float pyz = fmaf(ayv[fy], ayv[fy], pz2);
                            if (pyz >= T2) continue;
                            #pragma unroll
                            for (int fx = 0; fx < 4; ++fx) {
                                float md2 = fmaf(axv[fx], axv[fx], pyz);
                                if (md2 < T2) {
                                    int c = ((fbz+fz)*RG + (fby+fy))*RG + (fbx+fx);
                                    scan_cell(spts, cellend, c, qx, qy, qz, T2, &cntq[q], candp);
                                }
                            }
                        }
                    }
                }
            }
        }
        __syncthreads();
        int bad = 0;
        if (t < QT2 && retq[t]) {
            unsigned int c_ = cntq[t];
            if (c_ >= (unsigned)KNN && c_ <= (unsigned)CAP2) retq[t] = 0;
            else {
                // geometric bracket bisection: Tlo = known undershoot, Thi = known overshoot
                float T = Tq[t], tlo = Tloq[t], thi = Thiq[t], nT;
                if (c_ < (unsigned)KNN) {
                    tlo = T;
                    if (thi > 0.0f) nT = sqrtf(tlo * thi);
                    else {
                        float sc = cbrtf(TGT / (float)(c_ ? c_ : 1u));
                        sc = fminf(fmaxf(sc, 1.2f), 2.5f);
                        nT = T * sc;
                    }
                } else {   // c_ > CAP2: overshoot (candidates were truncated)
                    thi = T;
                    if (tlo > 0.0f) nT = sqrtf(tlo * thi);
                    else {
                        float sc = cbrtf(TGT / (float)c_);
                        sc = fminf(fmaxf(sc, 0.30f), 0.75f);
                        nT = T * sc;
                    }
                }
                nT = fminf(nT, Tcq[t]);
                Tq[t] = nT; Tloq[t] = tlo; Thiq[t] = thi;
                cntq[t] = 0u; bad = 1;
            }
        }
        if (!__syncthreads_or(bad)) break;
    }

    // ---- phase C: exact rank-select of KNN smallest keys (8 lanes/query) ----
    {
        unsigned int cc = cntq[q];
        int C = (int)(cc < (unsigned)CAP2 ? cc : (unsigned)CAP2);
        const unsigned int* cd = cand + q * CAPS2;
        for (int a = l; a < C; a += 8) {
            unsigned int ka = cd[a]; int r = 0;
            for (int b = 0; b < C; ++b) r += (cd[b] < ka) ? 1 : 0;
            if (r < KNN) selk[q*KNN + r] = ka;
        }
    }
    __syncthreads();

    // ---- phase D: epilogue (same math as verified kernel) ----
    {
        // belt: if a query somehow didn't converge, only use the neighbors we have
        unsigned int ccq = cntq[q];
        int Cq = (int)(ccq < (unsigned)CAP2 ? ccq : (unsigned)CAP2);
        int kmax = Cq < KNN ? Cq : KNN;

        float px_[4], py_[4], pz_[4], nx_[4], ny_[4], nz_[4];
        float fx_[4], phi_[4], gco_[4], r2_[4];
        float dsum = 0.0f;
        #pragma unroll
        for (int u = 0; u < 4; ++u) {
            int k = l + 8*u;
            bool v = (k < kmax);
            int j = v ? (int)(selk[q*KNN + k] & 0xFFFFu) : 0;
            float sx = sverts[3*j+0], sy = sverts[3*j+1], sz = sverts[3*j+2];
            float px = qx - sx, py = qy - sy, pz = qz - sz;
            float r2 = px*px + py*py + pz*pz;
            float nx = snorms[3*j+0], ny = snorms[3*j+1], nz = snorms[3*j+2];
            float nrm = sqrtf(nx*nx + ny*ny + nz*nz);
            float inv = 1.0f / fmaxf(nrm, 1e-8f);
            float m = v ? 1.0f : 0.0f;
            nx *= inv * m; ny *= inv * m; nz *= inv * m;
            px_[u] = px * m; py_[u] = py * m; pz_[u] = pz * m;
            nx_[u] = nx; ny_[u] = ny; nz_[u] = nz;
            r2_[u] = r2 * m;
            fx_[u] = px_[u]*nx + py_[u]*ny + pz_[u]*nz;
            dsum += v ? sqrtf(r2) : 0.0f;
            phi_[u] = m;
        }
        dsum += __shfl_xor(dsum, 1);
        dsum += __shfl_xor(dsum, 2);
        dsum += __shfl_xor(dsum, 4);
        float h = dsum * (1.0f / (float)KNN) + 1e-8f;
        float h2 = h * h;
        float c8 = -8.0f / h2;
        #pragma unroll
        for (int u = 0; u < 4; ++u) {
            float tt = fmaxf(1.0f - r2_[u] / h2, 0.0f);
            float t2 = tt * tt;
            float valid = phi_[u];
            phi_[u] = t2 * t2 * valid;
            gco_[u] = c8 * t2 * tt * valid;
        }

        const float inv_sn2 = 1.0f / (SIGMA_N * SIGMA_N);
        float f = 0.0f, gx = 0.0f, gy = 0.0f, gz = 0.0f;
        bool done = false;
        for (int it = 0; it < 3; ++it) {
            if (done) break;
            float sw=0, swf=0, sgx=0, sgy=0, sgz=0, sfx=0, sfy=0, sfz=0, snx=0, sny=0, snz=0;
            #pragma unroll
            for (int u = 0; u < 4; ++u) {
                float alpha = 1.0f;
                if (it > 0) {
                    float dx = nx_[u]-gx, dy = ny_[u]-gy, dz = nz_[u]-gz;
                    alpha = expf(-(dx*dx + dy*dy + dz*dz) * inv_sn2);
                }
                float w = alpha * phi_[u];
                float g = alpha * gco_[u];
                float gf = g * fx_[u];
                sw  += w;          swf += w * fx_[u];
                sgx += g*px_[u];   sgy += g*py_[u];   sgz += g*pz_[u];
                sfx += gf*px_[u];  sfy += gf*py_[u];  sfz += gf*pz_[u];
                snx += w*nx_[u];   sny += w*ny_[u];   snz += w*nz_[u];
            }
            #pragma unroll
            for (int m = 1; m < 8; m <<= 1) {
                sw  += __shfl_xor(sw, m);  swf += __shfl_xor(swf, m);
                sgx += __shfl_xor(sgx, m); sgy += __shfl_xor(sgy, m); sgz += __shfl_xor(sgz, m);
                sfx += __shfl_xor(sfx, m); sfy += __shfl_xor(sfy, m); sfz += __shfl_xor(sfz, m);
                snx += __shfl_xor(snx, m); sny += __shfl_xor(sny, m); snz += __shfl_xor(snz, m);
            }
            sw += 1e-8f;
            float fn  = swf / sw;
            float gnx = (sfx + snx - fn*sgx) / sw;
            float gny = (sfy + sny - fn*sgy) / sw;
            float gnz = (sfz + snz - fn*sgz) / sw;
            float delta = fabsf(fn - f);
            f = fn; gx = gnx; gy = gny; gz = gnz;
            done = (delta < THRESHV);
        }
        if (l == 0) {
            int gq = blockIdx.x * QT2 + q;
            if (gq < N) {
                out[gq] = f;
                out[N + 3*gq + 0] = gx;
                out[N + 3*gq + 1] = gy;
                out[N + 3*gq + 2] = gz;
            }
        }
    }
}

// ============================================================

extern "C" void kernel_launch(void* const* d_in, const int* in_sizes, int n_in,
                              void* d_out, int out_size, void* d_ws, size_t ws_size,
                              hipStream_t stream) {
    (void)n_in; (void)out_size;
    const float* qpts   = (const float*)d_in[0];
    const float* sverts = (const float*)d_in[1];
    const float* snorms = (const float*)d_in[2];
    float* out = (float*)d_out;
    int N = in_sizes[0] / 3;
    int M = in_sizes[1] / 3;

    size_t need_grid = (size_t)M * 16 + (size_t)NC * 4 + 256 * 4 + 6 * 4 + 12 * 4 + (size_t)NCC * 4;

    if (ws_size >= need_grid && M <= 65536) {
        char* w = (char*)d_ws;
        float4*       spts   = (float4*)w;
        unsigned int* offs   = (unsigned int*)(w + (size_t)M * 16);
        unsigned int* aux    = offs + NC;
        unsigned int* bbox   = aux + 256;
        float*        gp     = (float*)(bbox + 6);
        unsigned int* coarse = (unsigned int*)(gp + 12);

        int mb = (M + 255) / 256;
        grid_init   <<<(NC + 255) / 256, 256, 0, stream>>>(offs, aux, bbox, coarse);
        grid_bbox   <<<mb, 256, 0, stream>>>(sverts, bbox, M);
        grid_params <<<1, 64, 0, stream>>>(bbox, gp);
        grid_count  <<<mb, 256, 0, stream>>>(sverts, gp, offs, coarse, M);
        grid_scan_tile<<<NC / 1024, 256, 0, stream>>>(offs, aux);
        grid_scan_aux <<<1, 256, 0, stream>>>(aux);
        grid_scan_add <<<NC / 1024, 256, 0, stream>>>(offs, aux);
        grid_scatter<<<mb, 256, 0, stream>>>(sverts, gp, offs, spts, M);

        int blocks = (N + QT2 - 1) / QT2;
        rimls_grid<<<blocks, NTH2, 0, stream>>>(qpts, sverts, snorms, spts, offs, coarse, gp, out, N);
    } else {
        int blocks = (N + QT - 1) / QT;
        if (ws_size >= (size_t)M * sizeof(float4)) {
            float4* spack = (float4*)d_ws;
            prep_pack<<<(M + 255) / 256, 256, 0, stream>>>(sverts, spack, M);
            rimls_fused<true><<<blocks, NTH, 0, stream>>>(qpts, sverts, snorms, spack, out, N, M);
        } else {
            rimls_fused<false><<<blocks, NTH, 0, stream>>>(qpts, sverts, snorms, nullptr, out, N, M);
        }
    }
}

// Round 4
// 1142.543 us; speedup vs baseline: 2.4982x; 1.1751x over previous
//
#include <hip/hip_runtime.h>
#include <math.h>

#define KNN 30
#define SIGMA_N 0.8f
#define THRESHV 1e-3f

// ---------------- old (fallback) path constants ----------------
#define QT 32
#define NTH 256
#define CAP 160
#define CAPS 161
#define RSEL 20

// ---------------- grid path constants ----------------
#define RG 64
#define NC (RG*RG*RG)
#define RC 16                    // coarse grid (RG/4)
#define NCC (RC*RC*RC)
#define QT2 32
#define NTH2 256
#define CAP2 224
#define CAPS2 225
#define TGT 50.0f
#define MAXR 14

// ============================================================
// ===============  OLD BRUTE-FORCE PATH (fallback) ===========
// ============================================================

__global__ void prep_pack(const float* __restrict__ src, float4* __restrict__ dst, int M) {
    int j = blockIdx.x * 256 + threadIdx.x;
    if (j < M) {
        float x = src[3*j+0], y = src[3*j+1], z = src[3*j+2];
        dst[j] = make_float4(x, y, z, 0.5f*(x*x + y*y + z*z));
    }
}

template<bool PACKED>
__device__ __forceinline__ float4 fetch_pt(const float4* __restrict__ sp,
                                           const float* __restrict__ sv, int j) {
    if (PACKED) return sp[j];
    float x = sv[3*j+0], y = sv[3*j+1], z = sv[3*j+2];
    return make_float4(x, y, z, 0.5f*(x*x + y*y + z*z));
}

__device__ __forceinline__ void ins4(unsigned int k, unsigned int &m0, unsigned int &m1,
                                     unsigned int &m2, unsigned int &m3) {
    if (k < m3) {
        if (k < m2) {
            m3 = m2;
            if (k < m1) { m2 = m1; if (k < m0) { m1 = m0; m0 = k; } else m1 = k; }
            else m2 = k;
        } else m3 = k;
    }
}

template<bool PACKED>
__global__ __launch_bounds__(NTH)
void rimls_fused(const float* __restrict__ qpts,
                 const float* __restrict__ sverts,
                 const float* __restrict__ snorms,
                 const float4* __restrict__ spack,
                 float* __restrict__ out,
                 int N, int M)
{
    __shared__ unsigned int cand[QT * CAPS];
    __shared__ unsigned int selk[QT * KNN];
    __shared__ float4 qbuf[QT];
    __shared__ unsigned int cnt[QT];
    __shared__ unsigned int T16[QT];
    __shared__ int retryq[QT];

    const int t  = threadIdx.x;
    const int qg = t >> 4;
    const int c  = t & 15;
    const int qa = qg, qb = qg + 16;

    if (t < QT) {
        int gq = blockIdx.x * QT + t; if (gq >= N) gq = N - 1;
        float x = qpts[3*gq+0], y = qpts[3*gq+1], z = qpts[3*gq+2];
        qbuf[t] = make_float4(x, y, z, 0.5f*(x*x + y*y + z*z));
    }
    for (int i = t; i < QT * KNN; i += NTH) selk[i] = 0u;
    __syncthreads();

    const float ax = qbuf[qa].x, ay = qbuf[qa].y, az = qbuf[qa].z, aw = qbuf[qa].w;
    const float bx = qbuf[qb].x, by = qbuf[qb].y, bz = qbuf[qb].z, bw = qbuf[qb].w;

    unsigned int a0=~0u,a1=~0u,a2=~0u,a3=~0u, b0=~0u,b1=~0u,b2=~0u,b3=~0u;
    {
        const int n1 = M >> 6;
        #pragma unroll 2
        for (int i = 0; i < n1; ++i) {
            int j = (c + (i << 4)) << 2;
            float4 s = fetch_pt<PACKED>(spack, sverts, j);
            float va = fmaxf(fmaf(-ax, s.x, fmaf(-ay, s.y, fmaf(-az, s.z, s.w + aw))), 0.0f);
            float vb = fmaxf(fmaf(-bx, s.x, fmaf(-by, s.y, fmaf(-bz, s.z, s.w + bw))), 0.0f);
            unsigned int ka = (__float_as_uint(va) & 0xFFFF0000u) | (unsigned int)j;
            unsigned int kb = (__float_as_uint(vb) & 0xFFFF0000u) | (unsigned int)j;
            ins4(ka, a0, a1, a2, a3);
            ins4(kb, b0, b1, b2, b3);
        }
    }
    {
        unsigned int* mb = cand;
        mb[qa*64 + c*4 + 0] = a0; mb[qa*64 + c*4 + 1] = a1;
        mb[qa*64 + c*4 + 2] = a2; mb[qa*64 + c*4 + 3] = a3;
        mb[qb*64 + c*4 + 0] = b0; mb[qb*64 + c*4 + 1] = b1;
        mb[qb*64 + c*4 + 2] = b2; mb[qb*64 + c*4 + 3] = b3;
    }
    __syncthreads();
    if (t < QT) {
        const unsigned int* m_ = cand + t * 64;
        unsigned int kth = 0xFFFFFFFFu;
        for (int a = 0; a < 64; ++a) {
            unsigned int ka = m_[a]; int r = 0;
            for (int b = 0; b < 64; ++b) r += (m_[b] < ka) ? 1 : 0;
            if (r == RSEL - 1) kth = ka;
        }
        unsigned int tb = (kth >> 16) + 1u;
        if (tb > 0x7F00u) tb = 0x7F00u;
        T16[t] = tb; cnt[t] = 0u; retryq[t] = 1;
    }
    __syncthreads();

    const int n3 = M >> 4;
    for (int round = 0; round < 8; ++round) {
        bool aa = retryq[qa] != 0, ab = retryq[qb] != 0;
        if (aa || ab) {
            float Ta = aa ? __uint_as_float(T16[qa] << 16) : 0.0f;
            float Tb = ab ? __uint_as_float(T16[qb] << 16) : 0.0f;
            #pragma unroll 4
            for (int i = 0; i < n3; ++i) {
                int j = c + (i << 4);
                float4 s = fetch_pt<PACKED>(spack, sverts, j);
                float va = fmaxf(fmaf(-ax, s.x, fmaf(-ay, s.y, fmaf(-az, s.z, s.w + aw))), 0.0f);
                float vb = fmaxf(fmaf(-bx, s.x, fmaf(-by, s.y, fmaf(-bz, s.z, s.w + bw))), 0.0f);
                if (va < Ta) {
                    unsigned int pos = atomicAdd(&cnt[qa], 1u);
                    if (pos < (unsigned)CAP)
                        cand[qa*CAPS + pos] = (__float_as_uint(va) & 0xFFFF0000u) | (unsigned int)j;
                }
                if (vb < Tb) {
                    unsigned int pos = atomicAdd(&cnt[qb], 1u);
                    if (pos < (unsigned)CAP)
                        cand[qb*CAPS + pos] = (__float_as_uint(vb) & 0xFFFF0000u) | (unsigned int)j;
                }
            }
        }
        __syncthreads();
        int bad = 0;
        if (t < QT && retryq[t]) {
            unsigned int cc = cnt[t], tb = T16[t];
            if (cc < (unsigned)KNN) {
                if (tb < 0x7F00u) {
                    tb += (1u << 7);
                    if (tb > 0x7F00u) tb = 0x7F00u;
                    bad = 1;
                }
            } else if (cc > (unsigned)CAP && round < 4 && tb > (1u << 6)) {
                tb -= (1u << 6); bad = 1;
            }
            if (bad) { T16[t] = tb; cnt[t] = 0u; }
            else retryq[t] = 0;
        }
        if (!__syncthreads_or(bad)) break;
    }

    const int qs = t >> 3, s8 = t & 7;
    {
        unsigned int cc = cnt[qs];
        int C = (int)(cc < (unsigned)CAP ? cc : (unsigned)CAP);
        const unsigned int* cd = cand + qs * CAPS;
        for (int a = s8; a < C; a += 8) {
            unsigned int ka = cd[a]; int r = 0;
            for (int b = 0; b < C; ++b) r += (cd[b] < ka) ? 1 : 0;
            if (r < KNN) selk[qs*KNN + r] = ka;
        }
    }
    __syncthreads();

    {
        const float qx = qbuf[qs].x, qy = qbuf[qs].y, qz = qbuf[qs].z;
        float px_[4], py_[4], pz_[4], nx_[4], ny_[4], nz_[4];
        float fx_[4], phi_[4], gco_[4], r2_[4];
        float dsum = 0.0f;
        #pragma unroll
        for (int u = 0; u < 4; ++u) {
            int k = s8 + 8*u;
            bool v = (k < KNN);
            int j = v ? (int)(selk[qs*KNN + k] & 0xFFFFu) : 0;
            float4 s = fetch_pt<PACKED>(spack, sverts, j);
            float px = qx - s.x, py = qy - s.y, pz = qz - s.z;
            float r2 = px*px + py*py + pz*pz;
            float nx = snorms[3*j+0], ny = snorms[3*j+1], nz = snorms[3*j+2];
            float nrm = sqrtf(nx*nx + ny*ny + nz*nz);
            float inv = 1.0f / fmaxf(nrm, 1e-8f);
            float m = v ? 1.0f : 0.0f;
            nx *= inv * m; ny *= inv * m; nz *= inv * m;
            px_[u] = px * m; py_[u] = py * m; pz_[u] = pz * m;
            nx_[u] = nx; ny_[u] = ny; nz_[u] = nz;
            r2_[u] = r2 * m;
            fx_[u] = px_[u]*nx + py_[u]*ny + pz_[u]*nz;
            dsum += v ? sqrtf(r2) : 0.0f;
            phi_[u] = m;
        }
        dsum += __shfl_xor(dsum, 1);
        dsum += __shfl_xor(dsum, 2);
        dsum += __shfl_xor(dsum, 4);
        float h = dsum * (1.0f / (float)KNN) + 1e-8f;
        float h2 = h * h;
        float c8 = -8.0f / h2;
        #pragma unroll
        for (int u = 0; u < 4; ++u) {
            float tt = fmaxf(1.0f - r2_[u] / h2, 0.0f);
            float t2 = tt * tt;
            float valid = phi_[u];
            phi_[u] = t2 * t2 * valid;
            gco_[u] = c8 * t2 * tt * valid;
        }

        const float inv_sn2 = 1.0f / (SIGMA_N * SIGMA_N);
        float f = 0.0f, gx = 0.0f, gy = 0.0f, gz = 0.0f;
        bool done = false;
        for (int it = 0; it < 3; ++it) {
            if (done) break;
            float sw=0, swf=0, sgx=0, sgy=0, sgz=0, sfx=0, sfy=0, sfz=0, snx=0, sny=0, snz=0;
            #pragma unroll
            for (int u = 0; u < 4; ++u) {
                float alpha = 1.0f;
                if (it > 0) {
                    float dx = nx_[u]-gx, dy = ny_[u]-gy, dz = nz_[u]-gz;
                    alpha = expf(-(dx*dx + dy*dy + dz*dz) * inv_sn2);
                }
                float w = alpha * phi_[u];
                float g = alpha * gco_[u];
                float gf = g * fx_[u];
                sw  += w;          swf += w * fx_[u];
                sgx += g*px_[u];   sgy += g*py_[u];   sgz += g*pz_[u];
                sfx += gf*px_[u];  sfy += gf*py_[u];  sfz += gf*pz_[u];
                snx += w*nx_[u];   sny += w*ny_[u];   snz += w*nz_[u];
            }
            #pragma unroll
            for (int m = 1; m < 8; m <<= 1) {
                sw  += __shfl_xor(sw, m);  swf += __shfl_xor(swf, m);
                sgx += __shfl_xor(sgx, m); sgy += __shfl_xor(sgy, m); sgz += __shfl_xor(sgz, m);
                sfx += __shfl_xor(sfx, m); sfy += __shfl_xor(sfy, m); sfz += __shfl_xor(sfz, m);
                snx += __shfl_xor(snx, m); sny += __shfl_xor(sny, m); snz += __shfl_xor(snz, m);
            }
            sw += 1e-8f;
            float fn  = swf / sw;
            float gnx = (sfx + snx - fn*sgx) / sw;
            float gny = (sfy + sny - fn*sgy) / sw;
            float gnz = (sfz + snz - fn*sgz) / sw;
            float delta = fabsf(fn - f);
            f = fn; gx = gnx; gy = gny; gz = gnz;
            done = (delta < THRESHV);
        }
        if (s8 == 0) {
            int gq = blockIdx.x * QT + qs;
            if (gq < N) {
                out[gq] = f;
                out[N + 3*gq + 0] = gx;
                out[N + 3*gq + 1] = gy;
                out[N + 3*gq + 2] = gz;
            }
        }
    }
}

// ============================================================
// ===============  GRID KNN PATH  ============================
// ============================================================

__device__ __forceinline__ unsigned int enc_f(float f) {
    unsigned int b = __float_as_uint(f);
    return (b & 0x80000000u) ? ~b : (b | 0x80000000u);
}
__device__ __forceinline__ float dec_f(unsigned int u) {
    unsigned int b = (u & 0x80000000u) ? (u ^ 0x80000000u) : ~u;
    return __uint_as_float(b);
}
__device__ __forceinline__ int cell_of(float v, float mn, float ics) {
    int c = (int)floorf((v - mn) * ics);
    return c < 0 ? 0 : (c >= RG ? RG-1 : c);
}

__global__ void grid_init(unsigned int* __restrict__ offs, unsigned int* __restrict__ aux,
                          unsigned int* __restrict__ bbox, unsigned int* __restrict__ coarse) {
    int i = blockIdx.x * 256 + threadIdx.x;
    if (i < NC) offs[i] = 0u;
    if (i < NCC) coarse[i] = 0u;
    if (i < 256) aux[i] = 0u;
    if (i < 6) bbox[i] = (i < 3) ? 0xFFFFFFFFu : 0u;
}

__global__ void grid_bbox(const float* __restrict__ sv, unsigned int* __restrict__ bbox, int M) {
    int i = blockIdx.x * 256 + threadIdx.x;
    unsigned int mn0=0xFFFFFFFFu, mn1=0xFFFFFFFFu, mn2=0xFFFFFFFFu;
    unsigned int mx0=0u, mx1=0u, mx2=0u;
    if (i < M) {
        unsigned int e0 = enc_f(sv[3*i+0]);
        unsigned int e1 = enc_f(sv[3*i+1]);
        unsigned int e2 = enc_f(sv[3*i+2]);
        mn0=e0; mn1=e1; mn2=e2; mx0=e0; mx1=e1; mx2=e2;
    }
    for (int off = 1; off < 64; off <<= 1) {
        mn0 = min(mn0, (unsigned int)__shfl_xor(mn0, off));
        mn1 = min(mn1, (unsigned int)__shfl_xor(mn1, off));
        mn2 = min(mn2, (unsigned int)__shfl_xor(mn2, off));
        mx0 = max(mx0, (unsigned int)__shfl_xor(mx0, off));
        mx1 = max(mx1, (unsigned int)__shfl_xor(mx1, off));
        mx2 = max(mx2, (unsigned int)__shfl_xor(mx2, off));
    }
    if ((threadIdx.x & 63) == 0) {
        atomicMin(&bbox[0], mn0); atomicMin(&bbox[1], mn1); atomicMin(&bbox[2], mn2);
        atomicMax(&bbox[3], mx0); atomicMax(&bbox[4], mx1); atomicMax(&bbox[5], mx2);
    }
}

__global__ void grid_params(const unsigned int* __restrict__ bbox, float* __restrict__ gp) {
    if (threadIdx.x != 0 || blockIdx.x != 0) return;
    float csmin = 1e30f, vcell = 1.0f;
    for (int a = 0; a < 3; ++a) {
        float mn = dec_f(bbox[a]), mx = dec_f(bbox[3+a]);
        float span = mx - mn;
        if (!(span > 1e-5f)) span = 1e-5f;
        float cs = span / (float)RG;
        gp[a] = mn; gp[3+a] = cs; gp[6+a] = 1.0f / cs;
        csmin = fminf(csmin, cs); vcell *= cs;
    }
    gp[9]  = 1.0f / csmin;
    gp[10] = vcell;
}

__global__ void grid_count(const float* __restrict__ sv, const float* __restrict__ gp,
                           unsigned int* __restrict__ offs, unsigned int* __restrict__ coarse,
                           int M) {
    int i = blockIdx.x * 256 + threadIdx.x;
    if (i >= M) return;
    int cx = cell_of(sv[3*i+0], gp[0], gp[6]);
    int cy = cell_of(sv[3*i+1], gp[1], gp[7]);
    int cz = cell_of(sv[3*i+2], gp[2], gp[8]);
    atomicAdd(&offs[(cz*RG + cy)*RG + cx], 1u);
    atomicAdd(&coarse[((cz>>2)*RC + (cy>>2))*RC + (cx>>2)], 1u);
}

__global__ void grid_scan_tile(unsigned int* __restrict__ offs, unsigned int* __restrict__ aux) {
    __shared__ unsigned int sm[256];
    const int tid = threadIdx.x;
    const int base = blockIdx.x * 1024 + tid * 4;
    uint4 v = *(const uint4*)&offs[base];
    v.y += v.x; v.z += v.y; v.w += v.z;
    sm[tid] = v.w;
    __syncthreads();
    for (int off = 1; off < 256; off <<= 1) {
        unsigned int add = (tid >= off) ? sm[tid - off] : 0u;
        __syncthreads();
        sm[tid] += add;
        __syncthreads();
    }
    unsigned int add = tid ? sm[tid-1] : 0u;
    v.x += add; v.y += add; v.z += add; v.w += add;
    *(uint4*)&offs[base] = v;
    if (tid == 255) aux[blockIdx.x] = sm[255];
}

__global__ void grid_scan_aux(unsigned int* __restrict__ aux) {
    __shared__ unsigned int sm[256];
    const int tid = threadIdx.x;
    sm[tid] = aux[tid];
    __syncthreads();
    for (int off = 1; off < 256; off <<= 1) {
        unsigned int add = (tid >= off) ? sm[tid - off] : 0u;
        __syncthreads();
        sm[tid] += add;
        __syncthreads();
    }
    aux[tid] = tid ? sm[tid-1] : 0u;
}

__global__ void grid_scan_add(unsigned int* __restrict__ offs, const unsigned int* __restrict__ aux) {
    __shared__ unsigned int sm[1024];
    const int tid = threadIdx.x;
    const int base = blockIdx.x * 1024;
    uint4 v = *(const uint4*)&offs[base + tid*4];
    sm[tid*4+0] = v.x; sm[tid*4+1] = v.y; sm[tid*4+2] = v.z; sm[tid*4+3] = v.w;
    __syncthreads();
    unsigned int a = aux[blockIdx.x];
    uint4 o;
    o.x = a + (tid ? sm[tid*4-1] : 0u);
    o.y = a + sm[tid*4+0];
    o.z = a + sm[tid*4+1];
    o.w = a + sm[tid*4+2];
    *(uint4*)&offs[base + tid*4] = o;
}

__global__ void grid_scatter(const float* __restrict__ sv, const float* __restrict__ gp,
                             unsigned int* __restrict__ offs, float4* __restrict__ spts, int M) {
    int i = blockIdx.x * 256 + threadIdx.x;
    if (i >= M) return;
    float x = sv[3*i+0], y = sv[3*i+1], z = sv[3*i+2];
    int cx = cell_of(x, gp[0], gp[6]);
    int cy = cell_of(y, gp[1], gp[7]);
    int cz = cell_of(z, gp[2], gp[8]);
    unsigned int pos = atomicAdd(&offs[(cz*RG + cy)*RG + cx], 1u);
    spts[pos] = make_float4(x, y, z, __uint_as_float((unsigned int)i));
}

// scan one fine cell's points; aborts once the query's count has exceeded CAP2
// (overshoot already detected — outcome of this round is decided).
__device__ __forceinline__ void scan_cell(const float4* __restrict__ spts,
                                          const unsigned int* __restrict__ cellend,
                                          int c, float qx, float qy, float qz, float T2,
                                          unsigned int* cntp, unsigned int* candp) {
    unsigned int e_ = cellend[c];
    unsigned int b_ = c ? cellend[c-1] : 0u;
    for (unsigned int p = b_; p < e_; ++p) {
        if (((p - b_) & 15u) == 0u &&
            *(volatile unsigned int*)cntp > (unsigned)CAP2) return;
        float4 sp = spts[p];
        float ex = qx - sp.x, ey = qy - sp.y, ez = qz - sp.z;
        float d2 = fmaf(ex, ex, fmaf(ey, ey, ez*ez));
        if (d2 < T2) {
            unsigned int pos = atomicAdd(cntp, 1u);
            if (pos < (unsigned)CAP2)
                candp[pos] = (__float_as_uint(d2) & 0xFFFF0000u) | (__float_as_uint(sp.w) & 0xFFFFu);
        }
    }
}

__global__ __launch_bounds__(NTH2)
void rimls_grid(const float* __restrict__ qpts,
                const float* __restrict__ sverts,
                const float* __restrict__ snorms,
                const float4* __restrict__ spts,
                const unsigned int* __restrict__ cellend,   // post-scatter: cellend[c] = end(c)
                const unsigned int* __restrict__ coarse,    // coarse cell point counts
                const float* __restrict__ gp,
                float* __restrict__ out,
                int N)
{
    __shared__ unsigned int cand[QT2*CAPS2];   // 28800 B
    __shared__ unsigned int selk[QT2*KNN];     // 3840 B
    __shared__ unsigned int ccnt[NCC];         // 16384 B — coarse counts, block-shared
    __shared__ float qsx[QT2], qsy[QT2], qsz[QT2];
    __shared__ float Tq[QT2], Tcq[QT2], Tloq[QT2], Thiq[QT2];
    __shared__ unsigned int cntq[QT2];
    __shared__ int retq[QT2];

    const int t = threadIdx.x;
    const int q = t >> 3;
    const int l = t & 7;

    if (t < QT2) {
        int gq = blockIdx.x * QT2 + t; if (gq >= N) gq = N - 1;
        qsx[t] = qpts[3*gq+0]; qsy[t] = qpts[3*gq+1]; qsz[t] = qpts[3*gq+2];
    }
    for (int i = t; i < QT2*KNN; i += NTH2) selk[i] = 0u;
    for (int i = t; i < NCC; i += NTH2) ccnt[i] = coarse[i];
    __syncthreads();

    const float gx0 = gp[0], gy0 = gp[1], gz0 = gp[2];
    const float csx = gp[3], csy = gp[4], csz = gp[5];
    const float icx = gp[6], icy = gp[7], icz = gp[8];
    const float icsmin = gp[9], vcell = gp[10];

    const float qx = qsx[q], qy = qsy[q], qz = qsz[q];
    int qcx = (int)floorf((qx - gx0) * icx); qcx = qcx < 0 ? 0 : (qcx >= RG ? RG-1 : qcx);
    int qcy = (int)floorf((qy - gy0) * icy); qcy = qcy < 0 ? 0 : (qcy >= RG ? RG-1 : qcy);
    int qcz = (int)floorf((qz - gz0) * icz); qcz = qcz < 0 ? 0 : (qcz >= RG ? RG-1 : qcz);

    // ---- phase A: grow COARSE cell box (LDS counts) until >= KNN points ----
    const int qccx = qcx >> 2, qccy = qcy >> 2, qccz = qcz >> 2;
    int S0 = 0; unsigned int cbox = 0;
    for (int s = 0; s < RC; ++s) {
        int lx = qccx - s; if (lx < 0) lx = 0;
        int hx = qccx + s; if (hx > RC-1) hx = RC-1;
        int ly = qccy - s; if (ly < 0) ly = 0;
        int hy = qccy + s; if (hy > RC-1) hy = RC-1;
        int lz = qccz - s; if (lz < 0) lz = 0;
        int hz = qccz + s; if (hz > RC-1) hz = RC-1;
        int nx = hx-lx+1, ny = hy-ly+1, nz = hz-lz+1;
        int nxy = nx*ny, tot = nxy*nz;
        unsigned int csum = 0u;
        for (int i = l; i < tot; i += 8) {
            int iz = i / nxy; int r = i - iz*nxy; int iy = r / nx; int ix = r - iy*nx;
            csum += ccnt[((lz+iz)*RC + (ly+iy))*RC + (lx+ix)];
        }
        csum += __shfl_xor(csum, 1);
        csum += __shfl_xor(csum, 2);
        csum += __shfl_xor(csum, 4);
        if (csum >= (unsigned)KNN || s == RC-1) { S0 = s; cbox = (csum ? csum : 1u); break; }
    }

    // threshold cap (rigorous: all cbox points lie within this radius) + density estimate
    {
        float ccsx = 4.0f*csx, ccsy = 4.0f*csy, ccsz = 4.0f*csz;
        float blx = gx0 + (float)(qccx - S0) * ccsx, bhx = gx0 + (float)(qccx + S0 + 1) * ccsx;
        float bly = gy0 + (float)(qccy - S0) * ccsy, bhy = gy0 + (float)(qccy + S0 + 1) * ccsy;
        float blz = gz0 + (float)(qccz - S0) * ccsz, bhz = gz0 + (float)(qccz + S0 + 1) * ccsz;
        float dfx = fmaxf(qx - blx, bhx - qx);
        float dfy = fmaxf(qy - bly, bhy - qy);
        float dfz = fmaxf(qz - blz, bhz - qz);
        float tc = sqrtf(dfx*dfx + dfy*dfy + dfz*dfz) * 1.0001f + 1e-6f;
        int nxc = ((qccx+S0 > RC-1) ? RC-1 : qccx+S0) - ((qccx-S0 < 0) ? 0 : qccx-S0) + 1;
        int nyc = ((qccy+S0 > RC-1) ? RC-1 : qccy+S0) - ((qccy-S0 < 0) ? 0 : qccy-S0) + 1;
        int nzc = ((qccz+S0 > RC-1) ? RC-1 : qccz+S0) - ((qccz-S0 < 0) ? 0 : qccz-S0) + 1;
        float vol = (float)(nxc*nyc*nzc) * vcell * 64.0f;
        float t0 = cbrtf(TGT * vol / (4.18879f * (float)cbox));
        if (t0 > tc) t0 = tc;
        if (l == 0) {
            Tq[q] = t0; Tcq[q] = tc; Tloq[q] = 0.0f; Thiq[q] = 0.0f;
            cntq[q] = 0u; retq[q] = 1;
        }
    }
    __syncthreads();

    // ---- phase B: hybrid pruned collection + bracket bisection, early-abort on overshoot ----
    for (int round = 0; round < MAXR; ++round) {
        if (retq[q]) {
            float T = Tq[q], T2 = T*T;
            int smaxF = (int)(T * icsmin) + 1; if (smaxF > RG) smaxF = RG;
            unsigned int* candp = cand + q*CAPS2;
            volatile unsigned int* cvp = &cntq[q];
            if (smaxF <= 4) {
                // ---- fine centered walk (dense-core common case), box dim <= 9 ----
                int B = 2*smaxF + 1, B2 = B*B, tot = B*B2;
                for (int i = l; i < tot; i += 8) {
                    if (*cvp > (unsigned)CAP2) break;
                    int dz = i / B2; int r = i - dz*B2; int dy = r / B; int dx = r - dy*B;
                    int cx = qcx + dx - smaxF, cy = qcy + dy - smaxF, cz = qcz + dz - smaxF;
                    if ((unsigned)cx < (unsigned)RG && (unsigned)cy < (unsigned)RG && (unsigned)cz < (unsigned)RG) {
                        float lox = gx0 + (float)cx * csx;
                        float loy = gy0 + (float)cy * csy;
                        float loz = gz0 + (float)cz * csz;
                        float ax_ = fmaxf(0.0f, fmaxf(lox - qx, qx - lox - csx));
                        float ay_ = fmaxf(0.0f, fmaxf(loy - qy, qy - loy - csy));
                        float az_ = fmaxf(0.0f, fmaxf(loz - qz, qz - loz - csz));
                        float md2 = fmaf(ax_, ax_, fmaf(ay_, ay_, az_*az_));
                        if (md2 < T2) {
                            int c = (cz*RG + cy)*RG + cx;
                            scan_cell(spts, cellend, c, qx, qy, qz, T2, &cntq[q], candp);
                        }
                    }
                }
            } else {
                // ---- coarse-skip walk (sparse outlier case) ----
                int fx0 = qcx - smaxF, fx1 = qcx + smaxF;
                int fy0 = qcy - smaxF, fy1 = qcy + smaxF;
                int fz0 = qcz - smaxF, fz1 = qcz + smaxF;
                int cx0 = (fx0 < 0 ? 0 : fx0) >> 2, cx1 = (fx1 > RG-1 ? RG-1 : fx1) >> 2;
                int cy0 = (fy0 < 0 ? 0 : fy0) >> 2, cy1 = (fy1 > RG-1 ? RG-1 : fy1) >> 2;
                int cz0 = (fz0 < 0 ? 0 : fz0) >> 2, cz1 = (fz1 > RG-1 ? RG-1 : fz1) >> 2;
                int nx = cx1-cx0+1, ny = cy1-cy0+1, nz = cz1-cz0+1;
                int nxy = nx*ny, tot = nxy*nz;
                float ccsx = 4.0f*csx, ccsy = 4.0f*csy, ccsz = 4.0f*csz;
                for (int i = l; i < tot; i += 8) {
                    if (*cvp > (unsigned)CAP2) break;
                    int iz = i / nxy; int r = i - iz*nxy; int iy = r / nx; int ix = r - iy*nx;
                    int ccx = cx0+ix, ccy = cy0+iy, ccz = cz0+iz;
                    unsigned int pc = ccnt[(ccz*RC + ccy)*RC + ccx];
                    if (!pc) continue;
                    float clx = gx0 + (float)ccx * ccsx;
                    float cly = gy0 + (float)ccy * ccsy;
                    float clz = gz0 + (float)ccz * ccsz;
                    float bx_ = fmaxf(0.0f, fmaxf(clx - qx, qx - clx - ccsx));
                    float by_ = fmaxf(0.0f, fmaxf(cly - qy, qy - cly - ccsy));
                    float bz_ = fmaxf(0.0f, fmaxf(clz - qz, qz - clz - ccsz));
                    float cmd2 = fmaf(bx_, bx_, fmaf(by_, by_, bz_*bz_));
                    if (cmd2 >= T2) continue;
                    // per-axis fine min-dist contributions for the 4x4x4 sub-cells
                    float axv[4], ayv[4], azv[4];
                    #pragma unroll
                    for (int u2 = 0; u2 < 4; ++u2) {
                        float lox = clx + (float)u2 * csx;
                        axv[u2] = fmaxf(0.0f, fmaxf(lox - qx, qx - lox - csx));
                        float loy = cly + (float)u2 * csy;
                        ayv[u2] = fmaxf(0.0f, fmaxf(loy - qy, qy - loy - csy));
                        float loz = clz + (float)u2 * csz;
                        azv[u2] = fmaxf(0.0f, fmaxf(loz - qz, qz - loz - csz));
                    }
                    int fbx = ccx << 2, fby = ccy << 2, fbz = ccz << 2;
                    #pragma unroll
                    for (int fz = 0; fz < 4; ++fz) {
                        float pz2 = azv[fz]*azv[fz];
                        #pragma unroll
                        for (int fy = 0; fy < 4; ++fy) {
                            float pyz = fmaf(ayv[fy], ayv[fy], pz2);
                            if (pyz >= T2) continue;
                            #pragma unroll
                            for (int fx = 0; fx < 4; ++fx) {
                                float md2 = fmaf(axv[fx], axv[fx], pyz);
                                if (md2 < T2) {
                                    int c = ((fbz+fz)*RG + (fby+fy))*RG + (fbx+fx);
                                    scan_cell(spts, cellend, c, qx, qy, qz, T2, &cntq[q], candp);
                                }
                            }
                        }
                    }
                }
            }
        }
        __syncthreads();
        int bad = 0;
        if (t < QT2 && retq[t]) {
            unsigned int c_ = cntq[t];
            if (c_ >= (unsigned)KNN && c_ <= (unsigned)CAP2) retq[t] = 0;
            else {
                // geometric bracket bisection: Tlo = known undershoot, Thi = known overshoot
                float T = Tq[t], tlo = Tloq[t], thi = Thiq[t], nT;
                if (c_ < (unsigned)KNN) {
                    tlo = T;
                    if (thi > 0.0f) nT = sqrtf(tlo * thi);
                    else {
                        float sc = cbrtf(TGT / (float)(c_ ? c_ : 1u));
                        sc = fminf(fmaxf(sc, 1.2f), 2.5f);
                        nT = T * sc;
                    }
                } else {   // c_ > CAP2: overshoot (count saturated; candidates truncated)
                    thi = T;
                    if (tlo > 0.0f) nT = sqrtf(tlo * thi);
                    else {
                        float sc = cbrtf(TGT / (float)c_);
                        sc = fminf(fmaxf(sc, 0.30f), 0.75f);
                        nT = T * sc;
                    }
                }
                nT = fminf(nT, Tcq[t]);
                Tq[t] = nT; Tloq[t] = tlo; Thiq[t] = thi;
                cntq[t] = 0u; bad = 1;
            }
        }
        if (!__syncthreads_or(bad)) break;
    }

    // ---- phase C: exact rank-select of KNN smallest keys (8 lanes/query) ----
    {
        unsigned int cc = cntq[q];
        int C = (int)(cc < (unsigned)CAP2 ? cc : (unsigned)CAP2);
        const unsigned int* cd = cand + q * CAPS2;
        for (int a = l; a < C; a += 8) {
            unsigned int ka = cd[a]; int r = 0;
            for (int b = 0; b < C; ++b) r += (cd[b] < ka) ? 1 : 0;
            if (r < KNN) selk[q*KNN + r] = ka;
        }
    }
    __syncthreads();

    // ---- phase D: epilogue (same math as verified kernel) ----
    {
        // belt: if a query somehow didn't converge, only use the neighbors we have
        unsigned int ccq = cntq[q];
        int Cq = (int)(ccq < (unsigned)CAP2 ? ccq : (unsigned)CAP2);
        int kmax = Cq < KNN ? Cq : KNN;

        float px_[4], py_[4], pz_[4], nx_[4], ny_[4], nz_[4];
        float fx_[4], phi_[4], gco_[4], r2_[4];
        float dsum = 0.0f;
        #pragma unroll
        for (int u = 0; u < 4; ++u) {
            int k = l + 8*u;
            bool v = (k < kmax);
            int j = v ? (int)(selk[q*KNN + k] & 0xFFFFu) : 0;
            float sx = sverts[3*j+0], sy = sverts[3*j+1], sz = sverts[3*j+2];
            float px = qx - sx, py = qy - sy, pz = qz - sz;
            float r2 = px*px + py*py + pz*pz;
            float nx = snorms[3*j+0], ny = snorms[3*j+1], nz = snorms[3*j+2];
            float nrm = sqrtf(nx*nx + ny*ny + nz*nz);
            float inv = 1.0f / fmaxf(nrm, 1e-8f);
            float m = v ? 1.0f : 0.0f;
            nx *= inv * m; ny *= inv * m; nz *= inv * m;
            px_[u] = px * m; py_[u] = py * m; pz_[u] = pz * m;
            nx_[u] = nx; ny_[u] = ny; nz_[u] = nz;
            r2_[u] = r2 * m;
            fx_[u] = px_[u]*nx + py_[u]*ny + pz_[u]*nz;
            dsum += v ? sqrtf(r2) : 0.0f;
            phi_[u] = m;
        }
        dsum += __shfl_xor(dsum, 1);
        dsum += __shfl_xor(dsum, 2);
        dsum += __shfl_xor(dsum, 4);
        float h = dsum * (1.0f / (float)KNN) + 1e-8f;
        float h2 = h * h;
        float c8 = -8.0f / h2;
        #pragma unroll
        for (int u = 0; u < 4; ++u) {
            float tt = fmaxf(1.0f - r2_[u] / h2, 0.0f);
            float t2 = tt * tt;
            float valid = phi_[u];
            phi_[u] = t2 * t2 * valid;
            gco_[u] = c8 * t2 * tt * valid;
        }

        const float inv_sn2 = 1.0f / (SIGMA_N * SIGMA_N);
        float f = 0.0f, gx = 0.0f, gy = 0.0f, gz = 0.0f;
        bool done = false;
        for (int it = 0; it < 3; ++it) {
            if (done) break;
            float sw=0, swf=0, sgx=0, sgy=0, sgz=0, sfx=0, sfy=0, sfz=0, snx=0, sny=0, snz=0;
            #pragma unroll
            for (int u = 0; u < 4; ++u) {
                float alpha = 1.0f;
                if (it > 0) {
                    float dx = nx_[u]-gx, dy = ny_[u]-gy, dz = nz_[u]-gz;
                    alpha = expf(-(dx*dx + dy*dy + dz*dz) * inv_sn2);
                }
                float w = alpha * phi_[u];
                float g = alpha * gco_[u];
                float gf = g * fx_[u];
                sw  += w;          swf += w * fx_[u];
                sgx += g*px_[u];   sgy += g*py_[u];   sgz += g*pz_[u];
                sfx += gf*px_[u];  sfy += gf*py_[u];  sfz += gf*pz_[u];
                snx += w*nx_[u];   sny += w*ny_[u];   snz += w*nz_[u];
            }
            #pragma unroll
            for (int m = 1; m < 8; m <<= 1) {
                sw  += __shfl_xor(sw, m);  swf += __shfl_xor(swf, m);
                sgx += __shfl_xor(sgx, m); sgy += __shfl_xor(sgy, m); sgz += __shfl_xor(sgz, m);
                sfx += __shfl_xor(sfx, m); sfy += __shfl_xor(sfy, m); sfz += __shfl_xor(sfz, m);
                snx += __shfl_xor(snx, m); sny += __shfl_xor(sny, m); snz += __shfl_xor(snz, m);
            }
            sw += 1e-8f;
            float fn  = swf / sw;
            float gnx = (sfx + snx - fn*sgx) / sw;
            float gny = (sfy + sny - fn*sgy) / sw;
            float gnz = (sfz + snz - fn*sgz) / sw;
            float delta = fabsf(fn - f);
            f = fn; gx = gnx; gy = gny; gz = gnz;
            done = (delta < THRESHV);
        }
        if (l == 0) {
            int gq = blockIdx.x * QT2 + q;
            if (gq < N) {
                out[gq] = f;
                out[N + 3*gq + 0] = gx;
                out[N + 3*gq + 1] = gy;
                out[N + 3*gq + 2] = gz;
            }
        }
    }
}

// ============================================================

extern "C" void kernel_launch(void* const* d_in, const int* in_sizes, int n_in,
                              void* d_out, int out_size, void* d_ws, size_t ws_size,
                              hipStream_t stream) {
    (void)n_in; (void)out_size;
    const float* qpts   = (const float*)d_in[0];
    const float* sverts = (const float*)d_in[1];
    const float* snorms = (const float*)d_in[2];
    float* out = (float*)d_out;
    int N = in_sizes[0] / 3;
    int M = in_sizes[1] / 3;

    size_t need_grid = (size_t)M * 16 + (size_t)NC * 4 + 256 * 4 + 6 * 4 + 12 * 4 + (size_t)NCC * 4;

    if (ws_size >= need_grid && M <= 65536) {
        char* w = (char*)d_ws;
        float4*       spts   = (float4*)w;
        unsigned int* offs   = (unsigned int*)(w + (size_t)M * 16);
        unsigned int* aux    = offs + NC;
        unsigned int* bbox   = aux + 256;
        float*        gp     = (float*)(bbox + 6);
        unsigned int* coarse = (unsigned int*)(gp + 12);

        int mb = (M + 255) / 256;
        grid_init   <<<(NC + 255) / 256, 256, 0, stream>>>(offs, aux, bbox, coarse);
        grid_bbox   <<<mb, 256, 0, stream>>>(sverts, bbox, M);
        grid_params <<<1, 64, 0, stream>>>(bbox, gp);
        grid_count  <<<mb, 256, 0, stream>>>(sverts, gp, offs, coarse, M);
        grid_scan_tile<<<NC / 1024, 256, 0, stream>>>(offs, aux);
        grid_scan_aux <<<1, 256, 0, stream>>>(aux);
        grid_scan_add <<<NC / 1024, 256, 0, stream>>>(offs, aux);
        grid_scatter<<<mb, 256, 0, stream>>>(sverts, gp, offs, spts, M);

        int blocks = (N + QT2 - 1) / QT2;
        rimls_grid<<<blocks, NTH2, 0, stream>>>(qpts, sverts, snorms, spts, offs, coarse, gp, out, N);
    } else {
        int blocks = (N + QT - 1) / QT;
        if (ws_size >= (size_t)M * sizeof(float4)) {
            float4* spack = (float4*)d_ws;
            prep_pack<<<(M + 255) / 256, 256, 0, stream>>>(sverts, spack, M);
            rimls_fused<true><<<blocks, NTH, 0, stream>>>(qpts, sverts, snorms, spack, out, N, M);
        } else {
            rimls_fused<false><<<blocks, NTH, 0, stream>>>(qpts, sverts, snorms, nullptr, out, N, M);
        }
    }
}

// Round 5
// 728.571 us; speedup vs baseline: 3.9177x; 1.5682x over previous
//
#include <hip/hip_runtime.h>
#include <math.h>

#define KNN 30
#define SIGMA_N 0.8f
#define THRESHV 1e-3f

// ---------------- old (fallback) path constants ----------------
#define QT 32
#define NTH 256
#define CAP 160
#define CAPS 161
#define RSEL 20

// ---------------- grid path constants ----------------
#define RG 64
#define NC (RG*RG*RG)
#define RC 16                    // coarse grid (RG/4)
#define NCC (RC*RC*RC)
#define QT2 16                   // queries per block
#define NTH2 256
#define LPQ 16                   // lanes per query (16 lanes = quarter wave)
#define CAP2 320
#define CAPS2 321
#define TGT 60.0f
#define MAXR 14

// ============================================================
// ===============  OLD BRUTE-FORCE PATH (fallback) ===========
// ============================================================

__global__ void prep_pack(const float* __restrict__ src, float4* __restrict__ dst, int M) {
    int j = blockIdx.x * 256 + threadIdx.x;
    if (j < M) {
        float x = src[3*j+0], y = src[3*j+1], z = src[3*j+2];
        dst[j] = make_float4(x, y, z, 0.5f*(x*x + y*y + z*z));
    }
}

template<bool PACKED>
__device__ __forceinline__ float4 fetch_pt(const float4* __restrict__ sp,
                                           const float* __restrict__ sv, int j) {
    if (PACKED) return sp[j];
    float x = sv[3*j+0], y = sv[3*j+1], z = sv[3*j+2];
    return make_float4(x, y, z, 0.5f*(x*x + y*y + z*z));
}

__device__ __forceinline__ void ins4(unsigned int k, unsigned int &m0, unsigned int &m1,
                                     unsigned int &m2, unsigned int &m3) {
    if (k < m3) {
        if (k < m2) {
            m3 = m2;
            if (k < m1) { m2 = m1; if (k < m0) { m1 = m0; m0 = k; } else m1 = k; }
            else m2 = k;
        } else m3 = k;
    }
}

template<bool PACKED>
__global__ __launch_bounds__(NTH)
void rimls_fused(const float* __restrict__ qpts,
                 const float* __restrict__ sverts,
                 const float* __restrict__ snorms,
                 const float4* __restrict__ spack,
                 float* __restrict__ out,
                 int N, int M)
{
    __shared__ unsigned int cand[QT * CAPS];
    __shared__ unsigned int selk[QT * KNN];
    __shared__ float4 qbuf[QT];
    __shared__ unsigned int cnt[QT];
    __shared__ unsigned int T16[QT];
    __shared__ int retryq[QT];

    const int t  = threadIdx.x;
    const int qg = t >> 4;
    const int c  = t & 15;
    const int qa = qg, qb = qg + 16;

    if (t < QT) {
        int gq = blockIdx.x * QT + t; if (gq >= N) gq = N - 1;
        float x = qpts[3*gq+0], y = qpts[3*gq+1], z = qpts[3*gq+2];
        qbuf[t] = make_float4(x, y, z, 0.5f*(x*x + y*y + z*z));
    }
    for (int i = t; i < QT * KNN; i += NTH) selk[i] = 0u;
    __syncthreads();

    const float ax = qbuf[qa].x, ay = qbuf[qa].y, az = qbuf[qa].z, aw = qbuf[qa].w;
    const float bx = qbuf[qb].x, by = qbuf[qb].y, bz = qbuf[qb].z, bw = qbuf[qb].w;

    unsigned int a0=~0u,a1=~0u,a2=~0u,a3=~0u, b0=~0u,b1=~0u,b2=~0u,b3=~0u;
    {
        const int n1 = M >> 6;
        #pragma unroll 2
        for (int i = 0; i < n1; ++i) {
            int j = (c + (i << 4)) << 2;
            float4 s = fetch_pt<PACKED>(spack, sverts, j);
            float va = fmaxf(fmaf(-ax, s.x, fmaf(-ay, s.y, fmaf(-az, s.z, s.w + aw))), 0.0f);
            float vb = fmaxf(fmaf(-bx, s.x, fmaf(-by, s.y, fmaf(-bz, s.z, s.w + bw))), 0.0f);
            unsigned int ka = (__float_as_uint(va) & 0xFFFF0000u) | (unsigned int)j;
            unsigned int kb = (__float_as_uint(vb) & 0xFFFF0000u) | (unsigned int)j;
            ins4(ka, a0, a1, a2, a3);
            ins4(kb, b0, b1, b2, b3);
        }
    }
    {
        unsigned int* mb = cand;
        mb[qa*64 + c*4 + 0] = a0; mb[qa*64 + c*4 + 1] = a1;
        mb[qa*64 + c*4 + 2] = a2; mb[qa*64 + c*4 + 3] = a3;
        mb[qb*64 + c*4 + 0] = b0; mb[qb*64 + c*4 + 1] = b1;
        mb[qb*64 + c*4 + 2] = b2; mb[qb*64 + c*4 + 3] = b3;
    }
    __syncthreads();
    if (t < QT) {
        const unsigned int* m_ = cand + t * 64;
        unsigned int kth = 0xFFFFFFFFu;
        for (int a = 0; a < 64; ++a) {
            unsigned int ka = m_[a]; int r = 0;
            for (int b = 0; b < 64; ++b) r += (m_[b] < ka) ? 1 : 0;
            if (r == RSEL - 1) kth = ka;
        }
        unsigned int tb = (kth >> 16) + 1u;
        if (tb > 0x7F00u) tb = 0x7F00u;
        T16[t] = tb; cnt[t] = 0u; retryq[t] = 1;
    }
    __syncthreads();

    const int n3 = M >> 4;
    for (int round = 0; round < 8; ++round) {
        bool aa = retryq[qa] != 0, ab = retryq[qb] != 0;
        if (aa || ab) {
            float Ta = aa ? __uint_as_float(T16[qa] << 16) : 0.0f;
            float Tb = ab ? __uint_as_float(T16[qb] << 16) : 0.0f;
            #pragma unroll 4
            for (int i = 0; i < n3; ++i) {
                int j = c + (i << 4);
                float4 s = fetch_pt<PACKED>(spack, sverts, j);
                float va = fmaxf(fmaf(-ax, s.x, fmaf(-ay, s.y, fmaf(-az, s.z, s.w + aw))), 0.0f);
                float vb = fmaxf(fmaf(-bx, s.x, fmaf(-by, s.y, fmaf(-bz, s.z, s.w + bw))), 0.0f);
                if (va < Ta) {
                    unsigned int pos = atomicAdd(&cnt[qa], 1u);
                    if (pos < (unsigned)CAP)
                        cand[qa*CAPS + pos] = (__float_as_uint(va) & 0xFFFF0000u) | (unsigned int)j;
                }
                if (vb < Tb) {
                    unsigned int pos = atomicAdd(&cnt[qb], 1u);
                    if (pos < (unsigned)CAP)
                        cand[qb*CAPS + pos] = (__float_as_uint(vb) & 0xFFFF0000u) | (unsigned int)j;
                }
            }
        }
        __syncthreads();
        int bad = 0;
        if (t < QT && retryq[t]) {
            unsigned int cc = cnt[t], tb = T16[t];
            if (cc < (unsigned)KNN) {
                if (tb < 0x7F00u) {
                    tb += (1u << 7);
                    if (tb > 0x7F00u) tb = 0x7F00u;
                    bad = 1;
                }
            } else if (cc > (unsigned)CAP && round < 4 && tb > (1u << 6)) {
                tb -= (1u << 6); bad = 1;
            }
            if (bad) { T16[t] = tb; cnt[t] = 0u; }
            else retryq[t] = 0;
        }
        if (!__syncthreads_or(bad)) break;
    }

    const int qs = t >> 3, s8 = t & 7;
    {
        unsigned int cc = cnt[qs];
        int C = (int)(cc < (unsigned)CAP ? cc : (unsigned)CAP);
        const unsigned int* cd = cand + qs * CAPS;
        for (int a = s8; a < C; a += 8) {
            unsigned int ka = cd[a]; int r = 0;
            for (int b = 0; b < C; ++b) r += (cd[b] < ka) ? 1 : 0;
            if (r < KNN) selk[qs*KNN + r] = ka;
        }
    }
    __syncthreads();

    {
        const float qx = qbuf[qs].x, qy = qbuf[qs].y, qz = qbuf[qs].z;
        float px_[4], py_[4], pz_[4], nx_[4], ny_[4], nz_[4];
        float fx_[4], phi_[4], gco_[4], r2_[4];
        float dsum = 0.0f;
        #pragma unroll
        for (int u = 0; u < 4; ++u) {
            int k = s8 + 8*u;
            bool v = (k < KNN);
            int j = v ? (int)(selk[qs*KNN + k] & 0xFFFFu) : 0;
            float4 s = fetch_pt<PACKED>(spack, sverts, j);
            float px = qx - s.x, py = qy - s.y, pz = qz - s.z;
            float r2 = px*px + py*py + pz*pz;
            float nx = snorms[3*j+0], ny = snorms[3*j+1], nz = snorms[3*j+2];
            float nrm = sqrtf(nx*nx + ny*ny + nz*nz);
            float inv = 1.0f / fmaxf(nrm, 1e-8f);
            float m = v ? 1.0f : 0.0f;
            nx *= inv * m; ny *= inv * m; nz *= inv * m;
            px_[u] = px * m; py_[u] = py * m; pz_[u] = pz * m;
            nx_[u] = nx; ny_[u] = ny; nz_[u] = nz;
            r2_[u] = r2 * m;
            fx_[u] = px_[u]*nx + py_[u]*ny + pz_[u]*nz;
            dsum += v ? sqrtf(r2) : 0.0f;
            phi_[u] = m;
        }
        dsum += __shfl_xor(dsum, 1);
        dsum += __shfl_xor(dsum, 2);
        dsum += __shfl_xor(dsum, 4);
        float h = dsum * (1.0f / (float)KNN) + 1e-8f;
        float h2 = h * h;
        float c8 = -8.0f / h2;
        #pragma unroll
        for (int u = 0; u < 4; ++u) {
            float tt = fmaxf(1.0f - r2_[u] / h2, 0.0f);
            float t2 = tt * tt;
            float valid = phi_[u];
            phi_[u] = t2 * t2 * valid;
            gco_[u] = c8 * t2 * tt * valid;
        }

        const float inv_sn2 = 1.0f / (SIGMA_N * SIGMA_N);
        float f = 0.0f, gx = 0.0f, gy = 0.0f, gz = 0.0f;
        bool done = false;
        for (int it = 0; it < 3; ++it) {
            if (done) break;
            float sw=0, swf=0, sgx=0, sgy=0, sgz=0, sfx=0, sfy=0, sfz=0, snx=0, sny=0, snz=0;
            #pragma unroll
            for (int u = 0; u < 4; ++u) {
                float alpha = 1.0f;
                if (it > 0) {
                    float dx = nx_[u]-gx, dy = ny_[u]-gy, dz = nz_[u]-gz;
                    alpha = expf(-(dx*dx + dy*dy + dz*dz) * inv_sn2);
                }
                float w = alpha * phi_[u];
                float g = alpha * gco_[u];
                float gf = g * fx_[u];
                sw  += w;          swf += w * fx_[u];
                sgx += g*px_[u];   sgy += g*py_[u];   sgz += g*pz_[u];
                sfx += gf*px_[u];  sfy += gf*py_[u];  sfz += gf*pz_[u];
                snx += w*nx_[u];   sny += w*ny_[u];   snz += w*nz_[u];
            }
            #pragma unroll
            for (int m = 1; m < 8; m <<= 1) {
                sw  += __shfl_xor(sw, m);  swf += __shfl_xor(swf, m);
                sgx += __shfl_xor(sgx, m); sgy += __shfl_xor(sgy, m); sgz += __shfl_xor(sgz, m);
                sfx += __shfl_xor(sfx, m); sfy += __shfl_xor(sfy, m); sfz += __shfl_xor(sfz, m);
                snx += __shfl_xor(snx, m); sny += __shfl_xor(sny, m); snz += __shfl_xor(snz, m);
            }
            sw += 1e-8f;
            float fn  = swf / sw;
            float gnx = (sfx + snx - fn*sgx) / sw;
            float gny = (sfy + sny - fn*sgy) / sw;
            float gnz = (sfz + snz - fn*sgz) / sw;
            float delta = fabsf(fn - f);
            f = fn; gx = gnx; gy = gny; gz = gnz;
            done = (delta < THRESHV);
        }
        if (s8 == 0) {
            int gq = blockIdx.x * QT + qs;
            if (gq < N) {
                out[gq] = f;
                out[N + 3*gq + 0] = gx;
                out[N + 3*gq + 1] = gy;
                out[N + 3*gq + 2] = gz;
            }
        }
    }
}

// ============================================================
// ===============  GRID KNN PATH  ============================
// ============================================================

__device__ __forceinline__ unsigned int enc_f(float f) {
    unsigned int b = __float_as_uint(f);
    return (b & 0x80000000u) ? ~b : (b | 0x80000000u);
}
__device__ __forceinline__ float dec_f(unsigned int u) {
    unsigned int b = (u & 0x80000000u) ? (u ^ 0x80000000u) : ~u;
    return __uint_as_float(b);
}
__device__ __forceinline__ int cell_of(float v, float mn, float ics) {
    int c = (int)floorf((v - mn) * ics);
    return c < 0 ? 0 : (c >= RG ? RG-1 : c);
}

__global__ void grid_init(unsigned int* __restrict__ offs, unsigned int* __restrict__ aux,
                          unsigned int* __restrict__ bbox, unsigned int* __restrict__ coarse) {
    int i = blockIdx.x * 256 + threadIdx.x;
    if (i < NC) offs[i] = 0u;
    if (i < NCC) coarse[i] = 0u;
    if (i < 256) aux[i] = 0u;
    if (i < 6) bbox[i] = (i < 3) ? 0xFFFFFFFFu : 0u;
}

__global__ void grid_bbox(const float* __restrict__ sv, unsigned int* __restrict__ bbox, int M) {
    int i = blockIdx.x * 256 + threadIdx.x;
    unsigned int mn0=0xFFFFFFFFu, mn1=0xFFFFFFFFu, mn2=0xFFFFFFFFu;
    unsigned int mx0=0u, mx1=0u, mx2=0u;
    if (i < M) {
        unsigned int e0 = enc_f(sv[3*i+0]);
        unsigned int e1 = enc_f(sv[3*i+1]);
        unsigned int e2 = enc_f(sv[3*i+2]);
        mn0=e0; mn1=e1; mn2=e2; mx0=e0; mx1=e1; mx2=e2;
    }
    for (int off = 1; off < 64; off <<= 1) {
        mn0 = min(mn0, (unsigned int)__shfl_xor(mn0, off));
        mn1 = min(mn1, (unsigned int)__shfl_xor(mn1, off));
        mn2 = min(mn2, (unsigned int)__shfl_xor(mn2, off));
        mx0 = max(mx0, (unsigned int)__shfl_xor(mx0, off));
        mx1 = max(mx1, (unsigned int)__shfl_xor(mx1, off));
        mx2 = max(mx2, (unsigned int)__shfl_xor(mx2, off));
    }
    if ((threadIdx.x & 63) == 0) {
        atomicMin(&bbox[0], mn0); atomicMin(&bbox[1], mn1); atomicMin(&bbox[2], mn2);
        atomicMax(&bbox[3], mx0); atomicMax(&bbox[4], mx1); atomicMax(&bbox[5], mx2);
    }
}

__global__ void grid_params(const unsigned int* __restrict__ bbox, float* __restrict__ gp) {
    if (threadIdx.x != 0 || blockIdx.x != 0) return;
    float csmin = 1e30f, vcell = 1.0f;
    for (int a = 0; a < 3; ++a) {
        float mn = dec_f(bbox[a]), mx = dec_f(bbox[3+a]);
        float span = mx - mn;
        if (!(span > 1e-5f)) span = 1e-5f;
        float cs = span / (float)RG;
        gp[a] = mn; gp[3+a] = cs; gp[6+a] = 1.0f / cs;
        csmin = fminf(csmin, cs); vcell *= cs;
    }
    gp[9]  = 1.0f / csmin;
    gp[10] = vcell;
}

__global__ void grid_count(const float* __restrict__ sv, const float* __restrict__ gp,
                           unsigned int* __restrict__ offs, unsigned int* __restrict__ coarse,
                           int M) {
    int i = blockIdx.x * 256 + threadIdx.x;
    if (i >= M) return;
    int cx = cell_of(sv[3*i+0], gp[0], gp[6]);
    int cy = cell_of(sv[3*i+1], gp[1], gp[7]);
    int cz = cell_of(sv[3*i+2], gp[2], gp[8]);
    atomicAdd(&offs[(cz*RG + cy)*RG + cx], 1u);
    atomicAdd(&coarse[((cz>>2)*RC + (cy>>2))*RC + (cx>>2)], 1u);
}

__global__ void grid_scan_tile(unsigned int* __restrict__ offs, unsigned int* __restrict__ aux) {
    __shared__ unsigned int sm[256];
    const int tid = threadIdx.x;
    const int base = blockIdx.x * 1024 + tid * 4;
    uint4 v = *(const uint4*)&offs[base];
    v.y += v.x; v.z += v.y; v.w += v.z;
    sm[tid] = v.w;
    __syncthreads();
    for (int off = 1; off < 256; off <<= 1) {
        unsigned int add = (tid >= off) ? sm[tid - off] : 0u;
        __syncthreads();
        sm[tid] += add;
        __syncthreads();
    }
    unsigned int add = tid ? sm[tid-1] : 0u;
    v.x += add; v.y += add; v.z += add; v.w += add;
    *(uint4*)&offs[base] = v;
    if (tid == 255) aux[blockIdx.x] = sm[255];
}

__global__ void grid_scan_aux(unsigned int* __restrict__ aux) {
    __shared__ unsigned int sm[256];
    const int tid = threadIdx.x;
    sm[tid] = aux[tid];
    __syncthreads();
    for (int off = 1; off < 256; off <<= 1) {
        unsigned int add = (tid >= off) ? sm[tid - off] : 0u;
        __syncthreads();
        sm[tid] += add;
        __syncthreads();
    }
    aux[tid] = tid ? sm[tid-1] : 0u;
}

__global__ void grid_scan_add(unsigned int* __restrict__ offs, const unsigned int* __restrict__ aux) {
    __shared__ unsigned int sm[1024];
    const int tid = threadIdx.x;
    const int base = blockIdx.x * 1024;
    uint4 v = *(const uint4*)&offs[base + tid*4];
    sm[tid*4+0] = v.x; sm[tid*4+1] = v.y; sm[tid*4+2] = v.z; sm[tid*4+3] = v.w;
    __syncthreads();
    unsigned int a = aux[blockIdx.x];
    uint4 o;
    o.x = a + (tid ? sm[tid*4-1] : 0u);
    o.y = a + sm[tid*4+0];
    o.z = a + sm[tid*4+1];
    o.w = a + sm[tid*4+2];
    *(uint4*)&offs[base + tid*4] = o;
}

__global__ void grid_scatter(const float* __restrict__ sv, const float* __restrict__ gp,
                             unsigned int* __restrict__ offs, float4* __restrict__ spts, int M) {
    int i = blockIdx.x * 256 + threadIdx.x;
    if (i >= M) return;
    float x = sv[3*i+0], y = sv[3*i+1], z = sv[3*i+2];
    int cx = cell_of(x, gp[0], gp[6]);
    int cy = cell_of(y, gp[1], gp[7]);
    int cz = cell_of(z, gp[2], gp[8]);
    unsigned int pos = atomicAdd(&offs[(cz*RG + cy)*RG + cx], 1u);
    spts[pos] = make_float4(x, y, z, __uint_as_float((unsigned int)i));
}

// scan one fine cell's points; aborts once the query's count has exceeded CAP2.
__device__ __forceinline__ void scan_cell(const float4* __restrict__ spts,
                                          const unsigned int* __restrict__ cellend,
                                          int c, float qx, float qy, float qz, float T2,
                                          unsigned int* cntp, unsigned int* candp) {
    unsigned int e_ = cellend[c];
    unsigned int b_ = c ? cellend[c-1] : 0u;
    for (unsigned int p = b_; p < e_; ++p) {
        if (((p - b_) & 15u) == 0u &&
            *(volatile unsigned int*)cntp > (unsigned)CAP2) return;
        float4 sp = spts[p];
        float ex = qx - sp.x, ey = qy - sp.y, ez = qz - sp.z;
        float d2 = fmaf(ex, ex, fmaf(ey, ey, ez*ez));
        if (d2 < T2) {
            unsigned int pos = atomicAdd(cntp, 1u);
            if (pos < (unsigned)CAP2)
                candp[pos] = (__float_as_uint(d2) & 0xFFFF0000u) | (__float_as_uint(sp.w) & 0xFFFFu);
        }
    }
}

// Barrier-free grid kernel: 16 queries/block, 16 lanes/query (one wave = 4 queries).
// After the cooperative prologue + one __syncthreads, each query group runs its
// entire pipeline (grow, probe/bisect, select, epilogue) with NO block barriers:
// all 16 lanes of a group are in the same wave64, so LDS ops are program-ordered.
__global__ __launch_bounds__(NTH2)
void rimls_grid(const float* __restrict__ qpts,
                const float* __restrict__ sverts,
                const float* __restrict__ snorms,
                const float4* __restrict__ spts,
                const unsigned int* __restrict__ cellend,
                const unsigned int* __restrict__ coarse,
                const float* __restrict__ gp,
                float* __restrict__ out,
                int N)
{
    __shared__ unsigned int cand[QT2*CAPS2];   // 20544 B
    __shared__ unsigned int selk[QT2*KNN];     // 1920 B
    __shared__ unsigned int ccnt[NCC];         // 16384 B
    __shared__ float qsx[QT2], qsy[QT2], qsz[QT2];
    __shared__ unsigned int cntq[QT2];

    const int t = threadIdx.x;
    const int q = t >> 4;       // 0..15
    const int l = t & 15;       // lane within query group

    if (t < QT2) {
        int gq = blockIdx.x * QT2 + t; if (gq >= N) gq = N - 1;
        qsx[t] = qpts[3*gq+0]; qsy[t] = qpts[3*gq+1]; qsz[t] = qpts[3*gq+2];
        cntq[t] = 0u;
    }
    for (int i = t; i < QT2*KNN; i += NTH2) selk[i] = 0u;
    for (int i = t; i < NCC; i += NTH2) ccnt[i] = coarse[i];
    __syncthreads();
    // ---- no block barriers beyond this point ----

    const float gx0 = gp[0], gy0 = gp[1], gz0 = gp[2];
    const float csx = gp[3], csy = gp[4], csz = gp[5];
    const float icx = gp[6], icy = gp[7], icz = gp[8];
    const float icsmin = gp[9], vcell = gp[10];
    const float ccsx = 4.0f*csx, ccsy = 4.0f*csy, ccsz = 4.0f*csz;

    const float qx = qsx[q], qy = qsy[q], qz = qsz[q];
    int qcx = (int)floorf((qx - gx0) * icx); qcx = qcx < 0 ? 0 : (qcx >= RG ? RG-1 : qcx);
    int qcy = (int)floorf((qy - gy0) * icy); qcy = qcy < 0 ? 0 : (qcy >= RG ? RG-1 : qcy);
    int qcz = (int)floorf((qz - gz0) * icz); qcz = qcz < 0 ? 0 : (qcz >= RG ? RG-1 : qcz);
    const int qccx = qcx >> 2, qccy = qcy >> 2, qccz = qcz >> 2;

    // ---- phase A: grow coarse box (LDS counts, division-free walk) ----
    int S0 = 0; unsigned int cbox = 1u;
    int lxS = 0, hxS = 0, lyS = 0, hyS = 0, lzS = 0, hzS = 0;
    for (int s = 0; s < RC; ++s) {
        int lx = qccx - s; if (lx < 0) lx = 0;
        int hx = qccx + s; if (hx > RC-1) hx = RC-1;
        int ly = qccy - s; if (ly < 0) ly = 0;
        int hy = qccy + s; if (hy > RC-1) hy = RC-1;
        int lz = qccz - s; if (lz < 0) lz = 0;
        int hz = qccz + s; if (hz > RC-1) hz = RC-1;
        int bnx = hx-lx+1, bny = hy-ly+1, bnz = hz-lz+1;
        int tot = bnx*bny*bnz;
        unsigned int csum = 0u;
        int ix = l, iy = 0, iz = 0;
        while (ix >= bnx) { ix -= bnx; ++iy; }
        while (iy >= bny) { iy -= bny; ++iz; }
        for (int i = l; i < tot; i += LPQ) {
            csum += ccnt[((lz+iz)*RC + (ly+iy))*RC + (lx+ix)];
            ix += LPQ;
            while (ix >= bnx) { ix -= bnx; ++iy; }
            while (iy >= bny) { iy -= bny; ++iz; }
        }
        csum += __shfl_xor(csum, 1);
        csum += __shfl_xor(csum, 2);
        csum += __shfl_xor(csum, 4);
        csum += __shfl_xor(csum, 8);
        if (csum >= (unsigned)KNN || s == RC-1) {
            S0 = s; cbox = csum ? csum : 1u;
            lxS = lx; hxS = hx; lyS = ly; hyS = hy; lzS = lz; hzS = hz;
            break;
        }
    }

    // rigorous cap (corner of clipped S0 box) + rigorous lower bracket (inscribed
    // sphere of the unclipped (S0-1) box: count < KNN there) + density estimate
    float T, tlo, thi = 0.0f, tc;
    {
        float blx = gx0 + (float)lxS * ccsx, bhx = gx0 + (float)(hxS+1) * ccsx;
        float bly = gy0 + (float)lyS * ccsy, bhy = gy0 + (float)(hyS+1) * ccsy;
        float blz = gz0 + (float)lzS * ccsz, bhz = gz0 + (float)(hzS+1) * ccsz;
        float dfx = fmaxf(qx - blx, bhx - qx);
        float dfy = fmaxf(qy - bly, bhy - qy);
        float dfz = fmaxf(qz - blz, bhz - qz);
        tc = sqrtf(dfx*dfx + dfy*dfy + dfz*dfz) * 1.0001f + 1e-6f;
        float vol = (float)((hxS-lxS+1)*(hyS-lyS+1)*(hzS-lzS+1)) * vcell * 64.0f;
        float t0 = cbrtf(TGT * vol / (4.18879f * (float)cbox));
        float tlo0 = 0.0f;
        if (S0 > 0) {
            float s1 = (float)(S0 - 1);
            float rx = fminf(qx - (gx0 + ((float)qccx - s1) * ccsx),
                             (gx0 + ((float)qccx + s1 + 1.0f) * ccsx) - qx);
            float ry = fminf(qy - (gy0 + ((float)qccy - s1) * ccsy),
                             (gy0 + ((float)qccy + s1 + 1.0f) * ccsy) - qy);
            float rz = fminf(qz - (gz0 + ((float)qccz - s1) * ccsz),
                             (gz0 + ((float)qccz + s1 + 1.0f) * ccsz) - qz);
            float rins = fminf(rx, fminf(ry, rz));
            tlo0 = fmaxf(rins, 0.0f) * 0.9999f;
        }
        tlo = tlo0;
        T = fminf(fmaxf(t0, tlo0 * 1.02f), tc);
    }

    // ---- phase B: probe + bracket bisection, per-group, barrier-free ----
    unsigned int* candp = cand + q*CAPS2;
    volatile unsigned int* cvp = &cntq[q];
    bool ret = true;
    for (int round = 0; round < MAXR; ++round) {
        if (!__any(ret)) break;
        if (ret) {
            cntq[q] = 0u;                       // same-wave ordering: safe
            float T2 = T*T;
            int smaxF = (int)(T * icsmin) + 1; if (smaxF > RG) smaxF = RG;
            if (smaxF <= 4) {
                // fine centered walk, cube side B <= 9, division-free
                int B = 2*smaxF + 1;
                int tot = B*B*B;
                int bx0 = qcx - smaxF, by0 = qcy - smaxF, bz0 = qcz - smaxF;
                int ix = l, iy = 0, iz = 0;
                while (ix >= B) { ix -= B; ++iy; }
                while (iy >= B) { iy -= B; ++iz; }
                for (int i = l; i < tot; i += LPQ) {
                    if (*cvp > (unsigned)CAP2) break;
                    int cx = bx0 + ix, cy = by0 + iy, cz = bz0 + iz;
                    if ((unsigned)cx < (unsigned)RG && (unsigned)cy < (unsigned)RG && (unsigned)cz < (unsigned)RG) {
                        float lox = gx0 + (float)cx * csx;
                        float loy = gy0 + (float)cy * csy;
                        float loz = gz0 + (float)cz * csz;
                        float ax_ = fmaxf(0.0f, fmaxf(lox - qx, qx - lox - csx));
                        float ay_ = fmaxf(0.0f, fmaxf(loy - qy, qy - loy - csy));
                        float az_ = fmaxf(0.0f, fmaxf(loz - qz, qz - loz - csz));
                        float md2 = fmaf(ax_, ax_, fmaf(ay_, ay_, az_*az_));
                        if (md2 < T2) {
                            int c = (cz*RG + cy)*RG + cx;
                            scan_cell(spts, cellend, c, qx, qy, qz, T2, &cntq[q], candp);
                        }
                    }
                    ix += LPQ;
                    while (ix >= B) { ix -= B; ++iy; }
                    while (iy >= B) { iy -= B; ++iz; }
                }
            } else {
                // coarse-skip walk over clipped coarse box, division-free
                int fx0 = qcx - smaxF, fx1 = qcx + smaxF;
                int fy0 = qcy - smaxF, fy1 = qcy + smaxF;
                int fz0 = qcz - smaxF, fz1 = qcz + smaxF;
                int cx0 = (fx0 < 0 ? 0 : fx0) >> 2, cx1 = (fx1 > RG-1 ? RG-1 : fx1) >> 2;
                int cy0 = (fy0 < 0 ? 0 : fy0) >> 2, cy1 = (fy1 > RG-1 ? RG-1 : fy1) >> 2;
                int cz0 = (fz0 < 0 ? 0 : fz0) >> 2, cz1 = (fz1 > RG-1 ? RG-1 : fz1) >> 2;
                int cnx = cx1-cx0+1, cny = cy1-cy0+1, cnz = cz1-cz0+1;
                int tot = cnx*cny*cnz;
                int ix = l, iy = 0, iz = 0;
                while (ix >= cnx) { ix -= cnx; ++iy; }
                while (iy >= cny) { iy -= cny; ++iz; }
                for (int i = l; i < tot; i += LPQ) {
                    if (*cvp > (unsigned)CAP2) break;
                    int ccx = cx0+ix, ccy = cy0+iy, ccz = cz0+iz;
                    ix += LPQ;
                    while (ix >= cnx) { ix -= cnx; ++iy; }
                    while (iy >= cny) { iy -= cny; ++iz; }
                    unsigned int pc = ccnt[(ccz*RC + ccy)*RC + ccx];
                    if (!pc) continue;
                    float clx = gx0 + (float)ccx * ccsx;
                    float cly = gy0 + (float)ccy * ccsy;
                    float clz = gz0 + (float)ccz * ccsz;
                    float bx_ = fmaxf(0.0f, fmaxf(clx - qx, qx - clx - ccsx));
                    float by_ = fmaxf(0.0f, fmaxf(cly - qy, qy - cly - ccsy));
                    float bz_ = fmaxf(0.0f, fmaxf(clz - qz, qz - clz - ccsz));
                    float cmd2 = fmaf(bx_, bx_, fmaf(by_, by_, bz_*bz_));
                    if (cmd2 >= T2) continue;
                    float axv[4], ayv[4], azv[4];
                    #pragma unroll
                    for (int u2 = 0; u2 < 4; ++u2) {
                        float lox = clx + (float)u2 * csx;
                        axv[u2] = fmaxf(0.0f, fmaxf(lox - qx, qx - lox - csx));
                        float loy = cly + (float)u2 * csy;
                        ayv[u2] = fmaxf(0.0f, fmaxf(loy - qy, qy - loy - csy));
                        float loz = clz + (float)u2 * csz;
                        azv[u2] = fmaxf(0.0f, fmaxf(loz - qz, qz - loz - csz));
                    }
                    int fbx = ccx << 2, fby = ccy << 2, fbz = ccz << 2;
                    #pragma unroll
                    for (int fz = 0; fz < 4; ++fz) {
                        float pz2 = azv[fz]*azv[fz];
                        #pragma unroll
                        for (int fy = 0; fy < 4; ++fy) {
                            float pyz = fmaf(ayv[fy], ayv[fy], pz2);
                            if (pyz >= T2) continue;
                            #pragma unroll
                            for (int fx = 0; fx < 4; ++fx) {
                                float md2 = fmaf(axv[fx], axv[fx], pyz);
                                if (md2 < T2) {
                                    int c = ((fbz+fz)*RG + (fby+fy))*RG + (fbx+fx);
                                    scan_cell(spts, cellend, c, qx, qy, qz, T2, &cntq[q], candp);
                                }
                            }
                        }
                    }
                }
            }
            // controller: identical scalar math on all 16 lanes (no broadcast needed)
            unsigned int c_ = cntq[q];
            if (c_ >= (unsigned)KNN && c_ <= (unsigned)CAP2) {
                ret = false;
            } else if (round < MAXR-1) {
                float nT;
                if (c_ < (unsigned)KNN) {
                    tlo = T;
                    nT = (thi > 0.0f) ? sqrtf(tlo * thi)
                       : fminf(T * fminf(fmaxf(cbrtf(TGT / (float)(c_ ? c_ : 1u)), 1.25f), 2.5f), tc);
                } else {
                    thi = T;
                    nT = (tlo > 0.0f) ? sqrtf(tlo * thi)
                       : T * fminf(fmaxf(cbrtf(TGT / (float)c_), 0.30f), 0.75f);
                }
                T = fminf(nT, tc);
            } else {
                ret = false;    // exhausted; belt in phase D handles gracefully
            }
        }
    }

    // ---- phase C: exact rank-select of KNN smallest keys (16 lanes/query) ----
    {
        unsigned int cc = cntq[q];
        int C = (int)(cc < (unsigned)CAP2 ? cc : (unsigned)CAP2);
        const unsigned int* cd = cand + q * CAPS2;
        for (int a = l; a < C; a += LPQ) {
            unsigned int ka = cd[a]; int r = 0;
            for (int b = 0; b < C; ++b) r += (cd[b] < ka) ? 1 : 0;
            if (r < KNN) selk[q*KNN + r] = ka;
        }
    }

    // ---- phase D: epilogue (same math; 16 lanes, 2 regs/lane) ----
    {
        unsigned int ccq = cntq[q];
        int Cq = (int)(ccq < (unsigned)CAP2 ? ccq : (unsigned)CAP2);
        int kmax = Cq < KNN ? Cq : KNN;

        float px_[2], py_[2], pz_[2], nx_[2], ny_[2], nz_[2];
        float fx_[2], phi_[2], gco_[2], r2_[2];
        float dsum = 0.0f;
        #pragma unroll
        for (int u = 0; u < 2; ++u) {
            int k = l + LPQ*u;
            bool v = (k < kmax);
            int j = v ? (int)(selk[q*KNN + k] & 0xFFFFu) : 0;
            float sx = sverts[3*j+0], sy = sverts[3*j+1], sz = sverts[3*j+2];
            float px = qx - sx, py = qy - sy, pz = qz - sz;
            float r2 = px*px + py*py + pz*pz;
            float nx = snorms[3*j+0], ny = snorms[3*j+1], nz = snorms[3*j+2];
            float nrm = sqrtf(nx*nx + ny*ny + nz*nz);
            float inv = 1.0f / fmaxf(nrm, 1e-8f);
            float m = v ? 1.0f : 0.0f;
            nx *= inv * m; ny *= inv * m; nz *= inv * m;
            px_[u] = px * m; py_[u] = py * m; pz_[u] = pz * m;
            nx_[u] = nx; ny_[u] = ny; nz_[u] = nz;
            r2_[u] = r2 * m;
            fx_[u] = px_[u]*nx + py_[u]*ny + pz_[u]*nz;
            dsum += v ? sqrtf(r2) : 0.0f;
            phi_[u] = m;
        }
        dsum += __shfl_xor(dsum, 1);
        dsum += __shfl_xor(dsum, 2);
        dsum += __shfl_xor(dsum, 4);
        dsum += __shfl_xor(dsum, 8);
        float h = dsum * (1.0f / (float)KNN) + 1e-8f;
        float h2 = h * h;
        float c8 = -8.0f / h2;
        #pragma unroll
        for (int u = 0; u < 2; ++u) {
            float tt = fmaxf(1.0f - r2_[u] / h2, 0.0f);
            float t2 = tt * tt;
            float valid = phi_[u];
            phi_[u] = t2 * t2 * valid;
            gco_[u] = c8 * t2 * tt * valid;
        }

        const float inv_sn2 = 1.0f / (SIGMA_N * SIGMA_N);
        float f = 0.0f, gx = 0.0f, gy = 0.0f, gz = 0.0f;
        bool done = false;
        for (int it = 0; it < 3; ++it) {
            if (done) break;
            float sw=0, swf=0, sgx=0, sgy=0, sgz=0, sfx=0, sfy=0, sfz=0, snx=0, sny=0, snz=0;
            #pragma unroll
            for (int u = 0; u < 2; ++u) {
                float alpha = 1.0f;
                if (it > 0) {
                    float dx = nx_[u]-gx, dy = ny_[u]-gy, dz = nz_[u]-gz;
                    alpha = expf(-(dx*dx + dy*dy + dz*dz) * inv_sn2);
                }
                float w = alpha * phi_[u];
                float g = alpha * gco_[u];
                float gf = g * fx_[u];
                sw  += w;          swf += w * fx_[u];
                sgx += g*px_[u];   sgy += g*py_[u];   sgz += g*pz_[u];
                sfx += gf*px_[u];  sfy += gf*py_[u];  sfz += gf*pz_[u];
                snx += w*nx_[u];   sny += w*ny_[u];   snz += w*nz_[u];
            }
            #pragma unroll
            for (int m = 1; m < LPQ; m <<= 1) {
                sw  += __shfl_xor(sw, m);  swf += __shfl_xor(swf, m);
                sgx += __shfl_xor(sgx, m); sgy += __shfl_xor(sgy, m); sgz += __shfl_xor(sgz, m);
                sfx += __shfl_xor(sfx, m); sfy += __shfl_xor(sfy, m); sfz += __shfl_xor(sfz, m);
                snx += __shfl_xor(snx, m); sny += __shfl_xor(sny, m); snz += __shfl_xor(snz, m);
            }
            sw += 1e-8f;
            float fn  = swf / sw;
            float gnx = (sfx + snx - fn*sgx) / sw;
            float gny = (sfy + sny - fn*sgy) / sw;
            float gnz = (sfz + snz - fn*sgz) / sw;
            float delta = fabsf(fn - f);
            f = fn; gx = gnx; gy = gny; gz = gnz;
            done = (delta < THRESHV);
        }
        if (l == 0) {
            int gq = blockIdx.x * QT2 + q;
            if (gq < N) {
                out[gq] = f;
                out[N + 3*gq + 0] = gx;
                out[N + 3*gq + 1] = gy;
                out[N + 3*gq + 2] = gz;
            }
        }
    }
}

// ============================================================

extern "C" void kernel_launch(void* const* d_in, const int* in_sizes, int n_in,
                              void* d_out, int out_size, void* d_ws, size_t ws_size,
                              hipStream_t stream) {
    (void)n_in; (void)out_size;
    const float* qpts   = (const float*)d_in[0];
    const float* sverts = (const float*)d_in[1];
    const float* snorms = (const float*)d_in[2];
    float* out = (float*)d_out;
    int N = in_sizes[0] / 3;
    int M = in_sizes[1] / 3;

    size_t need_grid = (size_t)M * 16 + (size_t)NC * 4 + 256 * 4 + 6 * 4 + 12 * 4 + (size_t)NCC * 4;

    if (ws_size >= need_grid && M <= 65536) {
        char* w = (char*)d_ws;
        float4*       spts   = (float4*)w;
        unsigned int* offs   = (unsigned int*)(w + (size_t)M * 16);
        unsigned int* aux    = offs + NC;
        unsigned int* bbox   = aux + 256;
        float*        gp     = (float*)(bbox + 6);
        unsigned int* coarse = (unsigned int*)(gp + 12);

        int mb = (M + 255) / 256;
        grid_init   <<<(NC + 255) / 256, 256, 0, stream>>>(offs, aux, bbox, coarse);
        grid_bbox   <<<mb, 256, 0, stream>>>(sverts, bbox, M);
        grid_params <<<1, 64, 0, stream>>>(bbox, gp);
        grid_count  <<<mb, 256, 0, stream>>>(sverts, gp, offs, coarse, M);
        grid_scan_tile<<<NC / 1024, 256, 0, stream>>>(offs, aux);
        grid_scan_aux <<<1, 256, 0, stream>>>(aux);
        grid_scan_add <<<NC / 1024, 256, 0, stream>>>(offs, aux);
        grid_scatter<<<mb, 256, 0, stream>>>(sverts, gp, offs, spts, M);

        int blocks = (N + QT2 - 1) / QT2;
        rimls_grid<<<blocks, NTH2, 0, stream>>>(qpts, sverts, snorms, spts, offs, coarse, gp, out, N);
    } else {
        int blocks = (N + QT - 1) / QT;
        if (ws_size >= (size_t)M * sizeof(float4)) {
            float4* spack = (float4*)d_ws;
            prep_pack<<<(M + 255) / 256, 256, 0, stream>>>(sverts, spack, M);
            rimls_fused<true><<<blocks, NTH, 0, stream>>>(qpts, sverts, snorms, spack, out, N, M);
        } else {
            rimls_fused<false><<<blocks, NTH, 0, stream>>>(qpts, sverts, snorms, nullptr, out, N, M);
        }
    }
}

// Round 6
// 579.074 us; speedup vs baseline: 4.9291x; 1.2582x over previous
//
#include <hip/hip_runtime.h>
#include <math.h>

#define KNN 30
#define SIGMA_N 0.8f
#define THRESHV 1e-3f

// ---------------- old (fallback) path constants ----------------
#define QT 32
#define NTH 256
#define CAP 160
#define CAPS 161
#define RSEL 20

// ---------------- grid path constants ----------------
#define RG 64
#define NC (RG*RG*RG)
#define RC 16                    // coarse grid (RG/4)
#define NCC (RC*RC*RC)
#define QT2 8                    // queries per block
#define NTH2 256
#define LPQ 32                   // lanes per query (half wave)
#define CAP2 320
#define CAPS2 321
#define TGT 60.0f
#define MAXR 12

// ============================================================
// ===============  OLD BRUTE-FORCE PATH (fallback) ===========
// ============================================================

__global__ void prep_pack(const float* __restrict__ src, float4* __restrict__ dst, int M) {
    int j = blockIdx.x * 256 + threadIdx.x;
    if (j < M) {
        float x = src[3*j+0], y = src[3*j+1], z = src[3*j+2];
        dst[j] = make_float4(x, y, z, 0.5f*(x*x + y*y + z*z));
    }
}

template<bool PACKED>
__device__ __forceinline__ float4 fetch_pt(const float4* __restrict__ sp,
                                           const float* __restrict__ sv, int j) {
    if (PACKED) return sp[j];
    float x = sv[3*j+0], y = sv[3*j+1], z = sv[3*j+2];
    return make_float4(x, y, z, 0.5f*(x*x + y*y + z*z));
}

__device__ __forceinline__ void ins4(unsigned int k, unsigned int &m0, unsigned int &m1,
                                     unsigned int &m2, unsigned int &m3) {
    if (k < m3) {
        if (k < m2) {
            m3 = m2;
            if (k < m1) { m2 = m1; if (k < m0) { m1 = m0; m0 = k; } else m1 = k; }
            else m2 = k;
        } else m3 = k;
    }
}

template<bool PACKED>
__global__ __launch_bounds__(NTH)
void rimls_fused(const float* __restrict__ qpts,
                 const float* __restrict__ sverts,
                 const float* __restrict__ snorms,
                 const float4* __restrict__ spack,
                 float* __restrict__ out,
                 int N, int M)
{
    __shared__ unsigned int cand[QT * CAPS];
    __shared__ unsigned int selk[QT * KNN];
    __shared__ float4 qbuf[QT];
    __shared__ unsigned int cnt[QT];
    __shared__ unsigned int T16[QT];
    __shared__ int retryq[QT];

    const int t  = threadIdx.x;
    const int qg = t >> 4;
    const int c  = t & 15;
    const int qa = qg, qb = qg + 16;

    if (t < QT) {
        int gq = blockIdx.x * QT + t; if (gq >= N) gq = N - 1;
        float x = qpts[3*gq+0], y = qpts[3*gq+1], z = qpts[3*gq+2];
        qbuf[t] = make_float4(x, y, z, 0.5f*(x*x + y*y + z*z));
    }
    for (int i = t; i < QT * KNN; i += NTH) selk[i] = 0u;
    __syncthreads();

    const float ax = qbuf[qa].x, ay = qbuf[qa].y, az = qbuf[qa].z, aw = qbuf[qa].w;
    const float bx = qbuf[qb].x, by = qbuf[qb].y, bz = qbuf[qb].z, bw = qbuf[qb].w;

    unsigned int a0=~0u,a1=~0u,a2=~0u,a3=~0u, b0=~0u,b1=~0u,b2=~0u,b3=~0u;
    {
        const int n1 = M >> 6;
        #pragma unroll 2
        for (int i = 0; i < n1; ++i) {
            int j = (c + (i << 4)) << 2;
            float4 s = fetch_pt<PACKED>(spack, sverts, j);
            float va = fmaxf(fmaf(-ax, s.x, fmaf(-ay, s.y, fmaf(-az, s.z, s.w + aw))), 0.0f);
            float vb = fmaxf(fmaf(-bx, s.x, fmaf(-by, s.y, fmaf(-bz, s.z, s.w + bw))), 0.0f);
            unsigned int ka = (__float_as_uint(va) & 0xFFFF0000u) | (unsigned int)j;
            unsigned int kb = (__float_as_uint(vb) & 0xFFFF0000u) | (unsigned int)j;
            ins4(ka, a0, a1, a2, a3);
            ins4(kb, b0, b1, b2, b3);
        }
    }
    {
        unsigned int* mb = cand;
        mb[qa*64 + c*4 + 0] = a0; mb[qa*64 + c*4 + 1] = a1;
        mb[qa*64 + c*4 + 2] = a2; mb[qa*64 + c*4 + 3] = a3;
        mb[qb*64 + c*4 + 0] = b0; mb[qb*64 + c*4 + 1] = b1;
        mb[qb*64 + c*4 + 2] = b2; mb[qb*64 + c*4 + 3] = b3;
    }
    __syncthreads();
    if (t < QT) {
        const unsigned int* m_ = cand + t * 64;
        unsigned int kth = 0xFFFFFFFFu;
        for (int a = 0; a < 64; ++a) {
            unsigned int ka = m_[a]; int r = 0;
            for (int b = 0; b < 64; ++b) r += (m_[b] < ka) ? 1 : 0;
            if (r == RSEL - 1) kth = ka;
        }
        unsigned int tb = (kth >> 16) + 1u;
        if (tb > 0x7F00u) tb = 0x7F00u;
        T16[t] = tb; cnt[t] = 0u; retryq[t] = 1;
    }
    __syncthreads();

    const int n3 = M >> 4;
    for (int round = 0; round < 8; ++round) {
        bool aa = retryq[qa] != 0, ab = retryq[qb] != 0;
        if (aa || ab) {
            float Ta = aa ? __uint_as_float(T16[qa] << 16) : 0.0f;
            float Tb = ab ? __uint_as_float(T16[qb] << 16) : 0.0f;
            #pragma unroll 4
            for (int i = 0; i < n3; ++i) {
                int j = c + (i << 4);
                float4 s = fetch_pt<PACKED>(spack, sverts, j);
                float va = fmaxf(fmaf(-ax, s.x, fmaf(-ay, s.y, fmaf(-az, s.z, s.w + aw))), 0.0f);
                float vb = fmaxf(fmaf(-bx, s.x, fmaf(-by, s.y, fmaf(-bz, s.z, s.w + bw))), 0.0f);
                if (va < Ta) {
                    unsigned int pos = atomicAdd(&cnt[qa], 1u);
                    if (pos < (unsigned)CAP)
                        cand[qa*CAPS + pos] = (__float_as_uint(va) & 0xFFFF0000u) | (unsigned int)j;
                }
                if (vb < Tb) {
                    unsigned int pos = atomicAdd(&cnt[qb], 1u);
                    if (pos < (unsigned)CAP)
                        cand[qb*CAPS + pos] = (__float_as_uint(vb) & 0xFFFF0000u) | (unsigned int)j;
                }
            }
        }
        __syncthreads();
        int bad = 0;
        if (t < QT && retryq[t]) {
            unsigned int cc = cnt[t], tb = T16[t];
            if (cc < (unsigned)KNN) {
                if (tb < 0x7F00u) {
                    tb += (1u << 7);
                    if (tb > 0x7F00u) tb = 0x7F00u;
                    bad = 1;
                }
            } else if (cc > (unsigned)CAP && round < 4 && tb > (1u << 6)) {
                tb -= (1u << 6); bad = 1;
            }
            if (bad) { T16[t] = tb; cnt[t] = 0u; }
            else retryq[t] = 0;
        }
        if (!__syncthreads_or(bad)) break;
    }

    const int qs = t >> 3, s8 = t & 7;
    {
        unsigned int cc = cnt[qs];
        int C = (int)(cc < (unsigned)CAP ? cc : (unsigned)CAP);
        const unsigned int* cd = cand + qs * CAPS;
        for (int a = s8; a < C; a += 8) {
            unsigned int ka = cd[a]; int r = 0;
            for (int b = 0; b < C; ++b) r += (cd[b] < ka) ? 1 : 0;
            if (r < KNN) selk[qs*KNN + r] = ka;
        }
    }
    __syncthreads();

    {
        const float qx = qbuf[qs].x, qy = qbuf[qs].y, qz = qbuf[qs].z;
        float px_[4], py_[4], pz_[4], nx_[4], ny_[4], nz_[4];
        float fx_[4], phi_[4], gco_[4], r2_[4];
        float dsum = 0.0f;
        #pragma unroll
        for (int u = 0; u < 4; ++u) {
            int k = s8 + 8*u;
            bool v = (k < KNN);
            int j = v ? (int)(selk[qs*KNN + k] & 0xFFFFu) : 0;
            float4 s = fetch_pt<PACKED>(spack, sverts, j);
            float px = qx - s.x, py = qy - s.y, pz = qz - s.z;
            float r2 = px*px + py*py + pz*pz;
            float nx = snorms[3*j+0], ny = snorms[3*j+1], nz = snorms[3*j+2];
            float nrm = sqrtf(nx*nx + ny*ny + nz*nz);
            float inv = 1.0f / fmaxf(nrm, 1e-8f);
            float m = v ? 1.0f : 0.0f;
            nx *= inv * m; ny *= inv * m; nz *= inv * m;
            px_[u] = px * m; py_[u] = py * m; pz_[u] = pz * m;
            nx_[u] = nx; ny_[u] = ny; nz_[u] = nz;
            r2_[u] = r2 * m;
            fx_[u] = px_[u]*nx + py_[u]*ny + pz_[u]*nz;
            dsum += v ? sqrtf(r2) : 0.0f;
            phi_[u] = m;
        }
        dsum += __shfl_xor(dsum, 1);
        dsum += __shfl_xor(dsum, 2);
        dsum += __shfl_xor(dsum, 4);
        float h = dsum * (1.0f / (float)KNN) + 1e-8f;
        float h2 = h * h;
        float c8 = -8.0f / h2;
        #pragma unroll
        for (int u = 0; u < 4; ++u) {
            float tt = fmaxf(1.0f - r2_[u] / h2, 0.0f);
            float t2 = tt * tt;
            float valid = phi_[u];
            phi_[u] = t2 * t2 * valid;
            gco_[u] = c8 * t2 * tt * valid;
        }

        const float inv_sn2 = 1.0f / (SIGMA_N * SIGMA_N);
        float f = 0.0f, gx = 0.0f, gy = 0.0f, gz = 0.0f;
        bool done = false;
        for (int it = 0; it < 3; ++it) {
            if (done) break;
            float sw=0, swf=0, sgx=0, sgy=0, sgz=0, sfx=0, sfy=0, sfz=0, snx=0, sny=0, snz=0;
            #pragma unroll
            for (int u = 0; u < 4; ++u) {
                float alpha = 1.0f;
                if (it > 0) {
                    float dx = nx_[u]-gx, dy = ny_[u]-gy, dz = nz_[u]-gz;
                    alpha = expf(-(dx*dx + dy*dy + dz*dz) * inv_sn2);
                }
                float w = alpha * phi_[u];
                float g = alpha * gco_[u];
                float gf = g * fx_[u];
                sw  += w;          swf += w * fx_[u];
                sgx += g*px_[u];   sgy += g*py_[u];   sgz += g*pz_[u];
                sfx += gf*px_[u];  sfy += gf*py_[u];  sfz += gf*pz_[u];
                snx += w*nx_[u];   sny += w*ny_[u];   snz += w*nz_[u];
            }
            #pragma unroll
            for (int m = 1; m < 8; m <<= 1) {
                sw  += __shfl_xor(sw, m);  swf += __shfl_xor(swf, m);
                sgx += __shfl_xor(sgx, m); sgy += __shfl_xor(sgy, m); sgz += __shfl_xor(sgz, m);
                sfx += __shfl_xor(sfx, m); sfy += __shfl_xor(sfy, m); sfz += __shfl_xor(sfz, m);
                snx += __shfl_xor(snx, m); sny += __shfl_xor(sny, m); snz += __shfl_xor(snz, m);
            }
            sw += 1e-8f;
            float fn  = swf / sw;
            float gnx = (sfx + snx - fn*sgx) / sw;
            float gny = (sfy + sny - fn*sgy) / sw;
            float gnz = (sfz + snz - fn*sgz) / sw;
            float delta = fabsf(fn - f);
            f = fn; gx = gnx; gy = gny; gz = gnz;
            done = (delta < THRESHV);
        }
        if (s8 == 0) {
            int gq = blockIdx.x * QT + qs;
            if (gq < N) {
                out[gq] = f;
                out[N + 3*gq + 0] = gx;
                out[N + 3*gq + 1] = gy;
                out[N + 3*gq + 2] = gz;
            }
        }
    }
}

// ============================================================
// ===============  GRID KNN PATH  ============================
// ============================================================

__device__ __forceinline__ unsigned int enc_f(float f) {
    unsigned int b = __float_as_uint(f);
    return (b & 0x80000000u) ? ~b : (b | 0x80000000u);
}
__device__ __forceinline__ float dec_f(unsigned int u) {
    unsigned int b = (u & 0x80000000u) ? (u ^ 0x80000000u) : ~u;
    return __uint_as_float(b);
}
__device__ __forceinline__ int cell_of(float v, float mn, float ics) {
    int c = (int)floorf((v - mn) * ics);
    return c < 0 ? 0 : (c >= RG ? RG-1 : c);
}
// coarse-major fine-cell index: each coarse cell's 64 fine cells (and thus its
// points after scatter) are CONTIGUOUS
__device__ __forceinline__ int fidx(int cx, int cy, int cz) {
    int cidx = (((cz >> 2)*RC + (cy >> 2))*RC + (cx >> 2));
    return (cidx << 6) | ((cz & 3) << 4) | ((cy & 3) << 2) | (cx & 3);
}

__global__ void grid_init(unsigned int* __restrict__ offs, unsigned int* __restrict__ aux,
                          unsigned int* __restrict__ bbox, unsigned int* __restrict__ coarse) {
    int i = blockIdx.x * 256 + threadIdx.x;
    if (i < NC) offs[i] = 0u;
    if (i < NCC) coarse[i] = 0u;
    if (i < 256) aux[i] = 0u;
    if (i < 6) bbox[i] = (i < 3) ? 0xFFFFFFFFu : 0u;
}

__global__ void grid_bbox(const float* __restrict__ sv, unsigned int* __restrict__ bbox, int M) {
    int i = blockIdx.x * 256 + threadIdx.x;
    unsigned int mn0=0xFFFFFFFFu, mn1=0xFFFFFFFFu, mn2=0xFFFFFFFFu;
    unsigned int mx0=0u, mx1=0u, mx2=0u;
    if (i < M) {
        unsigned int e0 = enc_f(sv[3*i+0]);
        unsigned int e1 = enc_f(sv[3*i+1]);
        unsigned int e2 = enc_f(sv[3*i+2]);
        mn0=e0; mn1=e1; mn2=e2; mx0=e0; mx1=e1; mx2=e2;
    }
    for (int off = 1; off < 64; off <<= 1) {
        mn0 = min(mn0, (unsigned int)__shfl_xor(mn0, off));
        mn1 = min(mn1, (unsigned int)__shfl_xor(mn1, off));
        mn2 = min(mn2, (unsigned int)__shfl_xor(mn2, off));
        mx0 = max(mx0, (unsigned int)__shfl_xor(mx0, off));
        mx1 = max(mx1, (unsigned int)__shfl_xor(mx1, off));
        mx2 = max(mx2, (unsigned int)__shfl_xor(mx2, off));
    }
    if ((threadIdx.x & 63) == 0) {
        atomicMin(&bbox[0], mn0); atomicMin(&bbox[1], mn1); atomicMin(&bbox[2], mn2);
        atomicMax(&bbox[3], mx0); atomicMax(&bbox[4], mx1); atomicMax(&bbox[5], mx2);
    }
}

__global__ void grid_params(const unsigned int* __restrict__ bbox, float* __restrict__ gp) {
    if (threadIdx.x != 0 || blockIdx.x != 0) return;
    float csmin = 1e30f, vcell = 1.0f;
    for (int a = 0; a < 3; ++a) {
        float mn = dec_f(bbox[a]), mx = dec_f(bbox[3+a]);
        float span = mx - mn;
        if (!(span > 1e-5f)) span = 1e-5f;
        float cs = span / (float)RG;
        gp[a] = mn; gp[3+a] = cs; gp[6+a] = 1.0f / cs;
        csmin = fminf(csmin, cs); vcell *= cs;
    }
    gp[9]  = 1.0f / csmin;
    gp[10] = vcell;
}

__global__ void grid_count(const float* __restrict__ sv, const float* __restrict__ gp,
                           unsigned int* __restrict__ offs, unsigned int* __restrict__ coarse,
                           int M) {
    int i = blockIdx.x * 256 + threadIdx.x;
    if (i >= M) return;
    int cx = cell_of(sv[3*i+0], gp[0], gp[6]);
    int cy = cell_of(sv[3*i+1], gp[1], gp[7]);
    int cz = cell_of(sv[3*i+2], gp[2], gp[8]);
    atomicAdd(&offs[fidx(cx, cy, cz)], 1u);
    atomicAdd(&coarse[((cz>>2)*RC + (cy>>2))*RC + (cx>>2)], 1u);
}

__global__ void grid_scan_tile(unsigned int* __restrict__ offs, unsigned int* __restrict__ aux) {
    __shared__ unsigned int sm[256];
    const int tid = threadIdx.x;
    const int base = blockIdx.x * 1024 + tid * 4;
    uint4 v = *(const uint4*)&offs[base];
    v.y += v.x; v.z += v.y; v.w += v.z;
    sm[tid] = v.w;
    __syncthreads();
    for (int off = 1; off < 256; off <<= 1) {
        unsigned int add = (tid >= off) ? sm[tid - off] : 0u;
        __syncthreads();
        sm[tid] += add;
        __syncthreads();
    }
    unsigned int add = tid ? sm[tid-1] : 0u;
    v.x += add; v.y += add; v.z += add; v.w += add;
    *(uint4*)&offs[base] = v;
    if (tid == 255) aux[blockIdx.x] = sm[255];
}

__global__ void grid_scan_aux(unsigned int* __restrict__ aux) {
    __shared__ unsigned int sm[256];
    const int tid = threadIdx.x;
    sm[tid] = aux[tid];
    __syncthreads();
    for (int off = 1; off < 256; off <<= 1) {
        unsigned int add = (tid >= off) ? sm[tid - off] : 0u;
        __syncthreads();
        sm[tid] += add;
        __syncthreads();
    }
    aux[tid] = tid ? sm[tid-1] : 0u;
}

__global__ void grid_scan_add(unsigned int* __restrict__ offs, const unsigned int* __restrict__ aux) {
    __shared__ unsigned int sm[1024];
    const int tid = threadIdx.x;
    const int base = blockIdx.x * 1024;
    uint4 v = *(const uint4*)&offs[base + tid*4];
    sm[tid*4+0] = v.x; sm[tid*4+1] = v.y; sm[tid*4+2] = v.z; sm[tid*4+3] = v.w;
    __syncthreads();
    unsigned int a = aux[blockIdx.x];
    uint4 o;
    o.x = a + (tid ? sm[tid*4-1] : 0u);
    o.y = a + sm[tid*4+0];
    o.z = a + sm[tid*4+1];
    o.w = a + sm[tid*4+2];
    *(uint4*)&offs[base + tid*4] = o;
}

__global__ void grid_scatter(const float* __restrict__ sv, const float* __restrict__ gp,
                             unsigned int* __restrict__ offs, float4* __restrict__ spts, int M) {
    int i = blockIdx.x * 256 + threadIdx.x;
    if (i >= M) return;
    float x = sv[3*i+0], y = sv[3*i+1], z = sv[3*i+2];
    int cx = cell_of(x, gp[0], gp[6]);
    int cy = cell_of(y, gp[1], gp[7]);
    int cz = cell_of(z, gp[2], gp[8]);
    unsigned int pos = atomicAdd(&offs[fidx(cx, cy, cz)], 1u);
    spts[pos] = make_float4(x, y, z, __uint_as_float((unsigned int)i));
}

// scan a contiguous point range with threshold filter; aborts on overshoot
__device__ __forceinline__ void scan_range(const float4* __restrict__ spts,
                                           unsigned int b_, unsigned int e_,
                                           float qx, float qy, float qz, float T2,
                                           unsigned int* cntp, unsigned int* candp) {
    for (unsigned int p = b_; p < e_; ++p) {
        if (((p - b_) & 15u) == 0u &&
            *(volatile unsigned int*)cntp > (unsigned)CAP2) return;
        float4 sp = spts[p];
        float ex = qx - sp.x, ey = qy - sp.y, ez = qz - sp.z;
        float d2 = fmaf(ex, ex, fmaf(ey, ey, ez*ez));
        if (d2 < T2) {
            unsigned int pos = atomicAdd(cntp, 1u);
            if (pos < (unsigned)CAP2)
                candp[pos] = (__float_as_uint(d2) & 0xFFFF0000u) | (__float_as_uint(sp.w) & 0xFFFFu);
        }
    }
}

// exact rank-select of the KNN smallest 32-bit keys among C candidates
__device__ __forceinline__ void rank_select(const unsigned int* __restrict__ cd, int C,
                                            unsigned int* __restrict__ sel, int l) {
    for (int a = l; a < C; a += LPQ) {
        unsigned int ka = cd[a]; int r = 0;
        for (int b = 0; b < C; ++b) r += (cd[b] < ka) ? 1 : 0;
        if (r < KNN) sel[r] = ka;
    }
}

// Barrier-free grid kernel: 8 queries/block, 32 lanes/query (half wave).
__global__ __launch_bounds__(NTH2)
void rimls_grid(const float* __restrict__ qpts,
                const float* __restrict__ sverts,
                const float* __restrict__ snorms,
                const float4* __restrict__ spts,
                const unsigned int* __restrict__ cellend,
                const unsigned int* __restrict__ coarse,
                const float* __restrict__ gp,
                float* __restrict__ out,
                int N)
{
    __shared__ unsigned int cand[QT2*CAPS2];       // 10272 B
    __shared__ unsigned int selk[QT2*KNN];         // 960 B
    __shared__ unsigned short ccnt[NCC];           // 8192 B
    __shared__ float qsx[QT2], qsy[QT2], qsz[QT2];
    __shared__ unsigned int cntq[QT2];

    const int t = threadIdx.x;
    const int q = t >> 5;       // 0..7
    const int l = t & 31;       // lane within query group

    if (t < QT2) {
        int gq = blockIdx.x * QT2 + t; if (gq >= N) gq = N - 1;
        qsx[t] = qpts[3*gq+0]; qsy[t] = qpts[3*gq+1]; qsz[t] = qpts[3*gq+2];
        cntq[t] = 0u;
    }
    for (int i = t; i < QT2*KNN; i += NTH2) selk[i] = 0u;
    for (int i = t; i < NCC; i += NTH2) {
        unsigned int v = coarse[i];
        ccnt[i] = (unsigned short)(v > 65535u ? 65535u : v);
    }
    __syncthreads();
    // ---- no block barriers beyond this point ----

    const float gx0 = gp[0], gy0 = gp[1], gz0 = gp[2];
    const float csx = gp[3], csy = gp[4], csz = gp[5];
    const float icx = gp[6], icy = gp[7], icz = gp[8];
    const float icsmin = gp[9], vcell = gp[10];
    const float ccsx = 4.0f*csx, ccsy = 4.0f*csy, ccsz = 4.0f*csz;

    const float qx = qsx[q], qy = qsy[q], qz = qsz[q];
    int qcx = (int)floorf((qx - gx0) * icx); qcx = qcx < 0 ? 0 : (qcx >= RG ? RG-1 : qcx);
    int qcy = (int)floorf((qy - gy0) * icy); qcy = qcy < 0 ? 0 : (qcy >= RG ? RG-1 : qcy);
    int qcz = (int)floorf((qz - gz0) * icz); qcz = qcz < 0 ? 0 : (qcz >= RG ? RG-1 : qcz);
    const int qccx = qcx >> 2, qccy = qcy >> 2, qccz = qcz >> 2;

    // ---- phase A: grow coarse box (LDS counts, division-free walk) ----
    int S0 = 0; unsigned int cbox = 1u;
    int lxS = 0, hxS = 0, lyS = 0, hyS = 0, lzS = 0, hzS = 0;
    for (int s = 0; s < RC; ++s) {
        int lx = qccx - s; if (lx < 0) lx = 0;
        int hx = qccx + s; if (hx > RC-1) hx = RC-1;
        int ly = qccy - s; if (ly < 0) ly = 0;
        int hy = qccy + s; if (hy > RC-1) hy = RC-1;
        int lz = qccz - s; if (lz < 0) lz = 0;
        int hz = qccz + s; if (hz > RC-1) hz = RC-1;
        int bnx = hx-lx+1, bny = hy-ly+1, bnz = hz-lz+1;
        int tot = bnx*bny*bnz;
        unsigned int csum = 0u;
        int ix = l, iy = 0, iz = 0;
        while (ix >= bnx) { ix -= bnx; ++iy; }
        while (iy >= bny) { iy -= bny; ++iz; }
        for (int i = l; i < tot; i += LPQ) {
            csum += (unsigned int)ccnt[((lz+iz)*RC + (ly+iy))*RC + (lx+ix)];
            ix += LPQ;
            while (ix >= bnx) { ix -= bnx; ++iy; }
            while (iy >= bny) { iy -= bny; ++iz; }
        }
        csum += __shfl_xor(csum, 1);
        csum += __shfl_xor(csum, 2);
        csum += __shfl_xor(csum, 4);
        csum += __shfl_xor(csum, 8);
        csum += __shfl_xor(csum, 16);
        if (csum >= (unsigned)KNN || s == RC-1) {
            S0 = s; cbox = csum ? csum : 1u;
            lxS = lx; hxS = hx; lyS = ly; hyS = hy; lzS = lz; hzS = hz;
            break;
        }
    }

    // common: rigorous cap tc (corner of clipped S0 box)
    float tc;
    {
        float blx = gx0 + (float)lxS * ccsx, bhx = gx0 + (float)(hxS+1) * ccsx;
        float bly = gy0 + (float)lyS * ccsy, bhy = gy0 + (float)(hyS+1) * ccsy;
        float blz = gz0 + (float)lzS * ccsz, bhz = gz0 + (float)(hzS+1) * ccsz;
        float dfx = fmaxf(qx - blx, bhx - qx);
        float dfy = fmaxf(qy - bly, bhy - qy);
        float dfz = fmaxf(qz - blz, bhz - qz);
        tc = sqrtf(dfx*dfx + dfy*dfy + dfz*dfz) * 1.0001f + 1e-6f;
    }

    unsigned int* candp = cand + q*CAPS2;
    bool done_sel = false;   // selk already holds final neighbors
    bool ret = true;
    float T = tc, tlo = 0.0f, thi = 0.0f;

    if (cbox <= (unsigned)CAP2) {
        // ======== BOX PATH (tail): exact d30 from box points ========
        if (l == 0) cntq[q] = 0u;
        {
            int bnx = hxS-lxS+1, bny = hyS-lyS+1, bnz = hzS-lzS+1;
            int tot = bnx*bny*bnz;
            int ix = l, iy = 0, iz = 0;
            while (ix >= bnx) { ix -= bnx; ++iy; }
            while (iy >= bny) { iy -= bny; ++iz; }
            for (int i = l; i < tot; i += LPQ) {
                int cidx = ((lzS+iz)*RC + (lyS+iy))*RC + (lxS+ix);
                ix += LPQ;
                while (ix >= bnx) { ix -= bnx; ++iy; }
                while (iy >= bny) { iy -= bny; ++iz; }
                if (!ccnt[cidx]) continue;
                int cbase = cidx << 6;
                unsigned int b_ = cbase ? cellend[cbase-1] : 0u;
                unsigned int e_ = cellend[cbase+63];
                for (unsigned int p = b_; p < e_; ++p) {
                    float4 sp = spts[p];
                    float ex = qx - sp.x, ey = qy - sp.y, ez = qz - sp.z;
                    float d2 = fmaf(ex, ex, fmaf(ey, ey, ez*ez));
                    unsigned int pos = atomicAdd(&cntq[q], 1u);
                    candp[pos] = (__float_as_uint(d2) & 0xFFFF0000u) | (__float_as_uint(sp.w) & 0xFFFFu);
                }
            }
        }
        int C = (int)cntq[q];       // == cbox, in [KNN, CAP2]
        rank_select(candp, C, selk + q*KNN, l);
        unsigned int k30 = selk[q*KNN + KNN-1];
        float T2b = __uint_as_float(((k30 >> 16) + 1u) << 16);  // all 30 have d2 < T2b
        // inscribed radius^2 of box around q (clipped faces -> +inf: no points beyond bbox)
        float rins2;
        {
            float rxl = (lxS > 0)    ? (qx - (gx0 + (float)lxS * ccsx))     : 1e30f;
            float rxh = (hxS < RC-1) ? ((gx0 + (float)(hxS+1) * ccsx) - qx) : 1e30f;
            float ryl = (lyS > 0)    ? (qy - (gy0 + (float)lyS * ccsy))     : 1e30f;
            float ryh = (hyS < RC-1) ? ((gy0 + (float)(hyS+1) * ccsy) - qy) : 1e30f;
            float rzl = (lzS > 0)    ? (qz - (gz0 + (float)lzS * ccsz))     : 1e30f;
            float rzh = (hzS < RC-1) ? ((gz0 + (float)(hzS+1) * ccsz) - qz) : 1e30f;
            float rins = fminf(fminf(fminf(rxl, rxh), fminf(ryl, ryh)), fminf(rzl, rzh));
            rins = fmaxf(rins, 0.0f);
            rins2 = rins * rins;
        }
        if (T2b <= rins2) {
            done_sel = true; ret = false;   // ball(d30) inside box: selk is final
        } else {
            T = fminf(sqrtf(T2b), tc);      // one sweep; count >= KNN guaranteed
        }
    } else {
        // ======== DENSE PATH: density estimate + bracket bisection ========
        float vol = (float)((hxS-lxS+1)*(hyS-lyS+1)*(hzS-lzS+1)) * vcell * 64.0f;
        float t0 = cbrtf(TGT * vol / (4.18879f * (float)cbox));
        float tlo0 = 0.0f;
        if (S0 > 0) {
            float s1 = (float)(S0 - 1);
            float rx = fminf(qx - (gx0 + ((float)qccx - s1) * ccsx),
                             (gx0 + ((float)qccx + s1 + 1.0f) * ccsx) - qx);
            float ry = fminf(qy - (gy0 + ((float)qccy - s1) * ccsy),
                             (gy0 + ((float)qccy + s1 + 1.0f) * ccsy) - qy);
            float rz = fminf(qz - (gz0 + ((float)qccz - s1) * ccsz),
                             (gz0 + ((float)qccz + s1 + 1.0f) * ccsz) - qz);
            float rins = fminf(rx, fminf(ry, rz));
            tlo0 = fmaxf(rins, 0.0f) * 0.9999f;
        }
        tlo = tlo0;
        T = fminf(fmaxf(t0, tlo0 * 1.02f), tc);
    }

    // ---- phase B: probe + bracket bisection, per-group, barrier-free ----
    volatile unsigned int* cvp = &cntq[q];
    for (int round = 0; round < MAXR; ++round) {
        if (!__any(ret)) break;
        if (ret) {
            cntq[q] = 0u;
            float T2 = T*T;
            int smaxF = (int)(T * icsmin) + 1; if (smaxF > RG) smaxF = RG;
            if (smaxF <= 4) {
                // fine centered walk, cube side B <= 9, division-free
                int B = 2*smaxF + 1;
                int tot = B*B*B;
                int bx0 = qcx - smaxF, by0 = qcy - smaxF, bz0 = qcz - smaxF;
                int ix = l, iy = 0, iz = 0;
                while (ix >= B) { ix -= B; ++iy; }
                while (iy >= B) { iy -= B; ++iz; }
                for (int i = l; i < tot; i += LPQ) {
                    if (*cvp > (unsigned)CAP2) break;
                    int cx = bx0 + ix, cy = by0 + iy, cz = bz0 + iz;
                    if ((unsigned)cx < (unsigned)RG && (unsigned)cy < (unsigned)RG && (unsigned)cz < (unsigned)RG) {
                        float lox = gx0 + (float)cx * csx;
                        float loy = gy0 + (float)cy * csy;
                        float loz = gz0 + (float)cz * csz;
                        float ax_ = fmaxf(0.0f, fmaxf(lox - qx, qx - lox - csx));
                        float ay_ = fmaxf(0.0f, fmaxf(loy - qy, qy - loy - csy));
                        float az_ = fmaxf(0.0f, fmaxf(loz - qz, qz - loz - csz));
                        float md2 = fmaf(ax_, ax_, fmaf(ay_, ay_, az_*az_));
                        if (md2 < T2) {
                            int c = fidx(cx, cy, cz);
                            unsigned int b_ = c ? cellend[c-1] : 0u;
                            scan_range(spts, b_, cellend[c], qx, qy, qz, T2, &cntq[q], candp);
                        }
                    }
                    ix += LPQ;
                    while (ix >= B) { ix -= B; ++iy; }
                    while (iy >= B) { iy -= B; ++iz; }
                }
            } else {
                // coarse-skip walk; contiguous range scan per coarse cell when cheap
                int fx0 = qcx - smaxF, fx1 = qcx + smaxF;
                int fy0 = qcy - smaxF, fy1 = qcy + smaxF;
                int fz0 = qcz - smaxF, fz1 = qcz + smaxF;
                int cx0 = (fx0 < 0 ? 0 : fx0) >> 2, cx1 = (fx1 > RG-1 ? RG-1 : fx1) >> 2;
                int cy0 = (fy0 < 0 ? 0 : fy0) >> 2, cy1 = (fy1 > RG-1 ? RG-1 : fy1) >> 2;
                int cz0 = (fz0 < 0 ? 0 : fz0) >> 2, cz1 = (fz1 > RG-1 ? RG-1 : fz1) >> 2;
                int cnx = cx1-cx0+1, cny = cy1-cy0+1, cnz = cz1-cz0+1;
                int tot = cnx*cny*cnz;
                int ix = l, iy = 0, iz = 0;
                while (ix >= cnx) { ix -= cnx; ++iy; }
                while (iy >= cny) { iy -= cny; ++iz; }
                for (int i = l; i < tot; i += LPQ) {
                    if (*cvp > (unsigned)CAP2) break;
                    int ccx = cx0+ix, ccy = cy0+iy, ccz = cz0+iz;
                    ix += LPQ;
                    while (ix >= cnx) { ix -= cnx; ++iy; }
                    while (iy >= cny) { iy -= cny; ++iz; }
                    int cidx = (ccz*RC + ccy)*RC + ccx;
                    unsigned int pc = ccnt[cidx];
                    if (!pc) continue;
                    float clx = gx0 + (float)ccx * ccsx;
                    float cly = gy0 + (float)ccy * ccsy;
                    float clz = gz0 + (float)ccz * ccsz;
                    float bx_ = fmaxf(0.0f, fmaxf(clx - qx, qx - clx - ccsx));
                    float by_ = fmaxf(0.0f, fmaxf(cly - qy, qy - cly - ccsy));
                    float bz_ = fmaxf(0.0f, fmaxf(clz - qz, qz - clz - ccsz));
                    float cmd2 = fmaf(bx_, bx_, fmaf(by_, by_, bz_*bz_));
                    if (cmd2 >= T2) continue;
                    int cbase = cidx << 6;
                    unsigned int cb_ = cbase ? cellend[cbase-1] : 0u;
                    unsigned int ce_ = cellend[cbase+63];
                    float mxx = fmaxf(qx - clx, clx + ccsx - qx);
                    float mxy = fmaxf(qy - cly, cly + ccsy - qy);
                    float mxz = fmaxf(qz - clz, clz + ccsz - qz);
                    float cmx2 = mxx*mxx + mxy*mxy + mxz*mxz;
                    if (cmx2 < T2 || pc <= 96u) {
                        scan_range(spts, cb_, ce_, qx, qy, qz, T2, &cntq[q], candp);
                    } else {
                        float axv[4], ayv[4], azv[4];
                        #pragma unroll
                        for (int u2 = 0; u2 < 4; ++u2) {
                            float lox = clx + (float)u2 * csx;
                            axv[u2] = fmaxf(0.0f, fmaxf(lox - qx, qx - lox - csx));
                            float loy = cly + (float)u2 * csy;
                            ayv[u2] = fmaxf(0.0f, fmaxf(loy - qy, qy - loy - csy));
                            float loz = clz + (float)u2 * csz;
                            azv[u2] = fmaxf(0.0f, fmaxf(loz - qz, qz - loz - csz));
                        }
                        #pragma unroll
                        for (int fz = 0; fz < 4; ++fz) {
                            float pz2 = azv[fz]*azv[fz];
                            #pragma unroll
                            for (int fy = 0; fy < 4; ++fy) {
                                float pyz = fmaf(ayv[fy], ayv[fy], pz2);
                                if (pyz >= T2) continue;
                                #pragma unroll
                                for (int fx = 0; fx < 4; ++fx) {
                                    float md2 = fmaf(axv[fx], axv[fx], pyz);
                                    if (md2 < T2) {
                                        int c = cbase + ((fz<<4) | (fy<<2) | fx);
                                        unsigned int b_ = c ? cellend[c-1] : 0u;
                                        scan_range(spts, b_, cellend[c], qx, qy, qz, T2, &cntq[q], candp);
                                    }
                                }
                            }
                        }
                    }
                }
            }
            // controller (identical on all lanes of the group)
            unsigned int c_ = cntq[q];
            if (c_ >= (unsigned)KNN && c_ <= (unsigned)CAP2) {
                ret = false;
            } else if (round < MAXR-1) {
                float nT;
                if (c_ < (unsigned)KNN) {
                    tlo = T;
                    nT = (thi > 0.0f) ? sqrtf(tlo * thi)
                       : fminf(T * fminf(fmaxf(cbrtf(TGT / (float)(c_ ? c_ : 1u)), 1.25f), 2.5f), tc);
                } else {
                    thi = T;
                    nT = (tlo > 0.0f) ? sqrtf(tlo * thi)
                       : T * fminf(fmaxf(cbrtf(TGT / (float)c_), 0.30f), 0.75f);
                }
                T = fminf(nT, tc);
            } else {
                ret = false;    // exhausted; belt in phase D handles gracefully
            }
        }
    }

    // ---- phase C: exact rank-select (skipped if box path finished) ----
    if (!done_sel) {
        unsigned int cc = cntq[q];
        int C = (int)(cc < (unsigned)CAP2 ? cc : (unsigned)CAP2);
        rank_select(candp, C, selk + q*KNN, l);
    }

    // ---- phase D: epilogue (one neighbor per lane) ----
    {
        unsigned int ccq = cntq[q];
        int Cq = (int)(ccq < (unsigned)CAP2 ? ccq : (unsigned)CAP2);
        int kmax = Cq < KNN ? Cq : KNN;

        bool v = (l < kmax);
        int j = v ? (int)(selk[q*KNN + l] & 0xFFFFu) : 0;
        float sx = sverts[3*j+0], sy = sverts[3*j+1], sz = sverts[3*j+2];
        float px = qx - sx, py = qy - sy, pz = qz - sz;
        float r2 = px*px + py*py + pz*pz;
        float nx = snorms[3*j+0], ny = snorms[3*j+1], nz = snorms[3*j+2];
        float nrm = sqrtf(nx*nx + ny*ny + nz*nz);
        float inv = 1.0f / fmaxf(nrm, 1e-8f);
        float m0 = v ? 1.0f : 0.0f;
        nx *= inv * m0; ny *= inv * m0; nz *= inv * m0;
        px *= m0; py *= m0; pz *= m0;
        float r2m = r2 * m0;
        float fxv = px*nx + py*ny + pz*nz;
        float dsum = v ? sqrtf(r2) : 0.0f;
        dsum += __shfl_xor(dsum, 1);
        dsum += __shfl_xor(dsum, 2);
        dsum += __shfl_xor(dsum, 4);
        dsum += __shfl_xor(dsum, 8);
        dsum += __shfl_xor(dsum, 16);
        float h = dsum * (1.0f / (float)KNN) + 1e-8f;
        float h2 = h * h;
        float c8 = -8.0f / h2;
        float tt = fmaxf(1.0f - r2m / h2, 0.0f);
        float t2 = tt * tt;
        float phi = t2 * t2 * m0;
        float gco = c8 * t2 * tt * m0;

        const float inv_sn2 = 1.0f / (SIGMA_N * SIGMA_N);
        float f = 0.0f, gx = 0.0f, gy = 0.0f, gz = 0.0f;
        bool done = false;
        for (int it = 0; it < 3; ++it) {
            if (done) break;
            float alpha = 1.0f;
            if (it > 0) {
                float dx = nx-gx, dy = ny-gy, dz = nz-gz;
                alpha = expf(-(dx*dx + dy*dy + dz*dz) * inv_sn2);
            }
            float w = alpha * phi;
            float g = alpha * gco;
            float gf = g * fxv;
            float sw  = w,      swf = w * fxv;
            float sgx = g*px,   sgy = g*py,   sgz = g*pz;
            float sfx = gf*px,  sfy = gf*py,  sfz = gf*pz;
            float snx = w*nx,   sny = w*ny,   snz = w*nz;
            #pragma unroll
            for (int m = 1; m < LPQ; m <<= 1) {
                sw  += __shfl_xor(sw, m);  swf += __shfl_xor(swf, m);
                sgx += __shfl_xor(sgx, m); sgy += __shfl_xor(sgy, m); sgz += __shfl_xor(sgz, m);
                sfx += __shfl_xor(sfx, m); sfy += __shfl_xor(sfy, m); sfz += __shfl_xor(sfz, m);
                snx += __shfl_xor(snx, m); sny += __shfl_xor(sny, m); snz += __shfl_xor(snz, m);
            }
            sw += 1e-8f;
            float fn  = swf / sw;
            float gnx = (sfx + snx - fn*sgx) / sw;
            float gny = (sfy + sny - fn*sgy) / sw;
            float gnz = (sfz + snz - fn*sgz) / sw;
            float delta = fabsf(fn - f);
            f = fn; gx = gnx; gy = gny; gz = gnz;
            done = (delta < THRESHV);
        }
        if (l == 0) {
            int gq = blockIdx.x * QT2 + q;
            if (gq < N) {
                out[gq] = f;
                out[N + 3*gq + 0] = gx;
                out[N + 3*gq + 1] = gy;
                out[N + 3*gq + 2] = gz;
            }
        }
    }
}

// ============================================================

extern "C" void kernel_launch(void* const* d_in, const int* in_sizes, int n_in,
                              void* d_out, int out_size, void* d_ws, size_t ws_size,
                              hipStream_t stream) {
    (void)n_in; (void)out_size;
    const float* qpts   = (const float*)d_in[0];
    const float* sverts = (const float*)d_in[1];
    const float* snorms = (const float*)d_in[2];
    float* out = (float*)d_out;
    int N = in_sizes[0] / 3;
    int M = in_sizes[1] / 3;

    size_t need_grid = (size_t)M * 16 + (size_t)NC * 4 + 256 * 4 + 6 * 4 + 12 * 4 + (size_t)NCC * 4;

    if (ws_size >= need_grid && M <= 65536) {
        char* w = (char*)d_ws;
        float4*       spts   = (float4*)w;
        unsigned int* offs   = (unsigned int*)(w + (size_t)M * 16);
        unsigned int* aux    = offs + NC;
        unsigned int* bbox   = aux + 256;
        float*        gp     = (float*)(bbox + 6);
        unsigned int* coarse = (unsigned int*)(gp + 12);

        int mb = (M + 255) / 256;
        grid_init   <<<(NC + 255) / 256, 256, 0, stream>>>(offs, aux, bbox, coarse);
        grid_bbox   <<<mb, 256, 0, stream>>>(sverts, bbox, M);
        grid_params <<<1, 64, 0, stream>>>(bbox, gp);
        grid_count  <<<mb, 256, 0, stream>>>(sverts, gp, offs, coarse, M);
        grid_scan_tile<<<NC / 1024, 256, 0, stream>>>(offs, aux);
        grid_scan_aux <<<1, 256, 0, stream>>>(aux);
        grid_scan_add <<<NC / 1024, 256, 0, stream>>>(offs, aux);
        grid_scatter<<<mb, 256, 0, stream>>>(sverts, gp, offs, spts, M);

        int blocks = (N + QT2 - 1) / QT2;
        rimls_grid<<<blocks, NTH2, 0, stream>>>(qpts, sverts, snorms, spts, offs, coarse, gp, out, N);
    } else {
        int blocks = (N + QT - 1) / QT;
        if (ws_size >= (size_t)M * sizeof(float4)) {
            float4* spack = (float4*)d_ws;
            prep_pack<<<(M + 255) / 256, 256, 0, stream>>>(sverts, spack, M);
            rimls_fused<true><<<blocks, NTH, 0, stream>>>(qpts, sverts, snorms, spack, out, N, M);
        } else {
            rimls_fused<false><<<blocks, NTH, 0, stream>>>(qpts, sverts, snorms, nullptr, out, N, M);
        }
    }
}

// Round 7
// 539.968 us; speedup vs baseline: 5.2861x; 1.0724x over previous
//
#include <hip/hip_runtime.h>
#include <math.h>

#define KNN 30
#define SIGMA_N 0.8f
#define THRESHV 1e-3f

// ---------------- old (fallback) path constants ----------------
#define QT 32
#define NTH 256
#define CAP 160
#define CAPS 161
#define RSEL 20

// ---------------- grid path constants ----------------
#define RG 64
#define NC (RG*RG*RG)
#define RC 16                    // coarse grid (RG/4)
#define NCC (RC*RC*RC)
#define QT2 8                    // queries per block
#define NTH2 256
#define LPQ 32                   // lanes per query (half wave)
#define CAP2 320
#define CAPS2 324                // multiple of 4 -> 16B-aligned rows for uint4 reads
#define TGT 48.0f
#define MAXR 12

// ============================================================
// ===============  OLD BRUTE-FORCE PATH (fallback) ===========
// ============================================================

__global__ void prep_pack(const float* __restrict__ src, float4* __restrict__ dst, int M) {
    int j = blockIdx.x * 256 + threadIdx.x;
    if (j < M) {
        float x = src[3*j+0], y = src[3*j+1], z = src[3*j+2];
        dst[j] = make_float4(x, y, z, 0.5f*(x*x + y*y + z*z));
    }
}

template<bool PACKED>
__device__ __forceinline__ float4 fetch_pt(const float4* __restrict__ sp,
                                           const float* __restrict__ sv, int j) {
    if (PACKED) return sp[j];
    float x = sv[3*j+0], y = sv[3*j+1], z = sv[3*j+2];
    return make_float4(x, y, z, 0.5f*(x*x + y*y + z*z));
}

__device__ __forceinline__ void ins4(unsigned int k, unsigned int &m0, unsigned int &m1,
                                     unsigned int &m2, unsigned int &m3) {
    if (k < m3) {
        if (k < m2) {
            m3 = m2;
            if (k < m1) { m2 = m1; if (k < m0) { m1 = m0; m0 = k; } else m1 = k; }
            else m2 = k;
        } else m3 = k;
    }
}

template<bool PACKED>
__global__ __launch_bounds__(NTH)
void rimls_fused(const float* __restrict__ qpts,
                 const float* __restrict__ sverts,
                 const float* __restrict__ snorms,
                 const float4* __restrict__ spack,
                 float* __restrict__ out,
                 int N, int M)
{
    __shared__ unsigned int cand[QT * CAPS];
    __shared__ unsigned int selk[QT * KNN];
    __shared__ float4 qbuf[QT];
    __shared__ unsigned int cnt[QT];
    __shared__ unsigned int T16[QT];
    __shared__ int retryq[QT];

    const int t  = threadIdx.x;
    const int qg = t >> 4;
    const int c  = t & 15;
    const int qa = qg, qb = qg + 16;

    if (t < QT) {
        int gq = blockIdx.x * QT + t; if (gq >= N) gq = N - 1;
        float x = qpts[3*gq+0], y = qpts[3*gq+1], z = qpts[3*gq+2];
        qbuf[t] = make_float4(x, y, z, 0.5f*(x*x + y*y + z*z));
    }
    for (int i = t; i < QT * KNN; i += NTH) selk[i] = 0u;
    __syncthreads();

    const float ax = qbuf[qa].x, ay = qbuf[qa].y, az = qbuf[qa].z, aw = qbuf[qa].w;
    const float bx = qbuf[qb].x, by = qbuf[qb].y, bz = qbuf[qb].z, bw = qbuf[qb].w;

    unsigned int a0=~0u,a1=~0u,a2=~0u,a3=~0u, b0=~0u,b1=~0u,b2=~0u,b3=~0u;
    {
        const int n1 = M >> 6;
        #pragma unroll 2
        for (int i = 0; i < n1; ++i) {
            int j = (c + (i << 4)) << 2;
            float4 s = fetch_pt<PACKED>(spack, sverts, j);
            float va = fmaxf(fmaf(-ax, s.x, fmaf(-ay, s.y, fmaf(-az, s.z, s.w + aw))), 0.0f);
            float vb = fmaxf(fmaf(-bx, s.x, fmaf(-by, s.y, fmaf(-bz, s.z, s.w + bw))), 0.0f);
            unsigned int ka = (__float_as_uint(va) & 0xFFFF0000u) | (unsigned int)j;
            unsigned int kb = (__float_as_uint(vb) & 0xFFFF0000u) | (unsigned int)j;
            ins4(ka, a0, a1, a2, a3);
            ins4(kb, b0, b1, b2, b3);
        }
    }
    {
        unsigned int* mb = cand;
        mb[qa*64 + c*4 + 0] = a0; mb[qa*64 + c*4 + 1] = a1;
        mb[qa*64 + c*4 + 2] = a2; mb[qa*64 + c*4 + 3] = a3;
        mb[qb*64 + c*4 + 0] = b0; mb[qb*64 + c*4 + 1] = b1;
        mb[qb*64 + c*4 + 2] = b2; mb[qb*64 + c*4 + 3] = b3;
    }
    __syncthreads();
    if (t < QT) {
        const unsigned int* m_ = cand + t * 64;
        unsigned int kth = 0xFFFFFFFFu;
        for (int a = 0; a < 64; ++a) {
            unsigned int ka = m_[a]; int r = 0;
            for (int b = 0; b < 64; ++b) r += (m_[b] < ka) ? 1 : 0;
            if (r == RSEL - 1) kth = ka;
        }
        unsigned int tb = (kth >> 16) + 1u;
        if (tb > 0x7F00u) tb = 0x7F00u;
        T16[t] = tb; cnt[t] = 0u; retryq[t] = 1;
    }
    __syncthreads();

    const int n3 = M >> 4;
    for (int round = 0; round < 8; ++round) {
        bool aa = retryq[qa] != 0, ab = retryq[qb] != 0;
        if (aa || ab) {
            float Ta = aa ? __uint_as_float(T16[qa] << 16) : 0.0f;
            float Tb = ab ? __uint_as_float(T16[qb] << 16) : 0.0f;
            #pragma unroll 4
            for (int i = 0; i < n3; ++i) {
                int j = c + (i << 4);
                float4 s = fetch_pt<PACKED>(spack, sverts, j);
                float va = fmaxf(fmaf(-ax, s.x, fmaf(-ay, s.y, fmaf(-az, s.z, s.w + aw))), 0.0f);
                float vb = fmaxf(fmaf(-bx, s.x, fmaf(-by, s.y, fmaf(-bz, s.z, s.w + bw))), 0.0f);
                if (va < Ta) {
                    unsigned int pos = atomicAdd(&cnt[qa], 1u);
                    if (pos < (unsigned)CAP)
                        cand[qa*CAPS + pos] = (__float_as_uint(va) & 0xFFFF0000u) | (unsigned int)j;
                }
                if (vb < Tb) {
                    unsigned int pos = atomicAdd(&cnt[qb], 1u);
                    if (pos < (unsigned)CAP)
                        cand[qb*CAPS + pos] = (__float_as_uint(vb) & 0xFFFF0000u) | (unsigned int)j;
                }
            }
        }
        __syncthreads();
        int bad = 0;
        if (t < QT && retryq[t]) {
            unsigned int cc = cnt[t], tb = T16[t];
            if (cc < (unsigned)KNN) {
                if (tb < 0x7F00u) {
                    tb += (1u << 7);
                    if (tb > 0x7F00u) tb = 0x7F00u;
                    bad = 1;
                }
            } else if (cc > (unsigned)CAP && round < 4 && tb > (1u << 6)) {
                tb -= (1u << 6); bad = 1;
            }
            if (bad) { T16[t] = tb; cnt[t] = 0u; }
            else retryq[t] = 0;
        }
        if (!__syncthreads_or(bad)) break;
    }

    const int qs = t >> 3, s8 = t & 7;
    {
        unsigned int cc = cnt[qs];
        int C = (int)(cc < (unsigned)CAP ? cc : (unsigned)CAP);
        const unsigned int* cd = cand + qs * CAPS;
        for (int a = s8; a < C; a += 8) {
            unsigned int ka = cd[a]; int r = 0;
            for (int b = 0; b < C; ++b) r += (cd[b] < ka) ? 1 : 0;
            if (r < KNN) selk[qs*KNN + r] = ka;
        }
    }
    __syncthreads();

    {
        const float qx = qbuf[qs].x, qy = qbuf[qs].y, qz = qbuf[qs].z;
        float px_[4], py_[4], pz_[4], nx_[4], ny_[4], nz_[4];
        float fx_[4], phi_[4], gco_[4], r2_[4];
        float dsum = 0.0f;
        #pragma unroll
        for (int u = 0; u < 4; ++u) {
            int k = s8 + 8*u;
            bool v = (k < KNN);
            int j = v ? (int)(selk[qs*KNN + k] & 0xFFFFu) : 0;
            float4 s = fetch_pt<PACKED>(spack, sverts, j);
            float px = qx - s.x, py = qy - s.y, pz = qz - s.z;
            float r2 = px*px + py*py + pz*pz;
            float nx = snorms[3*j+0], ny = snorms[3*j+1], nz = snorms[3*j+2];
            float nrm = sqrtf(nx*nx + ny*ny + nz*nz);
            float inv = 1.0f / fmaxf(nrm, 1e-8f);
            float m = v ? 1.0f : 0.0f;
            nx *= inv * m; ny *= inv * m; nz *= inv * m;
            px_[u] = px * m; py_[u] = py * m; pz_[u] = pz * m;
            nx_[u] = nx; ny_[u] = ny; nz_[u] = nz;
            r2_[u] = r2 * m;
            fx_[u] = px_[u]*nx + py_[u]*ny + pz_[u]*nz;
            dsum += v ? sqrtf(r2) : 0.0f;
            phi_[u] = m;
        }
        dsum += __shfl_xor(dsum, 1);
        dsum += __shfl_xor(dsum, 2);
        dsum += __shfl_xor(dsum, 4);
        float h = dsum * (1.0f / (float)KNN) + 1e-8f;
        float h2 = h * h;
        float c8 = -8.0f / h2;
        #pragma unroll
        for (int u = 0; u < 4; ++u) {
            float tt = fmaxf(1.0f - r2_[u] / h2, 0.0f);
            float t2 = tt * tt;
            float valid = phi_[u];
            phi_[u] = t2 * t2 * valid;
            gco_[u] = c8 * t2 * tt * valid;
        }

        const float inv_sn2 = 1.0f / (SIGMA_N * SIGMA_N);
        float f = 0.0f, gx = 0.0f, gy = 0.0f, gz = 0.0f;
        bool done = false;
        for (int it = 0; it < 3; ++it) {
            if (done) break;
            float sw=0, swf=0, sgx=0, sgy=0, sgz=0, sfx=0, sfy=0, sfz=0, snx=0, sny=0, snz=0;
            #pragma unroll
            for (int u = 0; u < 4; ++u) {
                float alpha = 1.0f;
                if (it > 0) {
                    float dx = nx_[u]-gx, dy = ny_[u]-gy, dz = nz_[u]-gz;
                    alpha = expf(-(dx*dx + dy*dy + dz*dz) * inv_sn2);
                }
                float w = alpha * phi_[u];
                float g = alpha * gco_[u];
                float gf = g * fx_[u];
                sw  += w;          swf += w * fx_[u];
                sgx += g*px_[u];   sgy += g*py_[u];   sgz += g*pz_[u];
                sfx += gf*px_[u];  sfy += gf*py_[u];  sfz += gf*pz_[u];
                snx += w*nx_[u];   sny += w*ny_[u];   snz += w*nz_[u];
            }
            #pragma unroll
            for (int m = 1; m < 8; m <<= 1) {
                sw  += __shfl_xor(sw, m);  swf += __shfl_xor(swf, m);
                sgx += __shfl_xor(sgx, m); sgy += __shfl_xor(sgy, m); sgz += __shfl_xor(sgz, m);
                sfx += __shfl_xor(sfx, m); sfy += __shfl_xor(sfy, m); sfz += __shfl_xor(sfz, m);
                snx += __shfl_xor(snx, m); sny += __shfl_xor(sny, m); snz += __shfl_xor(snz, m);
            }
            sw += 1e-8f;
            float fn  = swf / sw;
            float gnx = (sfx + snx - fn*sgx) / sw;
            float gny = (sfy + sny - fn*sgy) / sw;
            float gnz = (sfz + snz - fn*sgz) / sw;
            float delta = fabsf(fn - f);
            f = fn; gx = gnx; gy = gny; gz = gnz;
            done = (delta < THRESHV);
        }
        if (s8 == 0) {
            int gq = blockIdx.x * QT + qs;
            if (gq < N) {
                out[gq] = f;
                out[N + 3*gq + 0] = gx;
                out[N + 3*gq + 1] = gy;
                out[N + 3*gq + 2] = gz;
            }
        }
    }
}

// ============================================================
// ===============  GRID KNN PATH  ============================
// ============================================================

__device__ __forceinline__ unsigned int enc_f(float f) {
    unsigned int b = __float_as_uint(f);
    return (b & 0x80000000u) ? ~b : (b | 0x80000000u);
}
__device__ __forceinline__ float dec_f(unsigned int u) {
    unsigned int b = (u & 0x80000000u) ? (u ^ 0x80000000u) : ~u;
    return __uint_as_float(b);
}
__device__ __forceinline__ int cell_of(float v, float mn, float ics) {
    int c = (int)floorf((v - mn) * ics);
    return c < 0 ? 0 : (c >= RG ? RG-1 : c);
}
// coarse-major fine-cell index: each coarse cell's 64 fine cells (and thus its
// points after scatter) are CONTIGUOUS
__device__ __forceinline__ int fidx(int cx, int cy, int cz) {
    int cidx = (((cz >> 2)*RC + (cy >> 2))*RC + (cx >> 2));
    return (cidx << 6) | ((cz & 3) << 4) | ((cy & 3) << 2) | (cx & 3);
}

// fused bbox + grid params: single block, 1024 threads
__global__ void grid_bboxparams(const float* __restrict__ sv, float* __restrict__ gp, int M) {
    __shared__ unsigned int rmn[3][16], rmx[3][16];
    const int t = threadIdx.x;
    unsigned int mn0=0xFFFFFFFFu, mn1=0xFFFFFFFFu, mn2=0xFFFFFFFFu;
    unsigned int mx0=0u, mx1=0u, mx2=0u;
    for (int i = t; i < M; i += 1024) {
        unsigned int e0 = enc_f(sv[3*i+0]);
        unsigned int e1 = enc_f(sv[3*i+1]);
        unsigned int e2 = enc_f(sv[3*i+2]);
        mn0 = min(mn0, e0); mn1 = min(mn1, e1); mn2 = min(mn2, e2);
        mx0 = max(mx0, e0); mx1 = max(mx1, e1); mx2 = max(mx2, e2);
    }
    for (int off = 1; off < 64; off <<= 1) {
        mn0 = min(mn0, (unsigned int)__shfl_xor(mn0, off));
        mn1 = min(mn1, (unsigned int)__shfl_xor(mn1, off));
        mn2 = min(mn2, (unsigned int)__shfl_xor(mn2, off));
        mx0 = max(mx0, (unsigned int)__shfl_xor(mx0, off));
        mx1 = max(mx1, (unsigned int)__shfl_xor(mx1, off));
        mx2 = max(mx2, (unsigned int)__shfl_xor(mx2, off));
    }
    if ((t & 63) == 0) {
        int w = t >> 6;
        rmn[0][w]=mn0; rmn[1][w]=mn1; rmn[2][w]=mn2;
        rmx[0][w]=mx0; rmx[1][w]=mx1; rmx[2][w]=mx2;
    }
    __syncthreads();
    if (t == 0) {
        for (int w = 1; w < 16; ++w) {
            rmn[0][0]=min(rmn[0][0],rmn[0][w]); rmn[1][0]=min(rmn[1][0],rmn[1][w]); rmn[2][0]=min(rmn[2][0],rmn[2][w]);
            rmx[0][0]=max(rmx[0][0],rmx[0][w]); rmx[1][0]=max(rmx[1][0],rmx[1][w]); rmx[2][0]=max(rmx[2][0],rmx[2][w]);
        }
        float csmin = 1e30f, vcell = 1.0f;
        for (int a = 0; a < 3; ++a) {
            float mn = dec_f(rmn[a][0]), mx = dec_f(rmx[a][0]);
            float span = mx - mn;
            if (!(span > 1e-5f)) span = 1e-5f;
            float cs = span / (float)RG;
            gp[a] = mn; gp[3+a] = cs; gp[6+a] = 1.0f / cs;
            csmin = fminf(csmin, cs); vcell *= cs;
        }
        gp[9]  = 1.0f / csmin;
        gp[10] = vcell;
    }
}

__global__ void grid_count(const float* __restrict__ sv, const float* __restrict__ gp,
                           unsigned int* __restrict__ offs, int M) {
    int i = blockIdx.x * 256 + threadIdx.x;
    if (i >= M) return;
    int cx = cell_of(sv[3*i+0], gp[0], gp[6]);
    int cy = cell_of(sv[3*i+1], gp[1], gp[7]);
    int cz = cell_of(sv[3*i+2], gp[2], gp[8]);
    atomicAdd(&offs[fidx(cx, cy, cz)], 1u);
}

__global__ void grid_scan_tile(unsigned int* __restrict__ offs, unsigned int* __restrict__ aux) {
    __shared__ unsigned int sm[256];
    const int tid = threadIdx.x;
    const int base = blockIdx.x * 1024 + tid * 4;
    uint4 v = *(const uint4*)&offs[base];
    v.y += v.x; v.z += v.y; v.w += v.z;
    sm[tid] = v.w;
    __syncthreads();
    for (int off = 1; off < 256; off <<= 1) {
        unsigned int add = (tid >= off) ? sm[tid - off] : 0u;
        __syncthreads();
        sm[tid] += add;
        __syncthreads();
    }
    unsigned int add = tid ? sm[tid-1] : 0u;
    v.x += add; v.y += add; v.z += add; v.w += add;
    *(uint4*)&offs[base] = v;
    if (tid == 255) aux[blockIdx.x] = sm[255];
}

__global__ void grid_scan_aux(unsigned int* __restrict__ aux) {
    __shared__ unsigned int sm[256];
    const int tid = threadIdx.x;
    sm[tid] = aux[tid];
    __syncthreads();
    for (int off = 1; off < 256; off <<= 1) {
        unsigned int add = (tid >= off) ? sm[tid - off] : 0u;
        __syncthreads();
        sm[tid] += add;
        __syncthreads();
    }
    aux[tid] = tid ? sm[tid-1] : 0u;
}

__global__ void grid_scan_add(unsigned int* __restrict__ offs, const unsigned int* __restrict__ aux) {
    __shared__ unsigned int sm[1024];
    const int tid = threadIdx.x;
    const int base = blockIdx.x * 1024;
    uint4 v = *(const uint4*)&offs[base + tid*4];
    sm[tid*4+0] = v.x; sm[tid*4+1] = v.y; sm[tid*4+2] = v.z; sm[tid*4+3] = v.w;
    __syncthreads();
    unsigned int a = aux[blockIdx.x];
    uint4 o;
    o.x = a + (tid ? sm[tid*4-1] : 0u);
    o.y = a + sm[tid*4+0];
    o.z = a + sm[tid*4+1];
    o.w = a + sm[tid*4+2];
    *(uint4*)&offs[base + tid*4] = o;
}

__global__ void grid_scatter(const float* __restrict__ sv, const float* __restrict__ gp,
                             unsigned int* __restrict__ offs, float4* __restrict__ spts, int M) {
    int i = blockIdx.x * 256 + threadIdx.x;
    if (i >= M) return;
    float x = sv[3*i+0], y = sv[3*i+1], z = sv[3*i+2];
    int cx = cell_of(x, gp[0], gp[6]);
    int cy = cell_of(y, gp[1], gp[7]);
    int cz = cell_of(z, gp[2], gp[8]);
    unsigned int pos = atomicAdd(&offs[fidx(cx, cy, cz)], 1u);
    spts[pos] = make_float4(x, y, z, __uint_as_float((unsigned int)i));
}

// scan a contiguous point range with threshold filter; aborts on overshoot
__device__ __forceinline__ void scan_range(const float4* __restrict__ spts,
                                           unsigned int b_, unsigned int e_,
                                           float qx, float qy, float qz, float T2,
                                           unsigned int* cntp, unsigned int* candp) {
    for (unsigned int p = b_; p < e_; ++p) {
        if (((p - b_) & 15u) == 0u &&
            *(volatile unsigned int*)cntp > (unsigned)CAP2) return;
        float4 sp = spts[p];
        float ex = qx - sp.x, ey = qy - sp.y, ez = qz - sp.z;
        float d2 = fmaf(ex, ex, fmaf(ey, ey, ez*ez));
        if (d2 < T2) {
            unsigned int pos = atomicAdd(cntp, 1u);
            if (pos < (unsigned)CAP2)
                candp[pos] = (__float_as_uint(d2) & 0xFFFF0000u) | (__float_as_uint(sp.w) & 0xFFFFu);
        }
    }
}

// exact rank-select of the KNN smallest 32-bit keys among C candidates.
// cd must be 16B aligned (CAPS2 % 4 == 0); uint4 LDS reads cut DS-op count 4x.
__device__ __forceinline__ void rank_select(const unsigned int* __restrict__ cd, int C,
                                            unsigned int* __restrict__ sel, int l) {
    const int C4 = C & ~3;
    for (int a = l; a < C; a += LPQ) {
        unsigned int ka = cd[a]; int r = 0;
        for (int b = 0; b < C4; b += 4) {
            uint4 v = *(const uint4*)(cd + b);
            r += (v.x < ka) ? 1 : 0;
            r += (v.y < ka) ? 1 : 0;
            r += (v.z < ka) ? 1 : 0;
            r += (v.w < ka) ? 1 : 0;
        }
        for (int b = C4; b < C; ++b) r += (cd[b] < ka) ? 1 : 0;
        if (r < KNN) sel[r] = ka;
    }
}

// Barrier-free grid kernel: 8 queries/block, 32 lanes/query (half wave).
__global__ __launch_bounds__(NTH2)
void rimls_grid(const float* __restrict__ qpts,
                const float* __restrict__ sverts,
                const float* __restrict__ snorms,
                const float4* __restrict__ spts,
                const unsigned int* __restrict__ cellend,
                const float* __restrict__ gp,
                float* __restrict__ out,
                int N)
{
    __shared__ __align__(16) unsigned int cand[QT2*CAPS2];  // 10368 B
    __shared__ unsigned int selk[QT2*KNN];                  // 960 B
    __shared__ unsigned short ccnt[NCC];                    // 8192 B
    __shared__ float qsx[QT2], qsy[QT2], qsz[QT2];
    __shared__ unsigned int cntq[QT2];

    const int t = threadIdx.x;
    const int q = t >> 5;       // 0..7
    const int l = t & 31;       // lane within query group

    if (t < QT2) {
        int gq = blockIdx.x * QT2 + t; if (gq >= N) gq = N - 1;
        qsx[t] = qpts[3*gq+0]; qsy[t] = qpts[3*gq+1]; qsz[t] = qpts[3*gq+2];
        cntq[t] = 0u;
    }
    for (int i = t; i < QT2*KNN; i += NTH2) selk[i] = 0u;
    // coarse counts derived from fine cellend (coarse-major layout: contiguous 64)
    for (int i = t; i < NCC; i += NTH2) {
        unsigned int e_ = cellend[(i << 6) + 63];
        unsigned int b_ = i ? cellend[(i << 6) - 1] : 0u;
        unsigned int v = e_ - b_;
        ccnt[i] = (unsigned short)(v > 65535u ? 65535u : v);
    }
    __syncthreads();
    // ---- no block barriers beyond this point ----

    const float gx0 = gp[0], gy0 = gp[1], gz0 = gp[2];
    const float csx = gp[3], csy = gp[4], csz = gp[5];
    const float icx = gp[6], icy = gp[7], icz = gp[8];
    const float icsmin = gp[9], vcell = gp[10];
    const float ccsx = 4.0f*csx, ccsy = 4.0f*csy, ccsz = 4.0f*csz;

    const float qx = qsx[q], qy = qsy[q], qz = qsz[q];
    int qcx = (int)floorf((qx - gx0) * icx); qcx = qcx < 0 ? 0 : (qcx >= RG ? RG-1 : qcx);
    int qcy = (int)floorf((qy - gy0) * icy); qcy = qcy < 0 ? 0 : (qcy >= RG ? RG-1 : qcy);
    int qcz = (int)floorf((qz - gz0) * icz); qcz = qcz < 0 ? 0 : (qcz >= RG ? RG-1 : qcz);
    const int qccx = qcx >> 2, qccy = qcy >> 2, qccz = qcz >> 2;

    // ---- phase A: grow coarse box (LDS counts, division-free walk) ----
    int S0 = 0; unsigned int cbox = 1u;
    int lxS = 0, hxS = 0, lyS = 0, hyS = 0, lzS = 0, hzS = 0;
    for (int s = 0; s < RC; ++s) {
        int lx = qccx - s; if (lx < 0) lx = 0;
        int hx = qccx + s; if (hx > RC-1) hx = RC-1;
        int ly = qccy - s; if (ly < 0) ly = 0;
        int hy = qccy + s; if (hy > RC-1) hy = RC-1;
        int lz = qccz - s; if (lz < 0) lz = 0;
        int hz = qccz + s; if (hz > RC-1) hz = RC-1;
        int bnx = hx-lx+1, bny = hy-ly+1, bnz = hz-lz+1;
        int tot = bnx*bny*bnz;
        unsigned int csum = 0u;
        int ix = l, iy = 0, iz = 0;
        while (ix >= bnx) { ix -= bnx; ++iy; }
        while (iy >= bny) { iy -= bny; ++iz; }
        for (int i = l; i < tot; i += LPQ) {
            csum += (unsigned int)ccnt[((lz+iz)*RC + (ly+iy))*RC + (lx+ix)];
            ix += LPQ;
            while (ix >= bnx) { ix -= bnx; ++iy; }
            while (iy >= bny) { iy -= bny; ++iz; }
        }
        csum += __shfl_xor(csum, 1);
        csum += __shfl_xor(csum, 2);
        csum += __shfl_xor(csum, 4);
        csum += __shfl_xor(csum, 8);
        csum += __shfl_xor(csum, 16);
        if (csum >= (unsigned)KNN || s == RC-1) {
            S0 = s; cbox = csum ? csum : 1u;
            lxS = lx; hxS = hx; lyS = ly; hyS = hy; lzS = lz; hzS = hz;
            break;
        }
    }

    // common: rigorous cap tc (corner of clipped S0 box)
    float tc;
    {
        float blx = gx0 + (float)lxS * ccsx, bhx = gx0 + (float)(hxS+1) * ccsx;
        float bly = gy0 + (float)lyS * ccsy, bhy = gy0 + (float)(hyS+1) * ccsy;
        float blz = gz0 + (float)lzS * ccsz, bhz = gz0 + (float)(hzS+1) * ccsz;
        float dfx = fmaxf(qx - blx, bhx - qx);
        float dfy = fmaxf(qy - bly, bhy - qy);
        float dfz = fmaxf(qz - blz, bhz - qz);
        tc = sqrtf(dfx*dfx + dfy*dfy + dfz*dfz) * 1.0001f + 1e-6f;
    }

    unsigned int* candp = cand + q*CAPS2;
    bool done_sel = false;   // selk already holds final neighbors
    bool ret = true;
    float T = tc, tlo = 0.0f, thi = 0.0f;
    float vol = (float)((hxS-lxS+1)*(hyS-lyS+1)*(hzS-lzS+1)) * vcell * 64.0f;
    float t0 = cbrtf(TGT * vol / (4.18879f * (float)cbox));

    if (cbox <= (unsigned)CAP2) {
        // ======== BOX PATH (tail/mid): filtered collection + exact d30 ========
        t0 = fminf(fmaxf(t0, 1e-6f), tc);
        float T02 = t0 * t0;
        if (l == 0) cntq[q] = 0u;
        {
            int bnx = hxS-lxS+1, bny = hyS-lyS+1, bnz = hzS-lzS+1;
            int tot = bnx*bny*bnz;
            int ix = l, iy = 0, iz = 0;
            while (ix >= bnx) { ix -= bnx; ++iy; }
            while (iy >= bny) { iy -= bny; ++iz; }
            for (int i = l; i < tot; i += LPQ) {
                int cidx = ((lzS+iz)*RC + (lyS+iy))*RC + (lxS+ix);
                ix += LPQ;
                while (ix >= bnx) { ix -= bnx; ++iy; }
                while (iy >= bny) { iy -= bny; ++iz; }
                if (!ccnt[cidx]) continue;
                int cbase = cidx << 6;
                unsigned int b_ = cbase ? cellend[cbase-1] : 0u;
                unsigned int e_ = cellend[cbase+63];
                scan_range(spts, b_, e_, qx, qy, qz, T02, &cntq[q], candp);
            }
        }
        int C = (int)cntq[q];   // <= cbox <= CAP2, no overflow possible
        if (C >= KNN) {
            // top-30 among filtered set is exact (excluded points have d2 >= T02 > d30)
            rank_select(candp, C, selk + q*KNN, l);
            unsigned int k30 = selk[q*KNN + KNN-1];
            float T2b = __uint_as_float(((k30 >> 16) + 1u) << 16);
            // inscribed radius^2 of box around q (clipped faces -> +inf)
            float rins2;
            {
                float rxl = (lxS > 0)    ? (qx - (gx0 + (float)lxS * ccsx))     : 1e30f;
                float rxh = (hxS < RC-1) ? ((gx0 + (float)(hxS+1) * ccsx) - qx) : 1e30f;
                float ryl = (lyS > 0)    ? (qy - (gy0 + (float)lyS * ccsy))     : 1e30f;
                float ryh = (hyS < RC-1) ? ((gy0 + (float)(hyS+1) * ccsy) - qy) : 1e30f;
                float rzl = (lzS > 0)    ? (qz - (gz0 + (float)lzS * ccsz))     : 1e30f;
                float rzh = (hzS < RC-1) ? ((gz0 + (float)(hzS+1) * ccsz) - qz) : 1e30f;
                float rins = fminf(fminf(fminf(rxl, rxh), fminf(ryl, ryh)), fminf(rzl, rzh));
                rins = fmaxf(rins, 0.0f);
                rins2 = rins * rins;
            }
            if (T2b <= rins2) {
                done_sel = true; ret = false;   // ball(d30) inside box: selk is final
            } else {
                T = fminf(sqrtf(T2b), tc);      // one sweep; count >= KNN guaranteed
            }
        } else {
            // filter undershot: bracket [t0, tc], grow
            tlo = t0; thi = 0.0f;
            T = fminf(t0 * fminf(fmaxf(cbrtf(TGT / (float)(C ? C : 1)), 1.25f), 2.5f), tc);
        }
    } else {
        // ======== DENSE PATH: density estimate + bracket bisection ========
        float tlo0 = 0.0f;
        if (S0 > 0) {
            float s1 = (float)(S0 - 1);
            float rx = fminf(qx - (gx0 + ((float)qccx - s1) * ccsx),
                             (gx0 + ((float)qccx + s1 + 1.0f) * ccsx) - qx);
            float ry = fminf(qy - (gy0 + ((float)qccy - s1) * ccsy),
                             (gy0 + ((float)qccy + s1 + 1.0f) * ccsy) - qy);
            float rz = fminf(qz - (gz0 + ((float)qccz - s1) * ccsz),
                             (gz0 + ((float)qccz + s1 + 1.0f) * ccsz) - qz);
            float rins = fminf(rx, fminf(ry, rz));
            tlo0 = fmaxf(rins, 0.0f) * 0.9999f;
        }
        tlo = tlo0;
        T = fminf(fmaxf(t0, tlo0 * 1.02f), tc);
    }

    // ---- phase B: probe + bracket bisection, per-group, barrier-free ----
    volatile unsigned int* cvp = &cntq[q];
    for (int round = 0; round < MAXR; ++round) {
        if (!__any(ret)) break;
        if (ret) {
            cntq[q] = 0u;
            float T2 = T*T;
            int smaxF = (int)(T * icsmin) + 1; if (smaxF > RG) smaxF = RG;
            if (smaxF <= 4) {
                // fine centered walk, cube side B <= 9, division-free
                int B = 2*smaxF + 1;
                int tot = B*B*B;
                int bx0 = qcx - smaxF, by0 = qcy - smaxF, bz0 = qcz - smaxF;
                int ix = l, iy = 0, iz = 0;
                while (ix >= B) { ix -= B; ++iy; }
                while (iy >= B) { iy -= B; ++iz; }
                for (int i = l; i < tot; i += LPQ) {
                    if (*cvp > (unsigned)CAP2) break;
                    int cx = bx0 + ix, cy = by0 + iy, cz = bz0 + iz;
                    if ((unsigned)cx < (unsigned)RG && (unsigned)cy < (unsigned)RG && (unsigned)cz < (unsigned)RG) {
                        float lox = gx0 + (float)cx * csx;
                        float loy = gy0 + (float)cy * csy;
                        float loz = gz0 + (float)cz * csz;
                        float ax_ = fmaxf(0.0f, fmaxf(lox - qx, qx - lox - csx));
                        float ay_ = fmaxf(0.0f, fmaxf(loy - qy, qy - loy - csy));
                        float az_ = fmaxf(0.0f, fmaxf(loz - qz, qz - loz - csz));
                        float md2 = fmaf(ax_, ax_, fmaf(ay_, ay_, az_*az_));
                        if (md2 < T2) {
                            int c = fidx(cx, cy, cz);
                            unsigned int b_ = c ? cellend[c-1] : 0u;
                            scan_range(spts, b_, cellend[c], qx, qy, qz, T2, &cntq[q], candp);
                        }
                    }
                    ix += LPQ;
                    while (ix >= B) { ix -= B; ++iy; }
                    while (iy >= B) { iy -= B; ++iz; }
                }
            } else {
                // coarse-skip walk; contiguous range scan per coarse cell when cheap
                int fx0 = qcx - smaxF, fx1 = qcx + smaxF;
                int fy0 = qcy - smaxF, fy1 = qcy + smaxF;
                int fz0 = qcz - smaxF, fz1 = qcz + smaxF;
                int cx0 = (fx0 < 0 ? 0 : fx0) >> 2, cx1 = (fx1 > RG-1 ? RG-1 : fx1) >> 2;
                int cy0 = (fy0 < 0 ? 0 : fy0) >> 2, cy1 = (fy1 > RG-1 ? RG-1 : fy1) >> 2;
                int cz0 = (fz0 < 0 ? 0 : fz0) >> 2, cz1 = (fz1 > RG-1 ? RG-1 : fz1) >> 2;
                int cnx = cx1-cx0+1, cny = cy1-cy0+1, cnz = cz1-cz0+1;
                int tot = cnx*cny*cnz;
                int ix = l, iy = 0, iz = 0;
                while (ix >= cnx) { ix -= cnx; ++iy; }
                while (iy >= cny) { iy -= cny; ++iz; }
                for (int i = l; i < tot; i += LPQ) {
                    if (*cvp > (unsigned)CAP2) break;
                    int ccx = cx0+ix, ccy = cy0+iy, ccz = cz0+iz;
                    ix += LPQ;
                    while (ix >= cnx) { ix -= cnx; ++iy; }
                    while (iy >= cny) { iy -= cny; ++iz; }
                    int cidx = (ccz*RC + ccy)*RC + ccx;
                    unsigned int pc = ccnt[cidx];
                    if (!pc) continue;
                    float clx = gx0 + (float)ccx * ccsx;
                    float cly = gy0 + (float)ccy * ccsy;
                    float clz = gz0 + (float)ccz * ccsz;
                    float bx_ = fmaxf(0.0f, fmaxf(clx - qx, qx - clx - ccsx));
                    float by_ = fmaxf(0.0f, fmaxf(cly - qy, qy - cly - ccsy));
                    float bz_ = fmaxf(0.0f, fmaxf(clz - qz, qz - clz - ccsz));
                    float cmd2 = fmaf(bx_, bx_, fmaf(by_, by_, bz_*bz_));
                    if (cmd2 >= T2) continue;
                    int cbase = cidx << 6;
                    unsigned int cb_ = cbase ? cellend[cbase-1] : 0u;
                    unsigned int ce_ = cellend[cbase+63];
                    float mxx = fmaxf(qx - clx, clx + ccsx - qx);
                    float mxy = fmaxf(qy - cly, cly + ccsy - qy);
                    float mxz = fmaxf(qz - clz, clz + ccsz - qz);
                    float cmx2 = mxx*mxx + mxy*mxy + mxz*mxz;
                    if (cmx2 < T2 || pc <= 96u) {
                        scan_range(spts, cb_, ce_, qx, qy, qz, T2, &cntq[q], candp);
                    } else {
                        float axv[4], ayv[4], azv[4];
                        #pragma unroll
                        for (int u2 = 0; u2 < 4; ++u2) {
                            float lox = clx + (float)u2 * csx;
                            axv[u2] = fmaxf(0.0f, fmaxf(lox - qx, qx - lox - csx));
                            float loy = cly + (float)u2 * csy;
                            ayv[u2] = fmaxf(0.0f, fmaxf(loy - qy, qy - loy - csy));
                            float loz = clz + (float)u2 * csz;
                            azv[u2] = fmaxf(0.0f, fmaxf(loz - qz, qz - loz - csz));
                        }
                        #pragma unroll
                        for (int fz = 0; fz < 4; ++fz) {
                            float pz2 = azv[fz]*azv[fz];
                            #pragma unroll
                            for (int fy = 0; fy < 4; ++fy) {
                                float pyz = fmaf(ayv[fy], ayv[fy], pz2);
                                if (pyz >= T2) continue;
                                #pragma unroll
                                for (int fx = 0; fx < 4; ++fx) {
                                    float md2 = fmaf(axv[fx], axv[fx], pyz);
                                    if (md2 < T2) {
                                        int c = cbase + ((fz<<4) | (fy<<2) | fx);
                                        unsigned int b_ = c ? cellend[c-1] : 0u;
                                        scan_range(spts, b_, cellend[c], qx, qy, qz, T2, &cntq[q], candp);
                                    }
                                }
                            }
                        }
                    }
                }
            }
            // controller (identical on all lanes of the group)
            unsigned int c_ = cntq[q];
            if (c_ >= (unsigned)KNN && c_ <= (unsigned)CAP2) {
                ret = false;
            } else if (round < MAXR-1) {
                float nT;
                if (c_ < (unsigned)KNN) {
                    tlo = T;
                    nT = (thi > 0.0f) ? sqrtf(tlo * thi)
                       : fminf(T * fminf(fmaxf(cbrtf(TGT / (float)(c_ ? c_ : 1u)), 1.25f), 2.5f), tc);
                } else {
                    thi = T;
                    nT = (tlo > 0.0f) ? sqrtf(tlo * thi)
                       : T * fminf(fmaxf(cbrtf(TGT / (float)c_), 0.30f), 0.75f);
                }
                T = fminf(nT, tc);
            } else {
                ret = false;    // exhausted; belt in phase D handles gracefully
            }
        }
    }

    // ---- phase C: exact rank-select (skipped if box path finished) ----
    if (!done_sel) {
        unsigned int cc = cntq[q];
        int C = (int)(cc < (unsigned)CAP2 ? cc : (unsigned)CAP2);
        rank_select(candp, C, selk + q*KNN, l);
    }

    // ---- phase D: epilogue (one neighbor per lane) ----
    {
        unsigned int ccq = cntq[q];
        int Cq = done_sel ? KNN : (int)(ccq < (unsigned)CAP2 ? ccq : (unsigned)CAP2);
        int kmax = Cq < KNN ? Cq : KNN;

        bool v = (l < kmax);
        int j = v ? (int)(selk[q*KNN + l] & 0xFFFFu) : 0;
        float sx = sverts[3*j+0], sy = sverts[3*j+1], sz = sverts[3*j+2];
        float px = qx - sx, py = qy - sy, pz = qz - sz;
        float r2 = px*px + py*py + pz*pz;
        float nx = snorms[3*j+0], ny = snorms[3*j+1], nz = snorms[3*j+2];
        float nrm = sqrtf(nx*nx + ny*ny + nz*nz);
        float inv = 1.0f / fmaxf(nrm, 1e-8f);
        float m0 = v ? 1.0f : 0.0f;
        nx *= inv * m0; ny *= inv * m0; nz *= inv * m0;
        px *= m0; py *= m0; pz *= m0;
        float r2m = r2 * m0;
        float fxv = px*nx + py*ny + pz*nz;
        float dsum = v ? sqrtf(r2) : 0.0f;
        dsum += __shfl_xor(dsum, 1);
        dsum += __shfl_xor(dsum, 2);
        dsum += __shfl_xor(dsum, 4);
        dsum += __shfl_xor(dsum, 8);
        dsum += __shfl_xor(dsum, 16);
        float h = dsum * (1.0f / (float)KNN) + 1e-8f;
        float h2 = h * h;
        float c8 = -8.0f / h2;
        float tt = fmaxf(1.0f - r2m / h2, 0.0f);
        float t2 = tt * tt;
        float phi = t2 * t2 * m0;
        float gco = c8 * t2 * tt * m0;

        const float inv_sn2 = 1.0f / (SIGMA_N * SIGMA_N);
        float f = 0.0f, gx = 0.0f, gy = 0.0f, gz = 0.0f;
        bool done = false;
        for (int it = 0; it < 3; ++it) {
            if (done) break;
            float alpha = 1.0f;
            if (it > 0) {
                float dx = nx-gx, dy = ny-gy, dz = nz-gz;
                alpha = expf(-(dx*dx + dy*dy + dz*dz) * inv_sn2);
            }
            float w = alpha * phi;
            float g = alpha * gco;
            float gf = g * fxv;
            float sw  = w,      swf = w * fxv;
            float sgx = g*px,   sgy = g*py,   sgz = g*pz;
            float sfx = gf*px,  sfy = gf*py,  sfz = gf*pz;
            float snx = w*nx,   sny = w*ny,   snz = w*nz;
            #pragma unroll
            for (int m = 1; m < LPQ; m <<= 1) {
                sw  += __shfl_xor(sw, m);  swf += __shfl_xor(swf, m);
                sgx += __shfl_xor(sgx, m); sgy += __shfl_xor(sgy, m); sgz += __shfl_xor(sgz, m);
                sfx += __shfl_xor(sfx, m); sfy += __shfl_xor(sfy, m); sfz += __shfl_xor(sfz, m);
                snx += __shfl_xor(snx, m); sny += __shfl_xor(sny, m); snz += __shfl_xor(snz, m);
            }
            sw += 1e-8f;
            float fn  = swf / sw;
            float gnx = (sfx + snx - fn*sgx) / sw;
            float gny = (sfy + sny - fn*sgy) / sw;
            float gnz = (sfz + snz - fn*sgz) / sw;
            float delta = fabsf(fn - f);
            f = fn; gx = gnx; gy = gny; gz = gnz;
            done = (delta < THRESHV);
        }
        if (l == 0) {
            int gq = blockIdx.x * QT2 + q;
            if (gq < N) {
                out[gq] = f;
                out[N + 3*gq + 0] = gx;
                out[N + 3*gq + 1] = gy;
                out[N + 3*gq + 2] = gz;
            }
        }
    }
}

// ============================================================

extern "C" void kernel_launch(void* const* d_in, const int* in_sizes, int n_in,
                              void* d_out, int out_size, void* d_ws, size_t ws_size,
                              hipStream_t stream) {
    (void)n_in; (void)out_size;
    const float* qpts   = (const float*)d_in[0];
    const float* sverts = (const float*)d_in[1];
    const float* snorms = (const float*)d_in[2];
    float* out = (float*)d_out;
    int N = in_sizes[0] / 3;
    int M = in_sizes[1] / 3;

    size_t need_grid = (size_t)M * 16 + (size_t)NC * 4 + 256 * 4 + 12 * 4;

    if (ws_size >= need_grid && M <= 65536) {
        char* w = (char*)d_ws;
        float4*       spts = (float4*)w;
        unsigned int* offs = (unsigned int*)(w + (size_t)M * 16);
        unsigned int* aux  = offs + NC;
        float*        gp   = (float*)(aux + 256);

        int mb = (M + 255) / 256;
        hipMemsetAsync(offs, 0, (size_t)NC * 4, stream);
        grid_bboxparams<<<1, 1024, 0, stream>>>(sverts, gp, M);
        grid_count  <<<mb, 256, 0, stream>>>(sverts, gp, offs, M);
        grid_scan_tile<<<NC / 1024, 256, 0, stream>>>(offs, aux);
        grid_scan_aux <<<1, 256, 0, stream>>>(aux);
        grid_scan_add <<<NC / 1024, 256, 0, stream>>>(offs, aux);
        grid_scatter<<<mb, 256, 0, stream>>>(sverts, gp, offs, spts, M);

        int blocks = (N + QT2 - 1) / QT2;
        rimls_grid<<<blocks, NTH2, 0, stream>>>(qpts, sverts, snorms, spts, offs, gp, out, N);
    } else {
        int blocks = (N + QT - 1) / QT;
        if (ws_size >= (size_t)M * sizeof(float4)) {
            float4* spack = (float4*)d_ws;
            prep_pack<<<(M + 255) / 256, 256, 0, stream>>>(sverts, spack, M);
            rimls_fused<true><<<blocks, NTH, 0, stream>>>(qpts, sverts, snorms, spack, out, N, M);
        } else {
            rimls_fused<false><<<blocks, NTH, 0, stream>>>(qpts, sverts, snorms, nullptr, out, N, M);
        }
    }
}